// Round 3
// baseline (1441.100 us; speedup 1.0000x reference)
//
#include <hip/hip_runtime.h>

#define B_ 8
#define N_ 512
#define D_ 512
#define H_ 8
#define DK_ 64

typedef unsigned int uint;
typedef unsigned short ushort;
typedef __attribute__((ext_vector_type(8))) short short8;
typedef __attribute__((ext_vector_type(4))) float floatx4;

__device__ __forceinline__ float bf2f(ushort s) { return __uint_as_float(((uint)s) << 16); }
__device__ __forceinline__ ushort f2bf(float f) {
    uint x = __float_as_uint(f);
    return (ushort)((x + 0x7fffu + ((x >> 16) & 1u)) >> 16);
}
__device__ __forceinline__ float blo(uint u) { return __uint_as_float(u << 16); }
__device__ __forceinline__ float bhi(uint u) { return __uint_as_float(u & 0xffff0000u); }

// dual-dtype scalar loads: isbf=1 -> buffer is packed bf16; else float32
__device__ __forceinline__ float ldf(const void* p, size_t i, int isbf) {
    return isbf ? bf2f(((const ushort*)p)[i]) : ((const float*)p)[i];
}
__device__ __forceinline__ short ldb(const void* p, size_t i, int isbf) {
    return isbf ? (short)(((const ushort*)p)[i]) : (short)f2bf(((const float*)p)[i]);
}

// Detect input float dtype. bf16-packed: bits[14:7] = exponent of a N(0,1) bf16,
// concentrated in [0x70,0x84]. fp32: those are mantissa bits, ~uniform (~8% in range).
__global__ __launch_bounds__(256) void probe_dtype(const uint* __restrict__ q,
                                                   int* __restrict__ flag) {
    __shared__ int s[256];
    const int t = threadIdx.x;
    int cnt = 0;
    for (int i = t; i < 4096; i += 256) {
        const uint e = (q[i] >> 7) & 0xffu;
        cnt += (e >= 0x70u && e <= 0x84u) ? 1 : 0;
    }
    s[t] = cnt;
    __syncthreads();
    for (int d = 128; d > 0; d >>= 1) {
        if (t < d) s[t] += s[t + d];
        __syncthreads();
    }
    if (t == 0) *flag = (s[0] > 3276) ? 1 : 0;   // >80% in-band => bf16
}

// C = A[4096,512] @ W[512,512] + bias, one 16x16 tile per wave.
// a_follows: A dtype follows *flagp (user input) vs forced bf16 (ws tensor).
// mode 1: out bf16 ws [B,H,N,DK]; mode 2: out = d_out flat [4096,512], dtype per flag.
__global__ __launch_bounds__(256) void gemm16(const void* __restrict__ A,
                                              const void* __restrict__ W,
                                              const void* __restrict__ bias,
                                              void* __restrict__ out,
                                              const int* __restrict__ flagp,
                                              int a_follows, int mode) {
    const int isbf = *flagp;
    const int a_isbf = a_follows ? isbf : 1;
    const int wave = threadIdx.x >> 6;
    const int tile = blockIdx.x * 4 + wave;      // 8192 tiles
    const int tm = tile >> 5, tn = tile & 31;
    const int row0 = tm * 16, col0 = tn * 16;
    const int lane = threadIdx.x & 63;
    const int m = lane & 15, quad = lane >> 4;

    floatx4 acc = {0.f, 0.f, 0.f, 0.f};
    const size_t abase = (size_t)(row0 + m) * D_ + quad * 8;
    const size_t wbase = (size_t)(quad * 8) * D_ + col0 + m;
    for (int k0 = 0; k0 < D_; k0 += 32) {
        short8 af, bf;
#pragma unroll
        for (int j = 0; j < 8; ++j) af[j] = ldb(A, abase + k0 + j, a_isbf);
#pragma unroll
        for (int j = 0; j < 8; ++j) bf[j] = ldb(W, wbase + (size_t)(k0 + j) * D_, isbf);
        acc = __builtin_amdgcn_mfma_f32_16x16x32_bf16(af, bf, acc, 0, 0, 0);
    }
    const int col = col0 + m;
    const float bi = ldf(bias, col, isbf);
#pragma unroll
    for (int r = 0; r < 4; ++r) {
        const int row = row0 + quad * 4 + r;
        const float v = acc[r] + bi;
        if (mode == 1) {
            ((ushort*)out)[(size_t)(((row >> 9) * H_ + (col >> 6)) * N_ + (row & 511)) * DK_ + (col & 63)] = f2bf(v);
        } else if (isbf) {
            ((ushort*)out)[(size_t)row * D_ + col] = f2bf(v);
        } else {
            ((float*)out)[(size_t)row * D_ + col] = v;
        }
    }
}

// Full-softmax box attention. Block = (b, h, 8-row i-tile), 256 threads.
__global__ __launch_bounds__(256) void attn_kernel(
    const ushort* __restrict__ qw, const ushort* __restrict__ kw,
    const ushort* __restrict__ vw, const void* __restrict__ box,
    const int* __restrict__ mask, const int* __restrict__ nobj,
    const void* __restrict__ WG, const void* __restrict__ bG,
    ushort* __restrict__ att, const int* __restrict__ flagp) {
    const int isbf = *flagp;
    const int b = blockIdx.z, h = blockIdx.y;
    const int i0 = blockIdx.x * 8;
    const int t = threadIdx.x;

    __shared__ float lg[8][520];     // logits -> probs, full 512-row per i
    __shared__ float q_s[8][68];     // q prescaled by 1/sqrt(DK)
    __shared__ float wgh[64];        // WG[h][:]
    __shared__ float cxi[8], cyi[8], rwi[8], rhi[8], lwi[8], lhi[8];
    __shared__ int noi[8];
    __shared__ float rsum[8];

    // ---- preamble ----
    for (int e = t; e < 512; e += 256) {
        const int ii = e >> 6, dk = e & 63;
        q_s[ii][dk] = bf2f(qw[(size_t)((b * H_ + h) * N_ + i0 + ii) * DK_ + dk]) * 0.125f;
    }
    if (t < 64) wgh[t] = ldf(WG, h * 64 + t, isbf);
    if (t < 8) {
        const size_t bb = (size_t)(b * N_ + i0 + t) * 4;
        const float xmn = ldf(box, bb + 0, isbf), ymn = ldf(box, bb + 1, isbf);
        const float xmx = ldf(box, bb + 2, isbf), ymx = ldf(box, bb + 3, isbf);
        const float w = xmx - xmn + 1.0f, hh = ymx - ymn + 1.0f;
        cxi[t] = (xmn + xmx) * 0.5f;
        cyi[t] = (ymn + ymx) * 0.5f;
        rwi[t] = 1.0f / w;
        rhi[t] = 1.0f / hh;
        lwi[t] = __logf(w);
        lhi[t] = __logf(hh);
        noi[t] = nobj[b * N_ + i0 + t];
    }
    const float bg = ldf(bG, h, isbf);
    __syncthreads();

    // ---- phase A: logits (scores + geometry), thread = j, two j per thread ----
    for (int jl = 0; jl < 2; ++jl) {
        const int j = t + jl * 256;
        float acc[8];
#pragma unroll
        for (int ii = 0; ii < 8; ++ii) acc[ii] = 0.f;
        const uint4* krow = (const uint4*)(kw + (size_t)((b * H_ + h) * N_ + j) * DK_);
#pragma unroll
        for (int c = 0; c < 8; ++c) {
            const uint4 ku = krow[c];
            float kf[8];
            kf[0] = blo(ku.x); kf[1] = bhi(ku.x); kf[2] = blo(ku.y); kf[3] = bhi(ku.y);
            kf[4] = blo(ku.z); kf[5] = bhi(ku.z); kf[6] = blo(ku.w); kf[7] = bhi(ku.w);
#pragma unroll
            for (int ii = 0; ii < 8; ++ii) {
                const float4 qa = *(const float4*)(&q_s[ii][c * 8]);
                const float4 qb = *(const float4*)(&q_s[ii][c * 8 + 4]);
                acc[ii] += qa.x * kf[0] + qa.y * kf[1] + qa.z * kf[2] + qa.w * kf[3] +
                           qb.x * kf[4] + qb.y * kf[5] + qb.z * kf[6] + qb.w * kf[7];
            }
        }
        const int mj = mask[b * N_ + j];
        const size_t bb = (size_t)(b * N_ + j) * 4;
        const float xmn = ldf(box, bb + 0, isbf), ymn = ldf(box, bb + 1, isbf);
        const float xmx = ldf(box, bb + 2, isbf), ymx = ldf(box, bb + 3, isbf);
        const float cxj = (xmn + xmx) * 0.5f, cyj = (ymn + ymx) * 0.5f;
        const float wj = xmx - xmn + 1.0f, hj = ymx - ymn + 1.0f;
        const float lwj = __logf(wj), lhj = __logf(hj);
        const int noj = nobj[b * N_ + j];
        const float dm[8] = {1.0f, 0.421696503f, 0.177827941f, 0.074989421f,
                             0.031622777f, 0.013335214f, 0.005623413f, 0.002371374f};
        for (int ii = 0; ii < 8; ++ii) {
            const float mobj = (noi[ii] || noj) ? 0.f : 1.f;
            const float dx = __logf(fmaxf(fabsf((cxi[ii] - cxj) * rwi[ii]), 0.001f));
            const float dy = __logf(fmaxf(fabsf((cyi[ii] - cyj) * rhi[ii]), 0.001f));
            const float dwv = lwi[ii] - lwj;
            const float dhv = lhi[ii] - lhj;
            const float pos[4] = {dx, dy, dwv, dhv};
            float wg = bg;
            for (int p = 0; p < 4; ++p) {
                const float base = 100.f * pos[p];
#pragma unroll
                for (int f = 0; f < 8; ++f) {
                    float sv, cv;
                    __sincosf(base * dm[f], &sv, &cv);
                    const int g = p * 8 + f;
                    wg += sv * wgh[g] + cv * wgh[32 + g];
                }
            }
            const float gl = __logf(fmaxf(wg, 1e-6f)) * mobj;
            lg[ii][j] = (mj ? acc[ii] : -1e9f) + gl;
        }
    }
    __syncthreads();

    // ---- phase B: full softmax per i-row; 32 threads per row ----
    {
        const int rr = t >> 5, l32 = t & 31;
        float mx = -3e38f;
        for (int j = l32; j < N_; j += 32) mx = fmaxf(mx, lg[rr][j]);
#pragma unroll
        for (int d = 1; d < 32; d <<= 1) mx = fmaxf(mx, __shfl_xor(mx, d, 32));
        float sm = 0.f;
        for (int j = l32; j < N_; j += 32) {
            const float p = __expf(lg[rr][j] - mx);
            lg[rr][j] = p;
            sm += p;
        }
#pragma unroll
        for (int d = 1; d < 32; d <<= 1) sm += __shfl_xor(sm, d, 32);
        if (l32 == 0) rsum[rr] = sm;
    }
    __syncthreads();

    // ---- phase C: PV + write; thread = (ii = t>>5, dk pair = t&31) ----
    {
        const int ii = t >> 5, dkp = t & 31;
        float o0 = 0.f, o1 = 0.f;
        const uint* vbase = (const uint*)vw + (size_t)((b * H_ + h) * N_) * (DK_ / 2) + dkp;
        for (int j = 0; j < N_; ++j) {
            const uint u = vbase[(size_t)j * (DK_ / 2)];
            const float p = lg[ii][j];
            o0 += p * blo(u);
            o1 += p * bhi(u);
        }
        const float inv = 1.0f / rsum[ii];
        const uint pk = (uint)f2bf(o0 * inv) | ((uint)f2bf(o1 * inv) << 16);
        ((uint*)att)[(size_t)(b * N_ + i0 + ii) * (D_ / 2) + h * 32 + dkp] = pk;
    }
}

extern "C" void kernel_launch(void* const* d_in, const int* in_sizes, int n_in,
                              void* d_out, int out_size, void* d_ws, size_t ws_size,
                              hipStream_t stream) {
    const void* xq = d_in[0];
    const void* xk = d_in[1];
    const void* xv = d_in[2];
    const void* box = d_in[3];
    const int* mask = (const int*)d_in[4];
    const int* nobj = (const int*)d_in[5];
    const void* Wq = d_in[6];
    const void* bq = d_in[7];
    const void* Wk = d_in[8];
    const void* bk = d_in[9];
    const void* Wv = d_in[10];
    const void* bv = d_in[11];
    const void* Wo = d_in[12];
    const void* bo = d_in[13];
    const void* WG = d_in[14];
    const void* bG = d_in[15];

    char* ws = (char*)d_ws;
    int* flag = (int*)ws;                            // 256 B header
    ushort* qw = (ushort*)(ws + 256);                // 4 MB bf16 [B,H,N,DK]
    ushort* kw = (ushort*)(ws + 256 + 4194304);      // 4 MB bf16 [B,H,N,DK]
    ushort* vw = (ushort*)(ws + 256 + 8388608);      // 4 MB bf16 [B,H,N,DK]
    ushort* att = (ushort*)(ws + 256 + 12582912);    // 4 MB bf16 [B,N,D]

    hipLaunchKernelGGL(probe_dtype, dim3(1), dim3(256), 0, stream, (const uint*)xq, flag);
    hipLaunchKernelGGL(gemm16, dim3(2048), dim3(256), 0, stream, xq, Wq, bq, (void*)qw, flag, 1, 1);
    hipLaunchKernelGGL(gemm16, dim3(2048), dim3(256), 0, stream, xk, Wk, bk, (void*)kw, flag, 1, 1);
    hipLaunchKernelGGL(gemm16, dim3(2048), dim3(256), 0, stream, xv, Wv, bv, (void*)vw, flag, 1, 1);
    hipLaunchKernelGGL(attn_kernel, dim3(N_ / 8, H_, B_), dim3(256), 0, stream,
                       qw, kw, vw, box, mask, nobj, WG, bG, att, flag);
    hipLaunchKernelGGL(gemm16, dim3(2048), dim3(256), 0, stream, att, Wo, bo, d_out, flag, 0, 2);
}

// Round 4
// 770.345 us; speedup vs baseline: 1.8707x; 1.8707x over previous
//
#include <hip/hip_runtime.h>
#include <hip/hip_fp16.h>

#define B_ 8
#define N_ 512
#define D_ 512
#define H_ 8
#define DK_ 64

typedef unsigned int uint;
typedef unsigned short ushort;
typedef __attribute__((ext_vector_type(8))) short short8;
typedef __attribute__((ext_vector_type(4))) float floatx4;

__device__ __forceinline__ float bf2f(ushort s) { return __uint_as_float(((uint)s) << 16); }
__device__ __forceinline__ ushort f2bf(float f) {
    uint x = __float_as_uint(f);
    return (ushort)((x + 0x7fffu + ((x >> 16) & 1u)) >> 16);
}
__device__ __forceinline__ float blo(uint u) { return __uint_as_float(u << 16); }
__device__ __forceinline__ float bhi(uint u) { return __uint_as_float(u & 0xffff0000u); }
__device__ __forceinline__ float ldf(const void* p, size_t i, int isbf) {
    return isbf ? bf2f(((const ushort*)p)[i]) : ((const float*)p)[i];
}
__device__ __forceinline__ short ldb(const void* p, size_t i, int isbf) {
    return isbf ? (short)(((const ushort*)p)[i]) : (short)f2bf(((const float*)p)[i]);
}

// ---------------- dtype probe (proven in round 3) ----------------
__global__ __launch_bounds__(256) void probe_dtype(const uint* __restrict__ q,
                                                   int* __restrict__ flag) {
    __shared__ int s[256];
    const int t = threadIdx.x;
    int cnt = 0;
    for (int i = t; i < 4096; i += 256) {
        const uint e = (q[i] >> 7) & 0xffu;
        cnt += (e >= 0x70u && e <= 0x84u) ? 1 : 0;
    }
    s[t] = cnt;
    __syncthreads();
    for (int d = 128; d > 0; d >>= 1) {
        if (t < d) s[t] += s[t + d];
        __syncthreads();
    }
    if (t == 0) *flag = (s[0] > 3276) ? 1 : 0;
}

// ---------------- bias convert: 4 x 512 -> fp32 ----------------
__global__ __launch_bounds__(256) void prep_bias(const void* __restrict__ b0,
                                                 const void* __restrict__ b1,
                                                 const void* __restrict__ b2,
                                                 const void* __restrict__ b3,
                                                 float* __restrict__ biasf,
                                                 const int* __restrict__ flagp) {
    const int isbf = *flagp;
    const int e = blockIdx.x * 256 + threadIdx.x;   // grid 8 -> 2048
    const int z = e >> 9;
    const void* src = (z == 0) ? b0 : (z == 1) ? b1 : (z == 2) ? b2 : b3;
    biasf[e] = ldf(src, e & 511, isbf);
}

// ---------------- W transpose -> Wt[n][k] bf16 ----------------
__global__ __launch_bounds__(256) void transw(const void* __restrict__ w0,
                                              const void* __restrict__ w1,
                                              const void* __restrict__ w2,
                                              const void* __restrict__ w3,
                                              ushort* __restrict__ wt,
                                              const int* __restrict__ flagp) {
    const int isbf = *flagp;
    const int z = blockIdx.z;
    const void* W = (z == 0) ? w0 : (z == 1) ? w1 : (z == 2) ? w2 : w3;
    const int n0 = blockIdx.x * 32, k0 = blockIdx.y * 32;
    __shared__ float tile[32][33];
    const int tx = threadIdx.x & 31, ty = threadIdx.x >> 5;   // 32 x 8
#pragma unroll
    for (int r = 0; r < 4; ++r)
        tile[ty + 8 * r][tx] = ldf(W, (size_t)(k0 + ty + 8 * r) * D_ + n0 + tx, isbf);
    __syncthreads();
#pragma unroll
    for (int r = 0; r < 4; ++r)
        wt[(size_t)z * 262144 + (size_t)(n0 + ty + 8 * r) * D_ + k0 + tx] =
            f2bf(tile[tx][ty + 8 * r]);
}

// ---------------- MFMA GEMM: C[4096,512] = A @ W + b ----------------
// Block tile 128x64, BK=32, 256 threads (4 waves of 32 M-rows x 64 N).
// Wt is k-major [n][k] bf16. MODE 0: z=blockIdx.z picks QKV, out [B,H,N,DK] bf16.
// MODE 1: out = d_out flat, dtype per flag. want>=0: early-exit unless *flagp==want.
template <typename AT, int MODE>
__global__ __launch_bounds__(256) void gemm_mfma(
    const AT* __restrict__ A0, const AT* __restrict__ A1, const AT* __restrict__ A2,
    const ushort* __restrict__ wt, const float* __restrict__ biasf,
    ushort* __restrict__ oq, ushort* __restrict__ ok, ushort* __restrict__ ov,
    void* __restrict__ dout, const int* __restrict__ flagp, int want) {
    if (want >= 0 && *flagp != want) return;
    const int z = (MODE == 0) ? blockIdx.z : 3;
    const AT* A = (MODE == 0) ? ((z == 0) ? A0 : (z == 1) ? A1 : A2) : A0;
    const ushort* W = wt + (size_t)z * 262144;
    const float* bias = biasf + z * 512;
    const int row0 = blockIdx.x * 128, col0 = blockIdx.y * 64;
    const int t = threadIdx.x, wv = t >> 6, lane = t & 63;
    const int m16 = lane & 15, quad = lane >> 4;

    __shared__ ushort As[128][40];
    __shared__ ushort Ws[64][40];
    floatx4 acc[2][4] = {};

    const int ar = t >> 1, ah = t & 1;        // A staging: row, 16-elem k-half
    const int wr = t >> 2, wc = (t & 3) * 8;  // W staging: n-row, 8-elem k-col

    for (int k0 = 0; k0 < D_; k0 += 32) {
        __syncthreads();
        {   // stage A (16 elems/thread), inline fp32->bf16 if needed
            const AT* ap = A + (size_t)(row0 + ar) * D_ + k0 + ah * 16;
            short8 s0, s1;
            if constexpr (sizeof(AT) == 4) {
                const float4 f0 = *(const float4*)(ap);
                const float4 f1 = *(const float4*)(ap + 4);
                const float4 f2 = *(const float4*)(ap + 8);
                const float4 f3 = *(const float4*)(ap + 12);
                s0[0] = (short)f2bf(f0.x); s0[1] = (short)f2bf(f0.y);
                s0[2] = (short)f2bf(f0.z); s0[3] = (short)f2bf(f0.w);
                s0[4] = (short)f2bf(f1.x); s0[5] = (short)f2bf(f1.y);
                s0[6] = (short)f2bf(f1.z); s0[7] = (short)f2bf(f1.w);
                s1[0] = (short)f2bf(f2.x); s1[1] = (short)f2bf(f2.y);
                s1[2] = (short)f2bf(f2.z); s1[3] = (short)f2bf(f2.w);
                s1[4] = (short)f2bf(f3.x); s1[5] = (short)f2bf(f3.y);
                s1[6] = (short)f2bf(f3.z); s1[7] = (short)f2bf(f3.w);
            } else {
                s0 = *(const short8*)(ap);
                s1 = *(const short8*)(ap + 8);
            }
            *(short8*)&As[ar][ah * 16] = s0;
            *(short8*)&As[ar][ah * 16 + 8] = s1;
        }
        *(short8*)&Ws[wr][wc] =
            *(const short8*)(W + (size_t)(col0 + wr) * D_ + k0 + wc);
        __syncthreads();

        const short8 a0 = *(const short8*)&As[wv * 32 + m16][quad * 8];
        const short8 a1 = *(const short8*)&As[wv * 32 + 16 + m16][quad * 8];
        const short8 b0 = *(const short8*)&Ws[m16][quad * 8];
        const short8 b1 = *(const short8*)&Ws[16 + m16][quad * 8];
        const short8 b2 = *(const short8*)&Ws[32 + m16][quad * 8];
        const short8 b3 = *(const short8*)&Ws[48 + m16][quad * 8];
        acc[0][0] = __builtin_amdgcn_mfma_f32_16x16x32_bf16(a0, b0, acc[0][0], 0, 0, 0);
        acc[0][1] = __builtin_amdgcn_mfma_f32_16x16x32_bf16(a0, b1, acc[0][1], 0, 0, 0);
        acc[0][2] = __builtin_amdgcn_mfma_f32_16x16x32_bf16(a0, b2, acc[0][2], 0, 0, 0);
        acc[0][3] = __builtin_amdgcn_mfma_f32_16x16x32_bf16(a0, b3, acc[0][3], 0, 0, 0);
        acc[1][0] = __builtin_amdgcn_mfma_f32_16x16x32_bf16(a1, b0, acc[1][0], 0, 0, 0);
        acc[1][1] = __builtin_amdgcn_mfma_f32_16x16x32_bf16(a1, b1, acc[1][1], 0, 0, 0);
        acc[1][2] = __builtin_amdgcn_mfma_f32_16x16x32_bf16(a1, b2, acc[1][2], 0, 0, 0);
        acc[1][3] = __builtin_amdgcn_mfma_f32_16x16x32_bf16(a1, b3, acc[1][3], 0, 0, 0);
    }

    const int isbf = *flagp;
#pragma unroll
    for (int mt = 0; mt < 2; ++mt) {
#pragma unroll
        for (int nt = 0; nt < 4; ++nt) {
            const int colg = col0 + nt * 16 + m16;
            const float bi = bias[colg];
#pragma unroll
            for (int r = 0; r < 4; ++r) {
                const int row = row0 + wv * 32 + mt * 16 + quad * 4 + r;
                const float v = acc[mt][nt][r] + bi;
                if (MODE == 0) {
                    ushort* o = (z == 0) ? oq : (z == 1) ? ok : ov;
                    o[((size_t)((row >> 9) * H_ + (colg >> 6)) * N_ + (row & 511)) * DK_ +
                      (colg & 63)] = f2bf(v);
                } else if (isbf) {
                    ((ushort*)dout)[(size_t)row * D_ + colg] = f2bf(v);
                } else {
                    ((float*)dout)[(size_t)row * D_ + colg] = v;
                }
            }
        }
    }
}

// ---------------- geometry log-bias, all heads at once ----------------
// glog[((bl*512 + i)*8 + h)*512 + j] fp16 = log(max(wg,1e-6)) * mobj
__global__ __launch_bounds__(256) void geom(const void* __restrict__ box,
                                            const int* __restrict__ nobj,
                                            const void* __restrict__ WG,
                                            const void* __restrict__ bG,
                                            ushort* __restrict__ glog,
                                            const int* __restrict__ flagp, int b0) {
    const int isbf = *flagp;
    const int i = blockIdx.x, bl = blockIdx.y, bg = b0 + bl;
    const int t = threadIdx.x;
    __shared__ float wgs[512];   // wgs[g*8+h] = WG[h][g]
    __shared__ float bgs[8];
    for (int e = t; e < 512; e += 256) wgs[e] = ldf(WG, (size_t)(e & 7) * 64 + (e >> 3), isbf);
    if (t < 8) bgs[t] = ldf(bG, t, isbf);

    const size_t ib = (size_t)(bg * N_ + i) * 4;
    const float ixn = ldf(box, ib + 0, isbf), iyn = ldf(box, ib + 1, isbf);
    const float ixx = ldf(box, ib + 2, isbf), iyx = ldf(box, ib + 3, isbf);
    const float wi = ixx - ixn + 1.0f, hi = iyx - iyn + 1.0f;
    const float cxi = (ixn + ixx) * 0.5f, cyi = (iyn + iyx) * 0.5f;
    const float rwi = 1.0f / wi, rhi = 1.0f / hi;
    const float lwi = __logf(wi), lhi = __logf(hi);
    const int noi = nobj[bg * N_ + i];
    __syncthreads();

    const float dm[8] = {1.0f, 0.421696503f, 0.177827941f, 0.074989421f,
                         0.031622777f, 0.013335214f, 0.005623413f, 0.002371374f};
    for (int jl = 0; jl < 2; ++jl) {
        const int j = t + jl * 256;
        const size_t jb = (size_t)(bg * N_ + j) * 4;
        const float jxn = ldf(box, jb + 0, isbf), jyn = ldf(box, jb + 1, isbf);
        const float jxx = ldf(box, jb + 2, isbf), jyx = ldf(box, jb + 3, isbf);
        const float wj = jxx - jxn + 1.0f, hj = jyx - jyn + 1.0f;
        const float cxj = (jxn + jxx) * 0.5f, cyj = (jyn + jyx) * 0.5f;
        const float mobj = (noi || nobj[bg * N_ + j]) ? 0.f : 1.f;
        const float dx = __logf(fmaxf(fabsf((cxi - cxj) * rwi), 0.001f));
        const float dy = __logf(fmaxf(fabsf((cyi - cyj) * rhi), 0.001f));
        const float pos[4] = {dx, dy, lwi - __logf(wj), lhi - __logf(hj)};
        float wg[8];
#pragma unroll
        for (int h = 0; h < 8; ++h) wg[h] = bgs[h];
#pragma unroll
        for (int p = 0; p < 4; ++p) {
            const float base = 100.f * pos[p];
#pragma unroll
            for (int f = 0; f < 8; ++f) {
                float sv, cv;
                __sincosf(base * dm[f], &sv, &cv);
                const int g = p * 8 + f;
                const float4 s0 = *(const float4*)&wgs[g * 8];
                const float4 s1 = *(const float4*)&wgs[g * 8 + 4];
                const float4 c0 = *(const float4*)&wgs[(32 + g) * 8];
                const float4 c1 = *(const float4*)&wgs[(32 + g) * 8 + 4];
                wg[0] += sv * s0.x + cv * c0.x;
                wg[1] += sv * s0.y + cv * c0.y;
                wg[2] += sv * s0.z + cv * c0.z;
                wg[3] += sv * s0.w + cv * c0.w;
                wg[4] += sv * s1.x + cv * c1.x;
                wg[5] += sv * s1.y + cv * c1.y;
                wg[6] += sv * s1.z + cv * c1.z;
                wg[7] += sv * s1.w + cv * c1.w;
            }
        }
        __half* gp = (__half*)glog + (((size_t)bl * N_ + i) * H_) * N_ + j;
#pragma unroll
        for (int h = 0; h < 8; ++h)
            gp[(size_t)h * N_] = __float2half(__logf(fmaxf(wg[h], 1e-6f)) * mobj);
    }
}

// ---------------- lean attention (geometry precomputed) ----------------
__global__ __launch_bounds__(256) void attn2(
    const ushort* __restrict__ qw, const ushort* __restrict__ kw,
    const ushort* __restrict__ vw, const int* __restrict__ mask,
    const ushort* __restrict__ glog, ushort* __restrict__ att, int b0) {
    const int bl = blockIdx.z, bg = b0 + bl, h = blockIdx.y;
    const int i0 = blockIdx.x * 8, t = threadIdx.x;

    __shared__ float lg[8][520];
    __shared__ float q_s[8][68];
    __shared__ float rsum[8];

    for (int e = t; e < 512; e += 256) {
        const int ii = e >> 6, dk = e & 63;
        q_s[ii][dk] = bf2f(qw[(size_t)((bg * H_ + h) * N_ + i0 + ii) * DK_ + dk]) * 0.125f;
    }
    __syncthreads();

    for (int jl = 0; jl < 2; ++jl) {
        const int j = t + jl * 256;
        float acc[8];
#pragma unroll
        for (int ii = 0; ii < 8; ++ii) acc[ii] = 0.f;
        const uint4* krow = (const uint4*)(kw + (size_t)((bg * H_ + h) * N_ + j) * DK_);
#pragma unroll
        for (int c = 0; c < 8; ++c) {
            const uint4 ku = krow[c];
            float kf[8];
            kf[0] = blo(ku.x); kf[1] = bhi(ku.x); kf[2] = blo(ku.y); kf[3] = bhi(ku.y);
            kf[4] = blo(ku.z); kf[5] = bhi(ku.z); kf[6] = blo(ku.w); kf[7] = bhi(ku.w);
#pragma unroll
            for (int ii = 0; ii < 8; ++ii) {
                const float4 qa = *(const float4*)(&q_s[ii][c * 8]);
                const float4 qb = *(const float4*)(&q_s[ii][c * 8 + 4]);
                acc[ii] += qa.x * kf[0] + qa.y * kf[1] + qa.z * kf[2] + qa.w * kf[3] +
                           qb.x * kf[4] + qb.y * kf[5] + qb.z * kf[6] + qb.w * kf[7];
            }
        }
        const int mj = mask[bg * N_ + j];
        const __half* gp = (const __half*)glog + (((size_t)bl * N_ + i0) * H_ + h) * N_ + j;
#pragma unroll
        for (int ii = 0; ii < 8; ++ii)
            lg[ii][j] = (mj ? acc[ii] : -1e9f) + __half2float(gp[(size_t)ii * H_ * N_]);
    }
    __syncthreads();

    {   // softmax, 32 threads per i-row
        const int rr = t >> 5, l32 = t & 31;
        float mx = -3e38f;
        for (int j = l32; j < N_; j += 32) mx = fmaxf(mx, lg[rr][j]);
#pragma unroll
        for (int d = 1; d < 32; d <<= 1) mx = fmaxf(mx, __shfl_xor(mx, d, 32));
        float sm = 0.f;
        for (int j = l32; j < N_; j += 32) {
            const float p = __expf(lg[rr][j] - mx);
            lg[rr][j] = p;
            sm += p;
        }
#pragma unroll
        for (int d = 1; d < 32; d <<= 1) sm += __shfl_xor(sm, d, 32);
        if (l32 == 0) rsum[rr] = sm;
    }
    __syncthreads();

    {   // PV + write
        const int ii = t >> 5, dkp = t & 31;
        float o0 = 0.f, o1 = 0.f;
        const uint* vbase = (const uint*)vw + (size_t)((bg * H_ + h) * N_) * (DK_ / 2) + dkp;
        for (int j = 0; j < N_; ++j) {
            const uint u = vbase[(size_t)j * (DK_ / 2)];
            const float p = lg[ii][j];
            o0 += p * blo(u);
            o1 += p * bhi(u);
        }
        const float inv = 1.0f / rsum[ii];
        const uint pk = (uint)f2bf(o0 * inv) | ((uint)f2bf(o1 * inv) << 16);
        ((uint*)att)[(size_t)(bg * N_ + i0 + ii) * (D_ / 2) + h * 32 + dkp] = pk;
    }
}

// ================= tier-3 fallback (round-3 proven kernels) =================
__global__ __launch_bounds__(256) void gemm16(const void* __restrict__ A,
                                              const void* __restrict__ W,
                                              const void* __restrict__ bias,
                                              void* __restrict__ out,
                                              const int* __restrict__ flagp,
                                              int a_follows, int mode) {
    const int isbf = *flagp;
    const int a_isbf = a_follows ? isbf : 1;
    const int wave = threadIdx.x >> 6;
    const int tile = blockIdx.x * 4 + wave;
    const int tm = tile >> 5, tn = tile & 31;
    const int row0 = tm * 16, col0 = tn * 16;
    const int lane = threadIdx.x & 63;
    const int m = lane & 15, quad = lane >> 4;
    floatx4 acc = {0.f, 0.f, 0.f, 0.f};
    const size_t abase = (size_t)(row0 + m) * D_ + quad * 8;
    const size_t wbase = (size_t)(quad * 8) * D_ + col0 + m;
    for (int k0 = 0; k0 < D_; k0 += 32) {
        short8 af, bf;
#pragma unroll
        for (int j = 0; j < 8; ++j) af[j] = ldb(A, abase + k0 + j, a_isbf);
#pragma unroll
        for (int j = 0; j < 8; ++j) bf[j] = ldb(W, wbase + (size_t)(k0 + j) * D_, isbf);
        acc = __builtin_amdgcn_mfma_f32_16x16x32_bf16(af, bf, acc, 0, 0, 0);
    }
    const int col = col0 + m;
    const float bi = ldf(bias, col, isbf);
#pragma unroll
    for (int r = 0; r < 4; ++r) {
        const int row = row0 + quad * 4 + r;
        const float v = acc[r] + bi;
        if (mode == 1) {
            ((ushort*)out)[(size_t)(((row >> 9) * H_ + (col >> 6)) * N_ + (row & 511)) * DK_ + (col & 63)] = f2bf(v);
        } else if (isbf) {
            ((ushort*)out)[(size_t)row * D_ + col] = f2bf(v);
        } else {
            ((float*)out)[(size_t)row * D_ + col] = v;
        }
    }
}

__global__ __launch_bounds__(256) void attn_old(
    const ushort* __restrict__ qw, const ushort* __restrict__ kw,
    const ushort* __restrict__ vw, const void* __restrict__ box,
    const int* __restrict__ mask, const int* __restrict__ nobj,
    const void* __restrict__ WG, const void* __restrict__ bG,
    ushort* __restrict__ att, const int* __restrict__ flagp) {
    const int isbf = *flagp;
    const int b = blockIdx.z, h = blockIdx.y;
    const int i0 = blockIdx.x * 8;
    const int t = threadIdx.x;
    __shared__ float lg[8][520];
    __shared__ float q_s[8][68];
    __shared__ float wgh[64];
    __shared__ float cxi[8], cyi[8], rwi[8], rhi[8], lwi[8], lhi[8];
    __shared__ int noi[8];
    __shared__ float rsum[8];
    for (int e = t; e < 512; e += 256) {
        const int ii = e >> 6, dk = e & 63;
        q_s[ii][dk] = bf2f(qw[(size_t)((b * H_ + h) * N_ + i0 + ii) * DK_ + dk]) * 0.125f;
    }
    if (t < 64) wgh[t] = ldf(WG, h * 64 + t, isbf);
    if (t < 8) {
        const size_t bb = (size_t)(b * N_ + i0 + t) * 4;
        const float xmn = ldf(box, bb + 0, isbf), ymn = ldf(box, bb + 1, isbf);
        const float xmx = ldf(box, bb + 2, isbf), ymx = ldf(box, bb + 3, isbf);
        const float w = xmx - xmn + 1.0f, hh = ymx - ymn + 1.0f;
        cxi[t] = (xmn + xmx) * 0.5f;
        cyi[t] = (ymn + ymx) * 0.5f;
        rwi[t] = 1.0f / w;
        rhi[t] = 1.0f / hh;
        lwi[t] = __logf(w);
        lhi[t] = __logf(hh);
        noi[t] = nobj[b * N_ + i0 + t];
    }
    const float bg = ldf(bG, h, isbf);
    __syncthreads();
    for (int jl = 0; jl < 2; ++jl) {
        const int j = t + jl * 256;
        float acc[8];
#pragma unroll
        for (int ii = 0; ii < 8; ++ii) acc[ii] = 0.f;
        const uint4* krow = (const uint4*)(kw + (size_t)((b * H_ + h) * N_ + j) * DK_);
#pragma unroll
        for (int c = 0; c < 8; ++c) {
            const uint4 ku = krow[c];
            float kf[8];
            kf[0] = blo(ku.x); kf[1] = bhi(ku.x); kf[2] = blo(ku.y); kf[3] = bhi(ku.y);
            kf[4] = blo(ku.z); kf[5] = bhi(ku.z); kf[6] = blo(ku.w); kf[7] = bhi(ku.w);
#pragma unroll
            for (int ii = 0; ii < 8; ++ii) {
                const float4 qa = *(const float4*)(&q_s[ii][c * 8]);
                const float4 qb = *(const float4*)(&q_s[ii][c * 8 + 4]);
                acc[ii] += qa.x * kf[0] + qa.y * kf[1] + qa.z * kf[2] + qa.w * kf[3] +
                           qb.x * kf[4] + qb.y * kf[5] + qb.z * kf[6] + qb.w * kf[7];
            }
        }
        const int mj = mask[b * N_ + j];
        const size_t bb = (size_t)(b * N_ + j) * 4;
        const float xmn = ldf(box, bb + 0, isbf), ymn = ldf(box, bb + 1, isbf);
        const float xmx = ldf(box, bb + 2, isbf), ymx = ldf(box, bb + 3, isbf);
        const float cxj = (xmn + xmx) * 0.5f, cyj = (ymn + ymx) * 0.5f;
        const float wj = xmx - xmn + 1.0f, hj = ymx - ymn + 1.0f;
        const float lwj = __logf(wj), lhj = __logf(hj);
        const int noj = nobj[b * N_ + j];
        const float dm[8] = {1.0f, 0.421696503f, 0.177827941f, 0.074989421f,
                             0.031622777f, 0.013335214f, 0.005623413f, 0.002371374f};
        for (int ii = 0; ii < 8; ++ii) {
            const float mobj = (noi[ii] || noj) ? 0.f : 1.f;
            const float dx = __logf(fmaxf(fabsf((cxi[ii] - cxj) * rwi[ii]), 0.001f));
            const float dy = __logf(fmaxf(fabsf((cyi[ii] - cyj) * rhi[ii]), 0.001f));
            const float pos[4] = {dx, dy, lwi[ii] - lwj, lhi[ii] - lhj};
            float wg = bg;
            for (int p = 0; p < 4; ++p) {
                const float base = 100.f * pos[p];
#pragma unroll
                for (int f = 0; f < 8; ++f) {
                    float sv, cv;
                    __sincosf(base * dm[f], &sv, &cv);
                    const int g = p * 8 + f;
                    wg += sv * wgh[g] + cv * wgh[32 + g];
                }
            }
            lg[ii][j] = (mj ? acc[ii] : -1e9f) + __logf(fmaxf(wg, 1e-6f)) * mobj;
        }
    }
    __syncthreads();
    {
        const int rr = t >> 5, l32 = t & 31;
        float mx = -3e38f;
        for (int j = l32; j < N_; j += 32) mx = fmaxf(mx, lg[rr][j]);
#pragma unroll
        for (int d = 1; d < 32; d <<= 1) mx = fmaxf(mx, __shfl_xor(mx, d, 32));
        float sm = 0.f;
        for (int j = l32; j < N_; j += 32) {
            const float p = __expf(lg[rr][j] - mx);
            lg[rr][j] = p;
            sm += p;
        }
#pragma unroll
        for (int d = 1; d < 32; d <<= 1) sm += __shfl_xor(sm, d, 32);
        if (l32 == 0) rsum[rr] = sm;
    }
    __syncthreads();
    {
        const int ii = t >> 5, dkp = t & 31;
        float o0 = 0.f, o1 = 0.f;
        const uint* vbase = (const uint*)vw + (size_t)((b * H_ + h) * N_) * (DK_ / 2) + dkp;
        for (int j = 0; j < N_; ++j) {
            const uint u = vbase[(size_t)j * (DK_ / 2)];
            const float p = lg[ii][j];
            o0 += p * blo(u);
            o1 += p * bhi(u);
        }
        const float inv = 1.0f / rsum[ii];
        const uint pk = (uint)f2bf(o0 * inv) | ((uint)f2bf(o1 * inv) << 16);
        ((uint*)att)[(size_t)(b * N_ + i0 + ii) * (D_ / 2) + h * 32 + dkp] = pk;
    }
}

extern "C" void kernel_launch(void* const* d_in, const int* in_sizes, int n_in,
                              void* d_out, int out_size, void* d_ws, size_t ws_size,
                              hipStream_t stream) {
    const void* xq = d_in[0];
    const void* xk = d_in[1];
    const void* xv = d_in[2];
    const void* box = d_in[3];
    const int* mask = (const int*)d_in[4];
    const int* nobj = (const int*)d_in[5];
    const void* Wq = d_in[6];
    const void* bq = d_in[7];
    const void* Wk = d_in[8];
    const void* bk = d_in[9];
    const void* Wv = d_in[10];
    const void* bv = d_in[11];
    const void* Wo = d_in[12];
    const void* bo = d_in[13];
    const void* WG = d_in[14];
    const void* bG = d_in[15];

    char* ws = (char*)d_ws;
    const size_t MB = 1u << 20;

    if (ws_size >= 54 * MB || (ws_size >= 24 * MB)) {
        const int nb = (ws_size >= 54 * MB) ? B_ : 1;   // tier1 : tier2
        int* flag = (int*)ws;
        float* biasf = (float*)(ws + 4096);
        ushort* wt = (ushort*)(ws + 16384);
        size_t p = 16384 + 2097152;
        ushort* qw = (ushort*)(ws + p); p += 4194304;
        ushort* kw = (ushort*)(ws + p); p += 4194304;
        ushort* vw = (ushort*)(ws + p); p += 4194304;
        ushort* att = (ushort*)(ws + p); p += 4194304;
        ushort* glog = (ushort*)(ws + p);

        hipLaunchKernelGGL(probe_dtype, dim3(1), dim3(256), 0, stream, (const uint*)xq, flag);
        hipLaunchKernelGGL(prep_bias, dim3(8), dim3(256), 0, stream, bq, bk, bv, bo, biasf, flag);
        hipLaunchKernelGGL(transw, dim3(16, 16, 4), dim3(256), 0, stream, Wq, Wk, Wv, Wo, wt, flag);
        hipLaunchKernelGGL((gemm_mfma<float, 0>), dim3(32, 8, 3), dim3(256), 0, stream,
                           (const float*)xq, (const float*)xk, (const float*)xv,
                           wt, biasf, qw, kw, vw, (void*)nullptr, flag, 0);
        hipLaunchKernelGGL((gemm_mfma<ushort, 0>), dim3(32, 8, 3), dim3(256), 0, stream,
                           (const ushort*)xq, (const ushort*)xk, (const ushort*)xv,
                           wt, biasf, qw, kw, vw, (void*)nullptr, flag, 1);
        if (nb == B_) {
            hipLaunchKernelGGL(geom, dim3(N_, B_), dim3(256), 0, stream,
                               box, nobj, WG, bG, glog, flag, 0);
            hipLaunchKernelGGL(attn2, dim3(N_ / 8, H_, B_), dim3(256), 0, stream,
                               qw, kw, vw, mask, glog, att, 0);
        } else {
            for (int b = 0; b < B_; ++b) {
                hipLaunchKernelGGL(geom, dim3(N_, 1), dim3(256), 0, stream,
                                   box, nobj, WG, bG, glog, flag, b);
                hipLaunchKernelGGL(attn2, dim3(N_ / 8, H_, 1), dim3(256), 0, stream,
                                   qw, kw, vw, mask, glog, att, b);
            }
        }
        hipLaunchKernelGGL((gemm_mfma<ushort, 1>), dim3(32, 8), dim3(256), 0, stream,
                           att, att, att, wt, biasf, qw, kw, vw, d_out, flag, -1);
    } else {
        // tier-3 fallback: proven round-3 path (needs ~16.6 MB)
        int* flag = (int*)ws;
        ushort* qw = (ushort*)(ws + 256);
        ushort* kw = (ushort*)(ws + 256 + 4194304);
        ushort* vw = (ushort*)(ws + 256 + 8388608);
        ushort* att = (ushort*)(ws + 256 + 12582912);
        hipLaunchKernelGGL(probe_dtype, dim3(1), dim3(256), 0, stream, (const uint*)xq, flag);
        hipLaunchKernelGGL(gemm16, dim3(2048), dim3(256), 0, stream, xq, Wq, bq, (void*)qw, flag, 1, 1);
        hipLaunchKernelGGL(gemm16, dim3(2048), dim3(256), 0, stream, xk, Wk, bk, (void*)kw, flag, 1, 1);
        hipLaunchKernelGGL(gemm16, dim3(2048), dim3(256), 0, stream, xv, Wv, bv, (void*)vw, flag, 1, 1);
        hipLaunchKernelGGL(attn_old, dim3(N_ / 8, H_, B_), dim3(256), 0, stream,
                           qw, kw, vw, box, mask, nobj, WG, bG, att, flag);
        hipLaunchKernelGGL(gemm16, dim3(2048), dim3(256), 0, stream, att, Wo, bo, d_out, flag, 0, 2);
    }
}

// Round 5
// 309.489 us; speedup vs baseline: 4.6564x; 2.4891x over previous
//
#include <hip/hip_runtime.h>
#include <hip/hip_fp16.h>

#define B_ 8
#define N_ 512
#define D_ 512
#define H_ 8
#define DK_ 64

typedef unsigned int uint;
typedef unsigned short ushort;
typedef __attribute__((ext_vector_type(8))) short short8;
typedef __attribute__((ext_vector_type(4))) float floatx4;

__device__ __forceinline__ float bf2f(ushort s) { return __uint_as_float(((uint)s) << 16); }
__device__ __forceinline__ ushort f2bf(float f) {
    uint x = __float_as_uint(f);
    return (ushort)((x + 0x7fffu + ((x >> 16) & 1u)) >> 16);
}
__device__ __forceinline__ float blo(uint u) { return __uint_as_float(u << 16); }
__device__ __forceinline__ float bhi(uint u) { return __uint_as_float(u & 0xffff0000u); }
__device__ __forceinline__ float ldf(const void* p, size_t i, int isbf) {
    return isbf ? bf2f(((const ushort*)p)[i]) : ((const float*)p)[i];
}
__device__ __forceinline__ short ldb(const void* p, size_t i, int isbf) {
    return isbf ? (short)(((const ushort*)p)[i]) : (short)f2bf(((const float*)p)[i]);
}

// ---------------- dtype probe (proven) ----------------
__global__ __launch_bounds__(256) void probe_dtype(const uint* __restrict__ q,
                                                   int* __restrict__ flag) {
    __shared__ int s[256];
    const int t = threadIdx.x;
    int cnt = 0;
    for (int i = t; i < 4096; i += 256) {
        const uint e = (q[i] >> 7) & 0xffu;
        cnt += (e >= 0x70u && e <= 0x84u) ? 1 : 0;
    }
    s[t] = cnt;
    __syncthreads();
    for (int d = 128; d > 0; d >>= 1) {
        if (t < d) s[t] += s[t + d];
        __syncthreads();
    }
    if (t == 0) *flag = (s[0] > 3276) ? 1 : 0;
}

// ---------------- bias convert ----------------
__global__ __launch_bounds__(256) void prep_bias(const void* __restrict__ b0,
                                                 const void* __restrict__ b1,
                                                 const void* __restrict__ b2,
                                                 const void* __restrict__ b3,
                                                 float* __restrict__ biasf,
                                                 const int* __restrict__ flagp) {
    const int isbf = *flagp;
    const int e = blockIdx.x * 256 + threadIdx.x;
    const int z = e >> 9;
    const void* src = (z == 0) ? b0 : (z == 1) ? b1 : (z == 2) ? b2 : b3;
    biasf[e] = ldf(src, e & 511, isbf);
}

// ---------------- W transpose -> Wt[n][k] bf16 ----------------
__global__ __launch_bounds__(256) void transw(const void* __restrict__ w0,
                                              const void* __restrict__ w1,
                                              const void* __restrict__ w2,
                                              const void* __restrict__ w3,
                                              ushort* __restrict__ wt,
                                              const int* __restrict__ flagp) {
    const int isbf = *flagp;
    const int z = blockIdx.z;
    const void* W = (z == 0) ? w0 : (z == 1) ? w1 : (z == 2) ? w2 : w3;
    const int n0 = blockIdx.x * 32, k0 = blockIdx.y * 32;
    __shared__ float tile[32][33];
    const int tx = threadIdx.x & 31, ty = threadIdx.x >> 5;
#pragma unroll
    for (int r = 0; r < 4; ++r)
        tile[ty + 8 * r][tx] = ldf(W, (size_t)(k0 + ty + 8 * r) * D_ + n0 + tx, isbf);
    __syncthreads();
#pragma unroll
    for (int r = 0; r < 4; ++r)
        wt[(size_t)z * 262144 + (size_t)(n0 + ty + 8 * r) * D_ + k0 + tx] =
            f2bf(tile[tx][ty + 8 * r]);
}

// ---------------- MFMA GEMM ----------------
// MODE 0: z=blockIdx.z in {0,1,2}=Q,K,V. Q,K -> [B,H,N,DK] bf16; V -> vt [B,H,DK,N] bf16.
// MODE 1: out = dout flat [4096,512], dtype per flag.
template <typename AT, int MODE>
__global__ __launch_bounds__(256) void gemm_mfma(
    const AT* __restrict__ A0, const AT* __restrict__ A1, const AT* __restrict__ A2,
    const ushort* __restrict__ wt, const float* __restrict__ biasf,
    ushort* __restrict__ oq, ushort* __restrict__ ok, ushort* __restrict__ ov,
    void* __restrict__ dout, const int* __restrict__ flagp, int want) {
    if (want >= 0 && *flagp != want) return;
    const int z = (MODE == 0) ? blockIdx.z : 3;
    const AT* A = (MODE == 0) ? ((z == 0) ? A0 : (z == 1) ? A1 : A2) : A0;
    const ushort* W = wt + (size_t)z * 262144;
    const float* bias = biasf + z * 512;
    const int row0 = blockIdx.x * 128, col0 = blockIdx.y * 64;
    const int t = threadIdx.x, wv = t >> 6, lane = t & 63;
    const int m16 = lane & 15, quad = lane >> 4;

    __shared__ ushort As[128][40];
    __shared__ ushort Ws[64][40];
    floatx4 acc[2][4] = {};

    const int ar = t >> 1, ah = t & 1;
    const int wr = t >> 2, wc = (t & 3) * 8;

    for (int k0 = 0; k0 < D_; k0 += 32) {
        __syncthreads();
        {
            const AT* ap = A + (size_t)(row0 + ar) * D_ + k0 + ah * 16;
            short8 s0, s1;
            if constexpr (sizeof(AT) == 4) {
                const float4 f0 = *(const float4*)(ap);
                const float4 f1 = *(const float4*)(ap + 4);
                const float4 f2 = *(const float4*)(ap + 8);
                const float4 f3 = *(const float4*)(ap + 12);
                s0[0] = (short)f2bf(f0.x); s0[1] = (short)f2bf(f0.y);
                s0[2] = (short)f2bf(f0.z); s0[3] = (short)f2bf(f0.w);
                s0[4] = (short)f2bf(f1.x); s0[5] = (short)f2bf(f1.y);
                s0[6] = (short)f2bf(f1.z); s0[7] = (short)f2bf(f1.w);
                s1[0] = (short)f2bf(f2.x); s1[1] = (short)f2bf(f2.y);
                s1[2] = (short)f2bf(f2.z); s1[3] = (short)f2bf(f2.w);
                s1[4] = (short)f2bf(f3.x); s1[5] = (short)f2bf(f3.y);
                s1[6] = (short)f2bf(f3.z); s1[7] = (short)f2bf(f3.w);
            } else {
                s0 = *(const short8*)(ap);
                s1 = *(const short8*)(ap + 8);
            }
            *(short8*)&As[ar][ah * 16] = s0;
            *(short8*)&As[ar][ah * 16 + 8] = s1;
        }
        *(short8*)&Ws[wr][wc] =
            *(const short8*)(W + (size_t)(col0 + wr) * D_ + k0 + wc);
        __syncthreads();

        const short8 a0 = *(const short8*)&As[wv * 32 + m16][quad * 8];
        const short8 a1 = *(const short8*)&As[wv * 32 + 16 + m16][quad * 8];
        const short8 b0 = *(const short8*)&Ws[m16][quad * 8];
        const short8 b1 = *(const short8*)&Ws[16 + m16][quad * 8];
        const short8 b2 = *(const short8*)&Ws[32 + m16][quad * 8];
        const short8 b3 = *(const short8*)&Ws[48 + m16][quad * 8];
        acc[0][0] = __builtin_amdgcn_mfma_f32_16x16x32_bf16(a0, b0, acc[0][0], 0, 0, 0);
        acc[0][1] = __builtin_amdgcn_mfma_f32_16x16x32_bf16(a0, b1, acc[0][1], 0, 0, 0);
        acc[0][2] = __builtin_amdgcn_mfma_f32_16x16x32_bf16(a0, b2, acc[0][2], 0, 0, 0);
        acc[0][3] = __builtin_amdgcn_mfma_f32_16x16x32_bf16(a0, b3, acc[0][3], 0, 0, 0);
        acc[1][0] = __builtin_amdgcn_mfma_f32_16x16x32_bf16(a1, b0, acc[1][0], 0, 0, 0);
        acc[1][1] = __builtin_amdgcn_mfma_f32_16x16x32_bf16(a1, b1, acc[1][1], 0, 0, 0);
        acc[1][2] = __builtin_amdgcn_mfma_f32_16x16x32_bf16(a1, b2, acc[1][2], 0, 0, 0);
        acc[1][3] = __builtin_amdgcn_mfma_f32_16x16x32_bf16(a1, b3, acc[1][3], 0, 0, 0);
    }

    const int isbf = *flagp;
#pragma unroll
    for (int mt = 0; mt < 2; ++mt) {
#pragma unroll
        for (int nt = 0; nt < 4; ++nt) {
            const int colg = col0 + nt * 16 + m16;
            const float bi = bias[colg];
            float v0 = acc[mt][nt][0] + bi, v1 = acc[mt][nt][1] + bi;
            float v2 = acc[mt][nt][2] + bi, v3 = acc[mt][nt][3] + bi;
            const int rowb = row0 + wv * 32 + mt * 16 + quad * 4;
            if (MODE == 0) {
                if (z == 2) {
                    // vt[b,h,dk,j], rows rowb..rowb+3 are 4 consecutive j -> uint2
                    const int bhv = (rowb >> 9) * H_ + (colg >> 6);
                    uint2 pk;
                    pk.x = (uint)f2bf(v0) | ((uint)f2bf(v1) << 16);
                    pk.y = (uint)f2bf(v2) | ((uint)f2bf(v3) << 16);
                    *(uint2*)(ov + ((size_t)bhv * DK_ + (colg & 63)) * N_ + (rowb & 511)) = pk;
                } else {
                    ushort* o = (z == 0) ? oq : ok;
                    const float vv[4] = {v0, v1, v2, v3};
#pragma unroll
                    for (int r = 0; r < 4; ++r) {
                        const int row = rowb + r;
                        o[((size_t)((row >> 9) * H_ + (colg >> 6)) * N_ + (row & 511)) * DK_ +
                          (colg & 63)] = f2bf(vv[r]);
                    }
                }
            } else {
                const float vv[4] = {v0, v1, v2, v3};
#pragma unroll
                for (int r = 0; r < 4; ++r) {
                    const int row = rowb + r;
                    if (isbf) ((ushort*)dout)[(size_t)row * D_ + colg] = f2bf(vv[r]);
                    else      ((float*)dout)[(size_t)row * D_ + colg] = vv[r];
                }
            }
        }
    }
}

// ---------------- geometry log-bias, all heads ----------------
// glog layout: [bl][it(32)][h(8)][ii(16)][j(512)] fp16 -> contiguous 16KB per attn tile
__global__ __launch_bounds__(256) void geom(const void* __restrict__ box,
                                            const int* __restrict__ nobj,
                                            const void* __restrict__ WG,
                                            const void* __restrict__ bG,
                                            ushort* __restrict__ glog,
                                            const int* __restrict__ flagp, int b0) {
    const int isbf = *flagp;
    const int i = blockIdx.x, bl = blockIdx.y, bg = b0 + bl;
    const int t = threadIdx.x;
    __shared__ float wgs[512];   // wgs[g*8+h] = WG[h][g]
    __shared__ float bgs[8];
    for (int e = t; e < 512; e += 256) wgs[e] = ldf(WG, (size_t)(e & 7) * 64 + (e >> 3), isbf);
    if (t < 8) bgs[t] = ldf(bG, t, isbf);

    const size_t ib = (size_t)(bg * N_ + i) * 4;
    const float ixn = ldf(box, ib + 0, isbf), iyn = ldf(box, ib + 1, isbf);
    const float ixx = ldf(box, ib + 2, isbf), iyx = ldf(box, ib + 3, isbf);
    const float wi = ixx - ixn + 1.0f, hi = iyx - iyn + 1.0f;
    const float cxi = (ixn + ixx) * 0.5f, cyi = (iyn + iyx) * 0.5f;
    const float rwi = 1.0f / wi, rhi = 1.0f / hi;
    const float lwi = __logf(wi), lhi = __logf(hi);
    const int noi = nobj[bg * N_ + i];
    __syncthreads();

    const float dm[8] = {1.0f, 0.421696503f, 0.177827941f, 0.074989421f,
                         0.031622777f, 0.013335214f, 0.005623413f, 0.002371374f};
    for (int jl = 0; jl < 2; ++jl) {
        const int j = t + jl * 256;
        const size_t jb = (size_t)(bg * N_ + j) * 4;
        const float jxn = ldf(box, jb + 0, isbf), jyn = ldf(box, jb + 1, isbf);
        const float jxx = ldf(box, jb + 2, isbf), jyx = ldf(box, jb + 3, isbf);
        const float wj = jxx - jxn + 1.0f, hj = jyx - jyn + 1.0f;
        const float cxj = (jxn + jxx) * 0.5f, cyj = (jyn + jyx) * 0.5f;
        const float mobj = (noi || nobj[bg * N_ + j]) ? 0.f : 1.f;
        const float dx = __logf(fmaxf(fabsf((cxi - cxj) * rwi), 0.001f));
        const float dy = __logf(fmaxf(fabsf((cyi - cyj) * rhi), 0.001f));
        const float pos[4] = {dx, dy, lwi - __logf(wj), lhi - __logf(hj)};
        float wg[8];
#pragma unroll
        for (int h = 0; h < 8; ++h) wg[h] = bgs[h];
#pragma unroll
        for (int p = 0; p < 4; ++p) {
            const float base = 100.f * pos[p];
#pragma unroll
            for (int f = 0; f < 8; ++f) {
                float sv, cv;
                __sincosf(base * dm[f], &sv, &cv);
                const int g = p * 8 + f;
                const float4 s0 = *(const float4*)&wgs[g * 8];
                const float4 s1 = *(const float4*)&wgs[g * 8 + 4];
                const float4 c0 = *(const float4*)&wgs[(32 + g) * 8];
                const float4 c1 = *(const float4*)&wgs[(32 + g) * 8 + 4];
                wg[0] += sv * s0.x + cv * c0.x;
                wg[1] += sv * s0.y + cv * c0.y;
                wg[2] += sv * s0.z + cv * c0.z;
                wg[3] += sv * s0.w + cv * c0.w;
                wg[4] += sv * s1.x + cv * c1.x;
                wg[5] += sv * s1.y + cv * c1.y;
                wg[6] += sv * s1.z + cv * c1.z;
                wg[7] += sv * s1.w + cv * c1.w;
            }
        }
        __half* gp = (__half*)glog + (((size_t)bl * 32 + (i >> 4)) * 128 + (i & 15)) * 512 + j;
#pragma unroll
        for (int h = 0; h < 8; ++h)
            gp[(size_t)h * 8192] = __float2half(__logf(fmaxf(wg[h], 1e-6f)) * mobj);
    }
}

// ---------------- MFMA attention ----------------
// Block = (i-tile 16 rows, h, b), 256 threads = 4 waves.
__global__ __launch_bounds__(256) void attn3(
    const ushort* __restrict__ qw, const ushort* __restrict__ kw,
    const ushort* __restrict__ vt, const int* __restrict__ mask,
    const ushort* __restrict__ glog, ushort* __restrict__ att, int b0) {
    const int it = blockIdx.x, h = blockIdx.y, bl = blockIdx.z;
    const int bg = b0 + bl;
    const int i0 = it * 16;
    const int t = threadIdx.x, wv = t >> 6, lane = t & 63;
    const int m16 = lane & 15, quad = lane >> 4;
    const size_t bh = (size_t)(bg * H_ + h);

    __shared__ float lg[16][516];        // logits
    __shared__ ushort sbuf[16 * 520];    // phase A: glog tile [16][512]; phase B+: P bf16 [16][520]
    __shared__ float rsumInv[16];

    // stage glog tile (contiguous 16 KB)
    {
        const uint4* src = (const uint4*)(glog + (((size_t)bl * 32 + it) * 8 + h) * 8192);
        uint4* dst = (uint4*)sbuf;
#pragma unroll
        for (int e = 0; e < 4; ++e) dst[t + 256 * e] = src[t + 256 * e];
    }
    // Q A-fragments (k=0..31, 32..63)
    const ushort* qrow = qw + (bh * N_ + i0 + m16) * DK_ + quad * 8;
    const short8 aq0 = *(const short8*)(qrow);
    const short8 aq1 = *(const short8*)(qrow + 32);
    __syncthreads();

    // QK^T: wave wv covers j-tiles wv*8 .. wv*8+7
#pragma unroll
    for (int tt = 0; tt < 8; ++tt) {
        const int j0 = wv * 128 + tt * 16;
        const ushort* krow = kw + (bh * N_ + j0 + m16) * DK_ + quad * 8;
        const short8 bk0 = *(const short8*)(krow);
        const short8 bk1 = *(const short8*)(krow + 32);
        floatx4 acc = {};
        acc = __builtin_amdgcn_mfma_f32_16x16x32_bf16(aq0, bk0, acc, 0, 0, 0);
        acc = __builtin_amdgcn_mfma_f32_16x16x32_bf16(aq1, bk1, acc, 0, 0, 0);
        const int mj = mask[bg * N_ + j0 + m16];
        const __half* gt = (const __half*)sbuf;
#pragma unroll
        for (int r = 0; r < 4; ++r) {
            const int i = quad * 4 + r;
            const float g = __half2float(gt[i * 512 + j0 + m16]);
            lg[i][j0 + m16] = (mj ? 0.125f * acc[r] : -1e9f) + g;
        }
    }
    __syncthreads();

    // softmax: 16 threads per row, 32 elems each (held in regs)
    {
        const int row = t >> 4, l = t & 15;
        float v[32];
        float mx = -3e38f;
#pragma unroll
        for (int s = 0; s < 32; ++s) { v[s] = lg[row][l + 16 * s]; mx = fmaxf(mx, v[s]); }
#pragma unroll
        for (int d = 1; d < 16; d <<= 1) mx = fmaxf(mx, __shfl_xor(mx, d, 16));
        float sm = 0.f;
#pragma unroll
        for (int s = 0; s < 32; ++s) { const float p = __expf(v[s] - mx); sm += p; v[s] = p; }
#pragma unroll
        for (int d = 1; d < 16; d <<= 1) sm += __shfl_xor(sm, d, 16);
#pragma unroll
        for (int s = 0; s < 32; ++s) sbuf[row * 520 + l + 16 * s] = f2bf(v[s]);
        if (l == 0) rsumInv[row] = 1.0f / sm;
    }
    __syncthreads();

    // PV: wave wv -> dk columns wv*16 .. wv*16+15; K-dim = 512 in 16 chunks of 32
    {
        const int dk0 = wv * 16;
        const ushort* vrow = vt + (bh * DK_ + dk0 + m16) * N_ + quad * 8;
        floatx4 oc = {};
#pragma unroll
        for (int kc = 0; kc < 16; ++kc) {
            const short8 ap = *(const short8*)(sbuf + m16 * 520 + kc * 32 + quad * 8);
            const short8 bv = *(const short8*)(vrow + kc * 32);
            oc = __builtin_amdgcn_mfma_f32_16x16x32_bf16(ap, bv, oc, 0, 0, 0);
        }
#pragma unroll
        for (int r = 0; r < 4; ++r) {
            const int i = quad * 4 + r;
            const float o = oc[r] * rsumInv[i];
            att[((size_t)(bg * N_ + i0 + i)) * D_ + h * DK_ + dk0 + m16] = f2bf(o);
        }
    }
}

// ================= tier-3 fallback (round-3 proven) =================
__global__ __launch_bounds__(256) void gemm16(const void* __restrict__ A,
                                              const void* __restrict__ W,
                                              const void* __restrict__ bias,
                                              void* __restrict__ out,
                                              const int* __restrict__ flagp,
                                              int a_follows, int mode) {
    const int isbf = *flagp;
    const int a_isbf = a_follows ? isbf : 1;
    const int wave = threadIdx.x >> 6;
    const int tile = blockIdx.x * 4 + wave;
    const int tm = tile >> 5, tn = tile & 31;
    const int row0 = tm * 16, col0 = tn * 16;
    const int lane = threadIdx.x & 63;
    const int m = lane & 15, quad = lane >> 4;
    floatx4 acc = {0.f, 0.f, 0.f, 0.f};
    const size_t abase = (size_t)(row0 + m) * D_ + quad * 8;
    const size_t wbase = (size_t)(quad * 8) * D_ + col0 + m;
    for (int k0 = 0; k0 < D_; k0 += 32) {
        short8 af, bf;
#pragma unroll
        for (int j = 0; j < 8; ++j) af[j] = ldb(A, abase + k0 + j, a_isbf);
#pragma unroll
        for (int j = 0; j < 8; ++j) bf[j] = ldb(W, wbase + (size_t)(k0 + j) * D_, isbf);
        acc = __builtin_amdgcn_mfma_f32_16x16x32_bf16(af, bf, acc, 0, 0, 0);
    }
    const int col = col0 + m;
    const float bi = ldf(bias, col, isbf);
#pragma unroll
    for (int r = 0; r < 4; ++r) {
        const int row = row0 + quad * 4 + r;
        const float v = acc[r] + bi;
        if (mode == 1) {
            ((ushort*)out)[(size_t)(((row >> 9) * H_ + (col >> 6)) * N_ + (row & 511)) * DK_ + (col & 63)] = f2bf(v);
        } else if (isbf) {
            ((ushort*)out)[(size_t)row * D_ + col] = f2bf(v);
        } else {
            ((float*)out)[(size_t)row * D_ + col] = v;
        }
    }
}

__global__ __launch_bounds__(256) void attn_old(
    const ushort* __restrict__ qw, const ushort* __restrict__ kw,
    const ushort* __restrict__ vw, const void* __restrict__ box,
    const int* __restrict__ mask, const int* __restrict__ nobj,
    const void* __restrict__ WG, const void* __restrict__ bG,
    ushort* __restrict__ att, const int* __restrict__ flagp) {
    const int isbf = *flagp;
    const int b = blockIdx.z, h = blockIdx.y;
    const int i0 = blockIdx.x * 8;
    const int t = threadIdx.x;
    __shared__ float lg[8][520];
    __shared__ float q_s[8][68];
    __shared__ float wgh[64];
    __shared__ float cxi[8], cyi[8], rwi[8], rhi[8], lwi[8], lhi[8];
    __shared__ int noi[8];
    __shared__ float rsum[8];
    for (int e = t; e < 512; e += 256) {
        const int ii = e >> 6, dk = e & 63;
        q_s[ii][dk] = bf2f(qw[(size_t)((b * H_ + h) * N_ + i0 + ii) * DK_ + dk]) * 0.125f;
    }
    if (t < 64) wgh[t] = ldf(WG, h * 64 + t, isbf);
    if (t < 8) {
        const size_t bb = (size_t)(b * N_ + i0 + t) * 4;
        const float xmn = ldf(box, bb + 0, isbf), ymn = ldf(box, bb + 1, isbf);
        const float xmx = ldf(box, bb + 2, isbf), ymx = ldf(box, bb + 3, isbf);
        const float w = xmx - xmn + 1.0f, hh = ymx - ymn + 1.0f;
        cxi[t] = (xmn + xmx) * 0.5f;
        cyi[t] = (ymn + ymx) * 0.5f;
        rwi[t] = 1.0f / w;
        rhi[t] = 1.0f / hh;
        lwi[t] = __logf(w);
        lhi[t] = __logf(hh);
        noi[t] = nobj[b * N_ + i0 + t];
    }
    const float bg = ldf(bG, h, isbf);
    __syncthreads();
    for (int jl = 0; jl < 2; ++jl) {
        const int j = t + jl * 256;
        float acc[8];
#pragma unroll
        for (int ii = 0; ii < 8; ++ii) acc[ii] = 0.f;
        const uint4* krow = (const uint4*)(kw + (size_t)((b * H_ + h) * N_ + j) * DK_);
#pragma unroll
        for (int c = 0; c < 8; ++c) {
            const uint4 ku = krow[c];
            float kf[8];
            kf[0] = blo(ku.x); kf[1] = bhi(ku.x); kf[2] = blo(ku.y); kf[3] = bhi(ku.y);
            kf[4] = blo(ku.z); kf[5] = bhi(ku.z); kf[6] = blo(ku.w); kf[7] = bhi(ku.w);
#pragma unroll
            for (int ii = 0; ii < 8; ++ii) {
                const float4 qa = *(const float4*)(&q_s[ii][c * 8]);
                const float4 qb = *(const float4*)(&q_s[ii][c * 8 + 4]);
                acc[ii] += qa.x * kf[0] + qa.y * kf[1] + qa.z * kf[2] + qa.w * kf[3] +
                           qb.x * kf[4] + qb.y * kf[5] + qb.z * kf[6] + qb.w * kf[7];
            }
        }
        const int mj = mask[b * N_ + j];
        const size_t bb = (size_t)(b * N_ + j) * 4;
        const float xmn = ldf(box, bb + 0, isbf), ymn = ldf(box, bb + 1, isbf);
        const float xmx = ldf(box, bb + 2, isbf), ymx = ldf(box, bb + 3, isbf);
        const float cxj = (xmn + xmx) * 0.5f, cyj = (ymn + ymx) * 0.5f;
        const float wj = xmx - xmn + 1.0f, hj = ymx - ymn + 1.0f;
        const float lwj = __logf(wj), lhj = __logf(hj);
        const int noj = nobj[b * N_ + j];
        const float dm[8] = {1.0f, 0.421696503f, 0.177827941f, 0.074989421f,
                             0.031622777f, 0.013335214f, 0.005623413f, 0.002371374f};
        for (int ii = 0; ii < 8; ++ii) {
            const float mobj = (noi[ii] || noj) ? 0.f : 1.f;
            const float dx = __logf(fmaxf(fabsf((cxi[ii] - cxj) * rwi[ii]), 0.001f));
            const float dy = __logf(fmaxf(fabsf((cyi[ii] - cyj) * rhi[ii]), 0.001f));
            const float pos[4] = {dx, dy, lwi[ii] - lwj, lhi[ii] - lhj};
            float wg = bg;
            for (int p = 0; p < 4; ++p) {
                const float base = 100.f * pos[p];
#pragma unroll
                for (int f = 0; f < 8; ++f) {
                    float sv, cv;
                    __sincosf(base * dm[f], &sv, &cv);
                    const int g = p * 8 + f;
                    wg += sv * wgh[g] + cv * wgh[32 + g];
                }
            }
            lg[ii][j] = (mj ? acc[ii] : -1e9f) + __logf(fmaxf(wg, 1e-6f)) * mobj;
        }
    }
    __syncthreads();
    {
        const int rr = t >> 5, l32 = t & 31;
        float mx = -3e38f;
        for (int j = l32; j < N_; j += 32) mx = fmaxf(mx, lg[rr][j]);
#pragma unroll
        for (int d = 1; d < 32; d <<= 1) mx = fmaxf(mx, __shfl_xor(mx, d, 32));
        float sm = 0.f;
        for (int j = l32; j < N_; j += 32) {
            const float p = __expf(lg[rr][j] - mx);
            lg[rr][j] = p;
            sm += p;
        }
#pragma unroll
        for (int d = 1; d < 32; d <<= 1) sm += __shfl_xor(sm, d, 32);
        if (l32 == 0) rsum[rr] = sm;
    }
    __syncthreads();
    {
        const int ii = t >> 5, dkp = t & 31;
        float o0 = 0.f, o1 = 0.f;
        const uint* vbase = (const uint*)vw + (size_t)((b * H_ + h) * N_) * (DK_ / 2) + dkp;
        for (int j = 0; j < N_; ++j) {
            const uint u = vbase[(size_t)j * (DK_ / 2)];
            const float p = lg[ii][j];
            o0 += p * blo(u);
            o1 += p * bhi(u);
        }
        const float inv = 1.0f / rsum[ii];
        const uint pk = (uint)f2bf(o0 * inv) | ((uint)f2bf(o1 * inv) << 16);
        ((uint*)att)[(size_t)(b * N_ + i0 + ii) * (D_ / 2) + h * 32 + dkp] = pk;
    }
}

extern "C" void kernel_launch(void* const* d_in, const int* in_sizes, int n_in,
                              void* d_out, int out_size, void* d_ws, size_t ws_size,
                              hipStream_t stream) {
    const void* xq = d_in[0];
    const void* xk = d_in[1];
    const void* xv = d_in[2];
    const void* box = d_in[3];
    const int* mask = (const int*)d_in[4];
    const int* nobj = (const int*)d_in[5];
    const void* Wq = d_in[6];
    const void* bq = d_in[7];
    const void* Wk = d_in[8];
    const void* bk = d_in[9];
    const void* Wv = d_in[10];
    const void* bv = d_in[11];
    const void* Wo = d_in[12];
    const void* bo = d_in[13];
    const void* WG = d_in[14];
    const void* bG = d_in[15];

    char* ws = (char*)d_ws;
    const size_t MB = 1u << 20;

    if (ws_size >= 54 * MB) {   // tier-1 (confirmed active in rounds 3-4)
        int* flag = (int*)ws;
        float* biasf = (float*)(ws + 4096);
        ushort* wt = (ushort*)(ws + 16384);
        size_t p = 16384 + 2097152;
        ushort* qw = (ushort*)(ws + p); p += 4194304;
        ushort* kw = (ushort*)(ws + p); p += 4194304;
        ushort* vt = (ushort*)(ws + p); p += 4194304;
        ushort* att = (ushort*)(ws + p); p += 4194304;
        ushort* glog = (ushort*)(ws + p);   // 32 MB: [bl][it][h][16][512] fp16

        hipLaunchKernelGGL(probe_dtype, dim3(1), dim3(256), 0, stream, (const uint*)xq, flag);
        hipLaunchKernelGGL(prep_bias, dim3(8), dim3(256), 0, stream, bq, bk, bv, bo, biasf, flag);
        hipLaunchKernelGGL(transw, dim3(16, 16, 4), dim3(256), 0, stream, Wq, Wk, Wv, Wo, wt, flag);
        hipLaunchKernelGGL((gemm_mfma<float, 0>), dim3(32, 8, 3), dim3(256), 0, stream,
                           (const float*)xq, (const float*)xk, (const float*)xv,
                           wt, biasf, qw, kw, vt, (void*)nullptr, flag, 0);
        hipLaunchKernelGGL((gemm_mfma<ushort, 0>), dim3(32, 8, 3), dim3(256), 0, stream,
                           (const ushort*)xq, (const ushort*)xk, (const ushort*)xv,
                           wt, biasf, qw, kw, vt, (void*)nullptr, flag, 1);
        hipLaunchKernelGGL(geom, dim3(N_, B_), dim3(256), 0, stream,
                           box, nobj, WG, bG, glog, flag, 0);
        hipLaunchKernelGGL(attn3, dim3(32, H_, B_), dim3(256), 0, stream,
                           qw, kw, vt, mask, glog, att, 0);
        hipLaunchKernelGGL((gemm_mfma<ushort, 1>), dim3(32, 8), dim3(256), 0, stream,
                           att, att, att, wt, biasf, qw, kw, vt, d_out, flag, -1);
    } else {
        // tier-3 fallback (proven round-3 path, ~16.6 MB)
        int* flag = (int*)ws;
        ushort* qw = (ushort*)(ws + 256);
        ushort* kw = (ushort*)(ws + 256 + 4194304);
        ushort* vw = (ushort*)(ws + 256 + 8388608);
        ushort* att = (ushort*)(ws + 256 + 12582912);
        hipLaunchKernelGGL(probe_dtype, dim3(1), dim3(256), 0, stream, (const uint*)xq, flag);
        hipLaunchKernelGGL(gemm16, dim3(2048), dim3(256), 0, stream, xq, Wq, bq, (void*)qw, flag, 1, 1);
        hipLaunchKernelGGL(gemm16, dim3(2048), dim3(256), 0, stream, xk, Wk, bk, (void*)kw, flag, 1, 1);
        hipLaunchKernelGGL(gemm16, dim3(2048), dim3(256), 0, stream, xv, Wv, bv, (void*)vw, flag, 1, 1);
        hipLaunchKernelGGL(attn_old, dim3(N_ / 8, H_, B_), dim3(256), 0, stream,
                           qw, kw, vw, box, mask, nobj, WG, bG, att, flag);
        hipLaunchKernelGGL(gemm16, dim3(2048), dim3(256), 0, stream, att, Wo, bo, d_out, flag, 0, 2);
    }
}

// Round 6
// 218.430 us; speedup vs baseline: 6.5975x; 1.4169x over previous
//
#include <hip/hip_runtime.h>
#include <hip/hip_fp16.h>

#define B_ 8
#define N_ 512
#define D_ 512
#define H_ 8
#define DK_ 64

typedef unsigned int uint;
typedef unsigned short ushort;
typedef __attribute__((ext_vector_type(8))) short short8;
typedef __attribute__((ext_vector_type(8))) _Float16 half8;
typedef __attribute__((ext_vector_type(4))) float floatx4;

__device__ __forceinline__ float bf2f(ushort s) { return __uint_as_float(((uint)s) << 16); }
__device__ __forceinline__ ushort f2bf(float f) {
    uint x = __float_as_uint(f);
    return (ushort)((x + 0x7fffu + ((x >> 16) & 1u)) >> 16);
}
__device__ __forceinline__ float blo(uint u) { return __uint_as_float(u << 16); }
__device__ __forceinline__ float bhi(uint u) { return __uint_as_float(u & 0xffff0000u); }
__device__ __forceinline__ float ldf(const void* p, size_t i, int isbf) {
    return isbf ? bf2f(((const ushort*)p)[i]) : ((const float*)p)[i];
}
__device__ __forceinline__ short ldb(const void* p, size_t i, int isbf) {
    return isbf ? (short)(((const ushort*)p)[i]) : (short)f2bf(((const float*)p)[i]);
}

// ---------------- dtype probe (proven) ----------------
__global__ __launch_bounds__(256) void probe_dtype(const uint* __restrict__ q,
                                                   int* __restrict__ flag) {
    __shared__ int s[256];
    const int t = threadIdx.x;
    int cnt = 0;
    for (int i = t; i < 4096; i += 256) {
        const uint e = (q[i] >> 7) & 0xffu;
        cnt += (e >= 0x70u && e <= 0x84u) ? 1 : 0;
    }
    s[t] = cnt;
    __syncthreads();
    for (int d = 128; d > 0; d >>= 1) {
        if (t < d) s[t] += s[t + d];
        __syncthreads();
    }
    if (t == 0) *flag = (s[0] > 3276) ? 1 : 0;
}

// ---------------- bias convert ----------------
__global__ __launch_bounds__(256) void prep_bias(const void* __restrict__ b0,
                                                 const void* __restrict__ b1,
                                                 const void* __restrict__ b2,
                                                 const void* __restrict__ b3,
                                                 float* __restrict__ biasf,
                                                 const int* __restrict__ flagp) {
    const int isbf = *flagp;
    const int e = blockIdx.x * 256 + threadIdx.x;
    const int z = e >> 9;
    const void* src = (z == 0) ? b0 : (z == 1) ? b1 : (z == 2) ? b2 : b3;
    biasf[e] = ldf(src, e & 511, isbf);
}

// ---------------- W transpose -> Wt[n][k] bf16 ----------------
__global__ __launch_bounds__(256) void transw(const void* __restrict__ w0,
                                              const void* __restrict__ w1,
                                              const void* __restrict__ w2,
                                              const void* __restrict__ w3,
                                              ushort* __restrict__ wt,
                                              const int* __restrict__ flagp) {
    const int isbf = *flagp;
    const int z = blockIdx.z;
    const void* W = (z == 0) ? w0 : (z == 1) ? w1 : (z == 2) ? w2 : w3;
    const int n0 = blockIdx.x * 32, k0 = blockIdx.y * 32;
    __shared__ float tile[32][33];
    const int tx = threadIdx.x & 31, ty = threadIdx.x >> 5;
#pragma unroll
    for (int r = 0; r < 4; ++r)
        tile[ty + 8 * r][tx] = ldf(W, (size_t)(k0 + ty + 8 * r) * D_ + n0 + tx, isbf);
    __syncthreads();
#pragma unroll
    for (int r = 0; r < 4; ++r)
        wt[(size_t)z * 262144 + (size_t)(n0 + ty + 8 * r) * D_ + k0 + tx] =
            f2bf(tile[tx][ty + 8 * r]);
}

// ---------------- MFMA GEMM ----------------
// MODE 0: z=blockIdx.z in {0,1,2}=Q,K,V. Q,K -> [B,H,N,DK] bf16; V -> vt [B,H,DK,N] bf16.
// MODE 1: out = dout flat [4096,512], dtype per flag.
template <typename AT, int MODE>
__global__ __launch_bounds__(256) void gemm_mfma(
    const AT* __restrict__ A0, const AT* __restrict__ A1, const AT* __restrict__ A2,
    const ushort* __restrict__ wt, const float* __restrict__ biasf,
    ushort* __restrict__ oq, ushort* __restrict__ ok, ushort* __restrict__ ov,
    void* __restrict__ dout, const int* __restrict__ flagp, int want) {
    if (want >= 0 && *flagp != want) return;
    const int z = (MODE == 0) ? blockIdx.z : 3;
    const AT* A = (MODE == 0) ? ((z == 0) ? A0 : (z == 1) ? A1 : A2) : A0;
    const ushort* W = wt + (size_t)z * 262144;
    const float* bias = biasf + z * 512;
    const int row0 = blockIdx.x * 128, col0 = blockIdx.y * 64;
    const int t = threadIdx.x, wv = t >> 6, lane = t & 63;
    const int m16 = lane & 15, quad = lane >> 4;

    __shared__ ushort As[128][40];
    __shared__ ushort Ws[64][40];
    floatx4 acc[2][4] = {};

    const int ar = t >> 1, ah = t & 1;
    const int wr = t >> 2, wc = (t & 3) * 8;

    for (int k0 = 0; k0 < D_; k0 += 32) {
        __syncthreads();
        {
            const AT* ap = A + (size_t)(row0 + ar) * D_ + k0 + ah * 16;
            short8 s0, s1;
            if constexpr (sizeof(AT) == 4) {
                const float4 f0 = *(const float4*)(ap);
                const float4 f1 = *(const float4*)(ap + 4);
                const float4 f2 = *(const float4*)(ap + 8);
                const float4 f3 = *(const float4*)(ap + 12);
                s0[0] = (short)f2bf(f0.x); s0[1] = (short)f2bf(f0.y);
                s0[2] = (short)f2bf(f0.z); s0[3] = (short)f2bf(f0.w);
                s0[4] = (short)f2bf(f1.x); s0[5] = (short)f2bf(f1.y);
                s0[6] = (short)f2bf(f1.z); s0[7] = (short)f2bf(f1.w);
                s1[0] = (short)f2bf(f2.x); s1[1] = (short)f2bf(f2.y);
                s1[2] = (short)f2bf(f2.z); s1[3] = (short)f2bf(f2.w);
                s1[4] = (short)f2bf(f3.x); s1[5] = (short)f2bf(f3.y);
                s1[6] = (short)f2bf(f3.z); s1[7] = (short)f2bf(f3.w);
            } else {
                s0 = *(const short8*)(ap);
                s1 = *(const short8*)(ap + 8);
            }
            *(short8*)&As[ar][ah * 16] = s0;
            *(short8*)&As[ar][ah * 16 + 8] = s1;
        }
        *(short8*)&Ws[wr][wc] =
            *(const short8*)(W + (size_t)(col0 + wr) * D_ + k0 + wc);
        __syncthreads();

        const short8 a0 = *(const short8*)&As[wv * 32 + m16][quad * 8];
        const short8 a1 = *(const short8*)&As[wv * 32 + 16 + m16][quad * 8];
        const short8 b0 = *(const short8*)&Ws[m16][quad * 8];
        const short8 b1 = *(const short8*)&Ws[16 + m16][quad * 8];
        const short8 b2 = *(const short8*)&Ws[32 + m16][quad * 8];
        const short8 b3 = *(const short8*)&Ws[48 + m16][quad * 8];
        acc[0][0] = __builtin_amdgcn_mfma_f32_16x16x32_bf16(a0, b0, acc[0][0], 0, 0, 0);
        acc[0][1] = __builtin_amdgcn_mfma_f32_16x16x32_bf16(a0, b1, acc[0][1], 0, 0, 0);
        acc[0][2] = __builtin_amdgcn_mfma_f32_16x16x32_bf16(a0, b2, acc[0][2], 0, 0, 0);
        acc[0][3] = __builtin_amdgcn_mfma_f32_16x16x32_bf16(a0, b3, acc[0][3], 0, 0, 0);
        acc[1][0] = __builtin_amdgcn_mfma_f32_16x16x32_bf16(a1, b0, acc[1][0], 0, 0, 0);
        acc[1][1] = __builtin_amdgcn_mfma_f32_16x16x32_bf16(a1, b1, acc[1][1], 0, 0, 0);
        acc[1][2] = __builtin_amdgcn_mfma_f32_16x16x32_bf16(a1, b2, acc[1][2], 0, 0, 0);
        acc[1][3] = __builtin_amdgcn_mfma_f32_16x16x32_bf16(a1, b3, acc[1][3], 0, 0, 0);
    }

    const int isbf = *flagp;
#pragma unroll
    for (int mt = 0; mt < 2; ++mt) {
#pragma unroll
        for (int nt = 0; nt < 4; ++nt) {
            const int colg = col0 + nt * 16 + m16;
            const float bi = bias[colg];
            float v0 = acc[mt][nt][0] + bi, v1 = acc[mt][nt][1] + bi;
            float v2 = acc[mt][nt][2] + bi, v3 = acc[mt][nt][3] + bi;
            const int rowb = row0 + wv * 32 + mt * 16 + quad * 4;
            if (MODE == 0) {
                if (z == 2) {
                    const int bhv = (rowb >> 9) * H_ + (colg >> 6);
                    uint2 pk;
                    pk.x = (uint)f2bf(v0) | ((uint)f2bf(v1) << 16);
                    pk.y = (uint)f2bf(v2) | ((uint)f2bf(v3) << 16);
                    *(uint2*)(ov + ((size_t)bhv * DK_ + (colg & 63)) * N_ + (rowb & 511)) = pk;
                } else {
                    ushort* o = (z == 0) ? oq : ok;
                    const float vv[4] = {v0, v1, v2, v3};
#pragma unroll
                    for (int r = 0; r < 4; ++r) {
                        const int row = rowb + r;
                        o[((size_t)((row >> 9) * H_ + (colg >> 6)) * N_ + (row & 511)) * DK_ +
                          (colg & 63)] = f2bf(vv[r]);
                    }
                }
            } else {
                const float vv[4] = {v0, v1, v2, v3};
#pragma unroll
                for (int r = 0; r < 4; ++r) {
                    const int row = rowb + r;
                    if (isbf) ((ushort*)dout)[(size_t)row * D_ + colg] = f2bf(vv[r]);
                    else      ((float*)dout)[(size_t)row * D_ + colg] = vv[r];
                }
            }
        }
    }
}

// ---------------- geometry log-bias v2: trig on VALU, 64x8 dot on MFMA ----------------
// glog layout: [bl][it(32)][h(8)][ii(16)][j(512)] fp16 (same as before; attn3 unchanged)
__global__ __launch_bounds__(256) void geom2(const void* __restrict__ box,
                                             const int* __restrict__ nobj,
                                             const void* __restrict__ WG,
                                             const void* __restrict__ bG,
                                             ushort* __restrict__ glog,
                                             const int* __restrict__ flagp) {
    const int isbf = *flagp;
    const int i = blockIdx.x, bl = blockIdx.y;
    const int t = threadIdx.x;

    __shared__ _Float16 trig[128][72];   // [pair][g]; stride 144B -> 2-way-ish aliasing
    __shared__ _Float16 wgf[16][72];     // B operand: rows 8..15 zero
    __shared__ float mobja[128];
    __shared__ float bgs[8];

    for (int e = t; e < 1024; e += 256) {
        const int h = e >> 6, g = e & 63;
        wgf[h][g] = (_Float16)((h < 8) ? ldf(WG, (size_t)h * 64 + g, isbf) : 0.f);
    }
    if (t < 8) bgs[t] = ldf(bG, t, isbf);

    // box_i params (redundant per thread, cheap)
    const size_t ib = (size_t)(bl * N_ + i) * 4;
    const float ixn = ldf(box, ib + 0, isbf), iyn = ldf(box, ib + 1, isbf);
    const float ixx = ldf(box, ib + 2, isbf), iyx = ldf(box, ib + 3, isbf);
    const float wi = ixx - ixn + 1.0f, hi = iyx - iyn + 1.0f;
    const float cxi = (ixn + ixx) * 0.5f, cyi = (iyn + iyx) * 0.5f;
    const float rwi = 1.0f / wi, rhi = 1.0f / hi;
    const float lwi = __logf(wi), lhi = __logf(hi);
    const int noi = nobj[bl * N_ + i];
    __syncthreads();

    const int wv = t >> 6, lane = t & 63, m16 = lane & 15, quad = lane >> 4;
    const half8 bf0 = *(const half8*)&wgf[m16][quad * 8];
    const half8 bf1 = *(const half8*)&wgf[m16][quad * 8 + 32];
    _Float16* gb = (_Float16*)glog +
                   ((((size_t)bl * 32 + (i >> 4)) * 8) * 16 + (i & 15)) * 512;
    const float dm[8] = {1.0f, 0.421696503f, 0.177827941f, 0.074989421f,
                         0.031622777f, 0.013335214f, 0.005623413f, 0.002371374f};

    for (int c = 0; c < 4; ++c) {
        const int jbase = c * 128;
        {   // phase 1: trig -> LDS; 2 threads per pair (each does 2 pos dims)
            const int pair = t >> 1, hf = t & 1;
            const int j = jbase + pair;
            const size_t jb = (size_t)(bl * N_ + j) * 4;
            const float jxn = ldf(box, jb + 0, isbf), jyn = ldf(box, jb + 1, isbf);
            const float jxx = ldf(box, jb + 2, isbf), jyx = ldf(box, jb + 3, isbf);
            const float wj = jxx - jxn + 1.0f, hj = jyx - jyn + 1.0f;
            float p0, p1;
            if (hf == 0) {
                const float cxj = (jxn + jxx) * 0.5f, cyj = (jyn + jyx) * 0.5f;
                p0 = __logf(fmaxf(fabsf((cxi - cxj) * rwi), 0.001f));
                p1 = __logf(fmaxf(fabsf((cyi - cyj) * rhi), 0.001f));
                mobja[pair] = (noi || nobj[bl * N_ + j]) ? 0.f : 1.f;
            } else {
                p0 = lwi - __logf(wj);
                p1 = lhi - __logf(hj);
            }
#pragma unroll
            for (int pp = 0; pp < 2; ++pp) {
                const float base = 100.f * (pp ? p1 : p0);
                half8 s8, c8;
#pragma unroll
                for (int f = 0; f < 8; ++f) {
                    float sv, cv;
                    __sincosf(base * dm[f], &sv, &cv);
                    s8[f] = (_Float16)sv;
                    c8[f] = (_Float16)cv;
                }
                const int g0 = hf * 16 + pp * 8;
                *(half8*)&trig[pair][g0] = s8;
                *(half8*)&trig[pair][32 + g0] = c8;
            }
        }
        __syncthreads();
        {   // phase 2: MFMA [16 pairs x 64] @ WG^T[64 x 8] + bias + log + store
#pragma unroll
            for (int sub = 0; sub < 2; ++sub) {
                const int pr0 = wv * 32 + sub * 16;
                const half8 a0 = *(const half8*)&trig[pr0 + m16][quad * 8];
                const half8 a1 = *(const half8*)&trig[pr0 + m16][quad * 8 + 32];
                floatx4 acc = {};
                acc = __builtin_amdgcn_mfma_f32_16x16x32_f16(a0, bf0, acc, 0, 0, 0);
                acc = __builtin_amdgcn_mfma_f32_16x16x32_f16(a1, bf1, acc, 0, 0, 0);
                if (m16 < 8) {
#pragma unroll
                    for (int r = 0; r < 4; ++r) {
                        const int pair = pr0 + quad * 4 + r;
                        const float wg = acc[r] + bgs[m16];
                        const float gl = __logf(fmaxf(wg, 1e-6f)) * mobja[pair];
                        gb[(size_t)m16 * 8192 + jbase + pair] = (_Float16)gl;
                    }
                }
            }
        }
        __syncthreads();
    }
}

// ---------------- MFMA attention (proven round 5) ----------------
__global__ __launch_bounds__(256) void attn3(
    const ushort* __restrict__ qw, const ushort* __restrict__ kw,
    const ushort* __restrict__ vt, const int* __restrict__ mask,
    const ushort* __restrict__ glog, ushort* __restrict__ att, int b0) {
    const int it = blockIdx.x, h = blockIdx.y, bl = blockIdx.z;
    const int bg = b0 + bl;
    const int i0 = it * 16;
    const int t = threadIdx.x, wv = t >> 6, lane = t & 63;
    const int m16 = lane & 15, quad = lane >> 4;
    const size_t bh = (size_t)(bg * H_ + h);

    __shared__ float lg[16][516];
    __shared__ ushort sbuf[16 * 520];
    __shared__ float rsumInv[16];

    {
        const uint4* src = (const uint4*)(glog + (((size_t)bl * 32 + it) * 8 + h) * 8192);
        uint4* dst = (uint4*)sbuf;
#pragma unroll
        for (int e = 0; e < 4; ++e) dst[t + 256 * e] = src[t + 256 * e];
    }
    const ushort* qrow = qw + (bh * N_ + i0 + m16) * DK_ + quad * 8;
    const short8 aq0 = *(const short8*)(qrow);
    const short8 aq1 = *(const short8*)(qrow + 32);
    __syncthreads();

#pragma unroll
    for (int tt = 0; tt < 8; ++tt) {
        const int j0 = wv * 128 + tt * 16;
        const ushort* krow = kw + (bh * N_ + j0 + m16) * DK_ + quad * 8;
        const short8 bk0 = *(const short8*)(krow);
        const short8 bk1 = *(const short8*)(krow + 32);
        floatx4 acc = {};
        acc = __builtin_amdgcn_mfma_f32_16x16x32_bf16(aq0, bk0, acc, 0, 0, 0);
        acc = __builtin_amdgcn_mfma_f32_16x16x32_bf16(aq1, bk1, acc, 0, 0, 0);
        const int mj = mask[bg * N_ + j0 + m16];
        const __half* gt = (const __half*)sbuf;
#pragma unroll
        for (int r = 0; r < 4; ++r) {
            const int i = quad * 4 + r;
            const float g = __half2float(gt[i * 512 + j0 + m16]);
            lg[i][j0 + m16] = (mj ? 0.125f * acc[r] : -1e9f) + g;
        }
    }
    __syncthreads();

    {
        const int row = t >> 4, l = t & 15;
        float v[32];
        float mx = -3e38f;
#pragma unroll
        for (int s = 0; s < 32; ++s) { v[s] = lg[row][l + 16 * s]; mx = fmaxf(mx, v[s]); }
#pragma unroll
        for (int d = 1; d < 16; d <<= 1) mx = fmaxf(mx, __shfl_xor(mx, d, 16));
        float sm = 0.f;
#pragma unroll
        for (int s = 0; s < 32; ++s) { const float p = __expf(v[s] - mx); sm += p; v[s] = p; }
#pragma unroll
        for (int d = 1; d < 16; d <<= 1) sm += __shfl_xor(sm, d, 16);
#pragma unroll
        for (int s = 0; s < 32; ++s) sbuf[row * 520 + l + 16 * s] = f2bf(v[s]);
        if (l == 0) rsumInv[row] = 1.0f / sm;
    }
    __syncthreads();

    {
        const int dk0 = wv * 16;
        const ushort* vrow = vt + (bh * DK_ + dk0 + m16) * N_ + quad * 8;
        floatx4 oc = {};
#pragma unroll
        for (int kc = 0; kc < 16; ++kc) {
            const short8 ap = *(const short8*)(sbuf + m16 * 520 + kc * 32 + quad * 8);
            const short8 bv = *(const short8*)(vrow + kc * 32);
            oc = __builtin_amdgcn_mfma_f32_16x16x32_bf16(ap, bv, oc, 0, 0, 0);
        }
#pragma unroll
        for (int r = 0; r < 4; ++r) {
            const int i = quad * 4 + r;
            const float o = oc[r] * rsumInv[i];
            att[((size_t)(bg * N_ + i0 + i)) * D_ + h * DK_ + dk0 + m16] = f2bf(o);
        }
    }
}

// ================= tier-3 fallback (round-3 proven) =================
__global__ __launch_bounds__(256) void gemm16(const void* __restrict__ A,
                                              const void* __restrict__ W,
                                              const void* __restrict__ bias,
                                              void* __restrict__ out,
                                              const int* __restrict__ flagp,
                                              int a_follows, int mode) {
    const int isbf = *flagp;
    const int a_isbf = a_follows ? isbf : 1;
    const int wave = threadIdx.x >> 6;
    const int tile = blockIdx.x * 4 + wave;
    const int tm = tile >> 5, tn = tile & 31;
    const int row0 = tm * 16, col0 = tn * 16;
    const int lane = threadIdx.x & 63;
    const int m = lane & 15, quad = lane >> 4;
    floatx4 acc = {0.f, 0.f, 0.f, 0.f};
    const size_t abase = (size_t)(row0 + m) * D_ + quad * 8;
    const size_t wbase = (size_t)(quad * 8) * D_ + col0 + m;
    for (int k0 = 0; k0 < D_; k0 += 32) {
        short8 af, bf;
#pragma unroll
        for (int j = 0; j < 8; ++j) af[j] = ldb(A, abase + k0 + j, a_isbf);
#pragma unroll
        for (int j = 0; j < 8; ++j) bf[j] = ldb(W, wbase + (size_t)(k0 + j) * D_, isbf);
        acc = __builtin_amdgcn_mfma_f32_16x16x32_bf16(af, bf, acc, 0, 0, 0);
    }
    const int col = col0 + m;
    const float bi = ldf(bias, col, isbf);
#pragma unroll
    for (int r = 0; r < 4; ++r) {
        const int row = row0 + quad * 4 + r;
        const float v = acc[r] + bi;
        if (mode == 1) {
            ((ushort*)out)[(size_t)(((row >> 9) * H_ + (col >> 6)) * N_ + (row & 511)) * DK_ + (col & 63)] = f2bf(v);
        } else if (isbf) {
            ((ushort*)out)[(size_t)row * D_ + col] = f2bf(v);
        } else {
            ((float*)out)[(size_t)row * D_ + col] = v;
        }
    }
}

__global__ __launch_bounds__(256) void attn_old(
    const ushort* __restrict__ qw, const ushort* __restrict__ kw,
    const ushort* __restrict__ vw, const void* __restrict__ box,
    const int* __restrict__ mask, const int* __restrict__ nobj,
    const void* __restrict__ WG, const void* __restrict__ bG,
    ushort* __restrict__ att, const int* __restrict__ flagp) {
    const int isbf = *flagp;
    const int b = blockIdx.z, h = blockIdx.y;
    const int i0 = blockIdx.x * 8;
    const int t = threadIdx.x;
    __shared__ float lg[8][520];
    __shared__ float q_s[8][68];
    __shared__ float wgh[64];
    __shared__ float cxi[8], cyi[8], rwi[8], rhi[8], lwi[8], lhi[8];
    __shared__ int noi[8];
    __shared__ float rsum[8];
    for (int e = t; e < 512; e += 256) {
        const int ii = e >> 6, dk = e & 63;
        q_s[ii][dk] = bf2f(qw[(size_t)((b * H_ + h) * N_ + i0 + ii) * DK_ + dk]) * 0.125f;
    }
    if (t < 64) wgh[t] = ldf(WG, h * 64 + t, isbf);
    if (t < 8) {
        const size_t bb = (size_t)(b * N_ + i0 + t) * 4;
        const float xmn = ldf(box, bb + 0, isbf), ymn = ldf(box, bb + 1, isbf);
        const float xmx = ldf(box, bb + 2, isbf), ymx = ldf(box, bb + 3, isbf);
        const float w = xmx - xmn + 1.0f, hh = ymx - ymn + 1.0f;
        cxi[t] = (xmn + xmx) * 0.5f;
        cyi[t] = (ymn + ymx) * 0.5f;
        rwi[t] = 1.0f / w;
        rhi[t] = 1.0f / hh;
        lwi[t] = __logf(w);
        lhi[t] = __logf(hh);
        noi[t] = nobj[b * N_ + i0 + t];
    }
    const float bg = ldf(bG, h, isbf);
    __syncthreads();
    for (int jl = 0; jl < 2; ++jl) {
        const int j = t + jl * 256;
        float acc[8];
#pragma unroll
        for (int ii = 0; ii < 8; ++ii) acc[ii] = 0.f;
        const uint4* krow = (const uint4*)(kw + (size_t)((b * H_ + h) * N_ + j) * DK_);
#pragma unroll
        for (int c = 0; c < 8; ++c) {
            const uint4 ku = krow[c];
            float kf[8];
            kf[0] = blo(ku.x); kf[1] = bhi(ku.x); kf[2] = blo(ku.y); kf[3] = bhi(ku.y);
            kf[4] = blo(ku.z); kf[5] = bhi(ku.z); kf[6] = blo(ku.w); kf[7] = bhi(ku.w);
#pragma unroll
            for (int ii = 0; ii < 8; ++ii) {
                const float4 qa = *(const float4*)(&q_s[ii][c * 8]);
                const float4 qb = *(const float4*)(&q_s[ii][c * 8 + 4]);
                acc[ii] += qa.x * kf[0] + qa.y * kf[1] + qa.z * kf[2] + qa.w * kf[3] +
                           qb.x * kf[4] + qb.y * kf[5] + qb.z * kf[6] + qb.w * kf[7];
            }
        }
        const int mj = mask[b * N_ + j];
        const size_t bb = (size_t)(b * N_ + j) * 4;
        const float xmn = ldf(box, bb + 0, isbf), ymn = ldf(box, bb + 1, isbf);
        const float xmx = ldf(box, bb + 2, isbf), ymx = ldf(box, bb + 3, isbf);
        const float cxj = (xmn + xmx) * 0.5f, cyj = (ymn + ymx) * 0.5f;
        const float wj = xmx - xmn + 1.0f, hj = ymx - ymn + 1.0f;
        const float lwj = __logf(wj), lhj = __logf(hj);
        const int noj = nobj[b * N_ + j];
        const float dm[8] = {1.0f, 0.421696503f, 0.177827941f, 0.074989421f,
                             0.031622777f, 0.013335214f, 0.005623413f, 0.002371374f};
        for (int ii = 0; ii < 8; ++ii) {
            const float mobj = (noi[ii] || noj) ? 0.f : 1.f;
            const float dx = __logf(fmaxf(fabsf((cxi[ii] - cxj) * rwi[ii]), 0.001f));
            const float dy = __logf(fmaxf(fabsf((cyi[ii] - cyj) * rhi[ii]), 0.001f));
            const float pos[4] = {dx, dy, lwi[ii] - lwj, lhi[ii] - lhj};
            float wg = bg;
            for (int p = 0; p < 4; ++p) {
                const float base = 100.f * pos[p];
#pragma unroll
                for (int f = 0; f < 8; ++f) {
                    float sv, cv;
                    __sincosf(base * dm[f], &sv, &cv);
                    const int g = p * 8 + f;
                    wg += sv * wgh[g] + cv * wgh[32 + g];
                }
            }
            lg[ii][j] = (mj ? acc[ii] : -1e9f) + __logf(fmaxf(wg, 1e-6f)) * mobj;
        }
    }
    __syncthreads();
    {
        const int rr = t >> 5, l32 = t & 31;
        float mx = -3e38f;
        for (int j = l32; j < N_; j += 32) mx = fmaxf(mx, lg[rr][j]);
#pragma unroll
        for (int d = 1; d < 32; d <<= 1) mx = fmaxf(mx, __shfl_xor(mx, d, 32));
        float sm = 0.f;
        for (int j = l32; j < N_; j += 32) {
            const float p = __expf(lg[rr][j] - mx);
            lg[rr][j] = p;
            sm += p;
        }
#pragma unroll
        for (int d = 1; d < 32; d <<= 1) sm += __shfl_xor(sm, d, 32);
        if (l32 == 0) rsum[rr] = sm;
    }
    __syncthreads();
    {
        const int ii = t >> 5, dkp = t & 31;
        float o0 = 0.f, o1 = 0.f;
        const uint* vbase = (const uint*)vw + (size_t)((b * H_ + h) * N_) * (DK_ / 2) + dkp;
        for (int j = 0; j < N_; ++j) {
            const uint u = vbase[(size_t)j * (DK_ / 2)];
            const float p = lg[ii][j];
            o0 += p * blo(u);
            o1 += p * bhi(u);
        }
        const float inv = 1.0f / rsum[ii];
        const uint pk = (uint)f2bf(o0 * inv) | ((uint)f2bf(o1 * inv) << 16);
        ((uint*)att)[(size_t)(b * N_ + i0 + ii) * (D_ / 2) + h * 32 + dkp] = pk;
    }
}

extern "C" void kernel_launch(void* const* d_in, const int* in_sizes, int n_in,
                              void* d_out, int out_size, void* d_ws, size_t ws_size,
                              hipStream_t stream) {
    const void* xq = d_in[0];
    const void* xk = d_in[1];
    const void* xv = d_in[2];
    const void* box = d_in[3];
    const int* mask = (const int*)d_in[4];
    const int* nobj = (const int*)d_in[5];
    const void* Wq = d_in[6];
    const void* bq = d_in[7];
    const void* Wk = d_in[8];
    const void* bk = d_in[9];
    const void* Wv = d_in[10];
    const void* bv = d_in[11];
    const void* Wo = d_in[12];
    const void* bo = d_in[13];
    const void* WG = d_in[14];
    const void* bG = d_in[15];

    char* ws = (char*)d_ws;
    const size_t MB = 1u << 20;

    if (ws_size >= 54 * MB) {   // tier-1 (confirmed active since round 3)
        int* flag = (int*)ws;
        float* biasf = (float*)(ws + 4096);
        ushort* wt = (ushort*)(ws + 16384);
        size_t p = 16384 + 2097152;
        ushort* qw = (ushort*)(ws + p); p += 4194304;
        ushort* kw = (ushort*)(ws + p); p += 4194304;
        ushort* vt = (ushort*)(ws + p); p += 4194304;
        ushort* att = (ushort*)(ws + p); p += 4194304;
        ushort* glog = (ushort*)(ws + p);   // 32 MB: [bl][it][h][16][512] fp16

        hipLaunchKernelGGL(probe_dtype, dim3(1), dim3(256), 0, stream, (const uint*)xq, flag);
        hipLaunchKernelGGL(prep_bias, dim3(8), dim3(256), 0, stream, bq, bk, bv, bo, biasf, flag);
        hipLaunchKernelGGL(transw, dim3(16, 16, 4), dim3(256), 0, stream, Wq, Wk, Wv, Wo, wt, flag);
        hipLaunchKernelGGL((gemm_mfma<float, 0>), dim3(32, 8, 3), dim3(256), 0, stream,
                           (const float*)xq, (const float*)xk, (const float*)xv,
                           wt, biasf, qw, kw, vt, (void*)nullptr, flag, 0);
        hipLaunchKernelGGL((gemm_mfma<ushort, 0>), dim3(32, 8, 3), dim3(256), 0, stream,
                           (const ushort*)xq, (const ushort*)xk, (const ushort*)xv,
                           wt, biasf, qw, kw, vt, (void*)nullptr, flag, 1);
        hipLaunchKernelGGL(geom2, dim3(N_, B_), dim3(256), 0, stream,
                           box, nobj, WG, bG, glog, flag);
        hipLaunchKernelGGL(attn3, dim3(32, H_, B_), dim3(256), 0, stream,
                           qw, kw, vt, mask, glog, att, 0);
        hipLaunchKernelGGL((gemm_mfma<ushort, 1>), dim3(32, 8), dim3(256), 0, stream,
                           att, att, att, wt, biasf, qw, kw, vt, d_out, flag, -1);
    } else {
        // tier-3 fallback (proven round-3 path, ~16.6 MB)
        int* flag = (int*)ws;
        ushort* qw = (ushort*)(ws + 256);
        ushort* kw = (ushort*)(ws + 256 + 4194304);
        ushort* vw = (ushort*)(ws + 256 + 8388608);
        ushort* att = (ushort*)(ws + 256 + 12582912);
        hipLaunchKernelGGL(probe_dtype, dim3(1), dim3(256), 0, stream, (const uint*)xq, flag);
        hipLaunchKernelGGL(gemm16, dim3(2048), dim3(256), 0, stream, xq, Wq, bq, (void*)qw, flag, 1, 1);
        hipLaunchKernelGGL(gemm16, dim3(2048), dim3(256), 0, stream, xk, Wk, bk, (void*)kw, flag, 1, 1);
        hipLaunchKernelGGL(gemm16, dim3(2048), dim3(256), 0, stream, xv, Wv, bv, (void*)vw, flag, 1, 1);
        hipLaunchKernelGGL(attn_old, dim3(N_ / 8, H_, B_), dim3(256), 0, stream,
                           qw, kw, vw, box, mask, nobj, WG, bG, att, flag);
        hipLaunchKernelGGL(gemm16, dim3(2048), dim3(256), 0, stream, att, Wo, bo, d_out, flag, 0, 2);
    }
}

// Round 7
// 210.057 us; speedup vs baseline: 6.8605x; 1.0399x over previous
//
#include <hip/hip_runtime.h>
#include <hip/hip_fp16.h>

#define B_ 8
#define N_ 512
#define D_ 512
#define H_ 8
#define DK_ 64

typedef unsigned int uint;
typedef unsigned short ushort;
typedef __attribute__((ext_vector_type(8))) short short8;
typedef __attribute__((ext_vector_type(8))) _Float16 half8;
typedef __attribute__((ext_vector_type(4))) _Float16 half4;
typedef __attribute__((ext_vector_type(4))) float floatx4;

__device__ __forceinline__ float bf2f(ushort s) { return __uint_as_float(((uint)s) << 16); }
__device__ __forceinline__ ushort f2bf(float f) {
    uint x = __float_as_uint(f);
    return (ushort)((x + 0x7fffu + ((x >> 16) & 1u)) >> 16);
}
__device__ __forceinline__ float blo(uint u) { return __uint_as_float(u << 16); }
__device__ __forceinline__ float bhi(uint u) { return __uint_as_float(u & 0xffff0000u); }
__device__ __forceinline__ float ldf(const void* p, size_t i, int isbf) {
    return isbf ? bf2f(((const ushort*)p)[i]) : ((const float*)p)[i];
}
__device__ __forceinline__ short ldb(const void* p, size_t i, int isbf) {
    return isbf ? (short)(((const ushort*)p)[i]) : (short)f2bf(((const float*)p)[i]);
}
// one vector load per box row (fp32: float4 16B; bf16: uint2 8B)
__device__ __forceinline__ float4 ldbox(const void* p, size_t row, int isbf) {
    if (isbf) {
        const uint2 u = ((const uint2*)p)[row];
        return make_float4(blo(u.x), bhi(u.x), blo(u.y), bhi(u.y));
    }
    return ((const float4*)p)[row];
}

// ---------------- dtype probe (proven) ----------------
__global__ __launch_bounds__(256) void probe_dtype(const uint* __restrict__ q,
                                                   int* __restrict__ flag) {
    __shared__ int s[256];
    const int t = threadIdx.x;
    int cnt = 0;
    for (int i = t; i < 4096; i += 256) {
        const uint e = (q[i] >> 7) & 0xffu;
        cnt += (e >= 0x70u && e <= 0x84u) ? 1 : 0;
    }
    s[t] = cnt;
    __syncthreads();
    for (int d = 128; d > 0; d >>= 1) {
        if (t < d) s[t] += s[t + d];
        __syncthreads();
    }
    if (t == 0) *flag = (s[0] > 3276) ? 1 : 0;
}

// ---------------- W transpose -> Wt[n][k] bf16, + bias convert folded in ----------------
__global__ __launch_bounds__(256) void transw(const void* __restrict__ w0,
                                              const void* __restrict__ w1,
                                              const void* __restrict__ w2,
                                              const void* __restrict__ w3,
                                              const void* __restrict__ b0,
                                              const void* __restrict__ b1,
                                              const void* __restrict__ b2,
                                              const void* __restrict__ b3,
                                              ushort* __restrict__ wt,
                                              float* __restrict__ biasf,
                                              const int* __restrict__ flagp) {
    const int isbf = *flagp;
    const int z = blockIdx.z;
    const void* W = (z == 0) ? w0 : (z == 1) ? w1 : (z == 2) ? w2 : w3;
    const int n0 = blockIdx.x * 32, k0 = blockIdx.y * 32;
    __shared__ float tile[32][33];
    const int tx = threadIdx.x & 31, ty = threadIdx.x >> 5;
#pragma unroll
    for (int r = 0; r < 4; ++r)
        tile[ty + 8 * r][tx] = ldf(W, (size_t)(k0 + ty + 8 * r) * D_ + n0 + tx, isbf);
    if (blockIdx.x == 0 && blockIdx.y == 0) {
        const void* bz = (z == 0) ? b0 : (z == 1) ? b1 : (z == 2) ? b2 : b3;
        for (int e = threadIdx.x; e < 512; e += 256)
            biasf[z * 512 + e] = ldf(bz, e, isbf);
    }
    __syncthreads();
#pragma unroll
    for (int r = 0; r < 4; ++r)
        wt[(size_t)z * 262144 + (size_t)(n0 + ty + 8 * r) * D_ + k0 + tx] =
            f2bf(tile[tx][ty + 8 * r]);
}

// ---------------- MFMA GEMM, QKV (mode 0): runtime dtype + k+1 reg prefetch ----------------
// z=blockIdx.z in {0,1,2}=Q,K,V. Q,K -> [B,H,N,DK] bf16; V -> vt [B,H,DK,N] bf16.
__global__ __launch_bounds__(256) void gemm0(
    const void* __restrict__ A0, const void* __restrict__ A1, const void* __restrict__ A2,
    const ushort* __restrict__ wt, const float* __restrict__ biasf,
    ushort* __restrict__ oq, ushort* __restrict__ ok, ushort* __restrict__ ov,
    const int* __restrict__ flagp) {
    const int isbf = *flagp;
    const int z = blockIdx.z;
    const char* A = (const char*)((z == 0) ? A0 : (z == 1) ? A1 : A2);
    const ushort* W = wt + (size_t)z * 262144;
    const float* bias = biasf + z * 512;
    const int row0 = blockIdx.x * 128, col0 = blockIdx.y * 64;
    const int t = threadIdx.x, wv = t >> 6, lane = t & 63;
    const int m16 = lane & 15, quad = lane >> 4;

    __shared__ ushort As[128][40];
    __shared__ ushort Ws[64][40];
    floatx4 acc[2][4] = {};

    const int ar = t >> 1, ah = t & 1;
    const int wr = t >> 2, wc = (t & 3) * 8;

    float4 pf0, pf1, pf2, pf3;
    short8 ps0, ps1, pw;

    auto loadA = [&](int k0) {
        const size_t e = (size_t)(row0 + ar) * D_ + k0 + ah * 16;
        if (isbf) {
            ps0 = *(const short8*)(A + 2 * e);
            ps1 = *(const short8*)(A + 2 * e + 16);
        } else {
            const float* ap = (const float*)(A + 4 * e);
            pf0 = *(const float4*)(ap);
            pf1 = *(const float4*)(ap + 4);
            pf2 = *(const float4*)(ap + 8);
            pf3 = *(const float4*)(ap + 12);
        }
        pw = *(const short8*)(W + (size_t)(col0 + wr) * D_ + k0 + wc);
    };
    auto stage = [&]() {
        short8 s0, s1;
        if (isbf) {
            s0 = ps0; s1 = ps1;
        } else {
            s0[0] = (short)f2bf(pf0.x); s0[1] = (short)f2bf(pf0.y);
            s0[2] = (short)f2bf(pf0.z); s0[3] = (short)f2bf(pf0.w);
            s0[4] = (short)f2bf(pf1.x); s0[5] = (short)f2bf(pf1.y);
            s0[6] = (short)f2bf(pf1.z); s0[7] = (short)f2bf(pf1.w);
            s1[0] = (short)f2bf(pf2.x); s1[1] = (short)f2bf(pf2.y);
            s1[2] = (short)f2bf(pf2.z); s1[3] = (short)f2bf(pf2.w);
            s1[4] = (short)f2bf(pf3.x); s1[5] = (short)f2bf(pf3.y);
            s1[6] = (short)f2bf(pf3.z); s1[7] = (short)f2bf(pf3.w);
        }
        *(short8*)&As[ar][ah * 16] = s0;
        *(short8*)&As[ar][ah * 16 + 8] = s1;
        *(short8*)&Ws[wr][wc] = pw;
    };

    loadA(0);
    for (int k0 = 0; k0 < D_; k0 += 32) {
        __syncthreads();
        stage();
        __syncthreads();
        if (k0 + 32 < D_) loadA(k0 + 32);   // in flight across the MFMA phase

        const short8 a0 = *(const short8*)&As[wv * 32 + m16][quad * 8];
        const short8 a1 = *(const short8*)&As[wv * 32 + 16 + m16][quad * 8];
        const short8 b0 = *(const short8*)&Ws[m16][quad * 8];
        const short8 b1 = *(const short8*)&Ws[16 + m16][quad * 8];
        const short8 b2 = *(const short8*)&Ws[32 + m16][quad * 8];
        const short8 b3 = *(const short8*)&Ws[48 + m16][quad * 8];
        acc[0][0] = __builtin_amdgcn_mfma_f32_16x16x32_bf16(a0, b0, acc[0][0], 0, 0, 0);
        acc[0][1] = __builtin_amdgcn_mfma_f32_16x16x32_bf16(a0, b1, acc[0][1], 0, 0, 0);
        acc[0][2] = __builtin_amdgcn_mfma_f32_16x16x32_bf16(a0, b2, acc[0][2], 0, 0, 0);
        acc[0][3] = __builtin_amdgcn_mfma_f32_16x16x32_bf16(a0, b3, acc[0][3], 0, 0, 0);
        acc[1][0] = __builtin_amdgcn_mfma_f32_16x16x32_bf16(a1, b0, acc[1][0], 0, 0, 0);
        acc[1][1] = __builtin_amdgcn_mfma_f32_16x16x32_bf16(a1, b1, acc[1][1], 0, 0, 0);
        acc[1][2] = __builtin_amdgcn_mfma_f32_16x16x32_bf16(a1, b2, acc[1][2], 0, 0, 0);
        acc[1][3] = __builtin_amdgcn_mfma_f32_16x16x32_bf16(a1, b3, acc[1][3], 0, 0, 0);
    }

#pragma unroll
    for (int mt = 0; mt < 2; ++mt) {
#pragma unroll
        for (int nt = 0; nt < 4; ++nt) {
            const int colg = col0 + nt * 16 + m16;
            const float bi = bias[colg];
            const float v0 = acc[mt][nt][0] + bi, v1 = acc[mt][nt][1] + bi;
            const float v2 = acc[mt][nt][2] + bi, v3 = acc[mt][nt][3] + bi;
            const int rowb = row0 + wv * 32 + mt * 16 + quad * 4;
            if (z == 2) {
                const int bhv = (rowb >> 9) * H_ + (colg >> 6);
                uint2 pk;
                pk.x = (uint)f2bf(v0) | ((uint)f2bf(v1) << 16);
                pk.y = (uint)f2bf(v2) | ((uint)f2bf(v3) << 16);
                *(uint2*)(ov + ((size_t)bhv * DK_ + (colg & 63)) * N_ + (rowb & 511)) = pk;
            } else {
                ushort* o = (z == 0) ? oq : ok;
                const float vv[4] = {v0, v1, v2, v3};
#pragma unroll
                for (int r = 0; r < 4; ++r) {
                    const int row = rowb + r;
                    o[((size_t)((row >> 9) * H_ + (colg >> 6)) * N_ + (row & 511)) * DK_ +
                      (colg & 63)] = f2bf(vv[r]);
                }
            }
        }
    }
}

// ---------------- MFMA GEMM, output proj (mode 1): A bf16 ws, out per flag ----------------
__global__ __launch_bounds__(256) void gemm1(
    const ushort* __restrict__ att, const ushort* __restrict__ wt,
    const float* __restrict__ biasf, void* __restrict__ dout,
    const int* __restrict__ flagp) {
    const int isbf = *flagp;
    const ushort* W = wt + (size_t)3 * 262144;
    const float* bias = biasf + 3 * 512;
    const int row0 = blockIdx.x * 128, col0 = blockIdx.y * 64;
    const int t = threadIdx.x, wv = t >> 6, lane = t & 63;
    const int m16 = lane & 15, quad = lane >> 4;

    __shared__ ushort As[128][40];
    __shared__ ushort Ws[64][40];
    floatx4 acc[2][4] = {};

    const int ar = t >> 1, ah = t & 1;
    const int wr = t >> 2, wc = (t & 3) * 8;

    short8 ps0, ps1, pw;
    auto loadA = [&](int k0) {
        const ushort* ap = att + (size_t)(row0 + ar) * D_ + k0 + ah * 16;
        ps0 = *(const short8*)(ap);
        ps1 = *(const short8*)(ap + 8);
        pw = *(const short8*)(W + (size_t)(col0 + wr) * D_ + k0 + wc);
    };

    loadA(0);
    for (int k0 = 0; k0 < D_; k0 += 32) {
        __syncthreads();
        *(short8*)&As[ar][ah * 16] = ps0;
        *(short8*)&As[ar][ah * 16 + 8] = ps1;
        *(short8*)&Ws[wr][wc] = pw;
        __syncthreads();
        if (k0 + 32 < D_) loadA(k0 + 32);

        const short8 a0 = *(const short8*)&As[wv * 32 + m16][quad * 8];
        const short8 a1 = *(const short8*)&As[wv * 32 + 16 + m16][quad * 8];
        const short8 b0 = *(const short8*)&Ws[m16][quad * 8];
        const short8 b1 = *(const short8*)&Ws[16 + m16][quad * 8];
        const short8 b2 = *(const short8*)&Ws[32 + m16][quad * 8];
        const short8 b3 = *(const short8*)&Ws[48 + m16][quad * 8];
        acc[0][0] = __builtin_amdgcn_mfma_f32_16x16x32_bf16(a0, b0, acc[0][0], 0, 0, 0);
        acc[0][1] = __builtin_amdgcn_mfma_f32_16x16x32_bf16(a0, b1, acc[0][1], 0, 0, 0);
        acc[0][2] = __builtin_amdgcn_mfma_f32_16x16x32_bf16(a0, b2, acc[0][2], 0, 0, 0);
        acc[0][3] = __builtin_amdgcn_mfma_f32_16x16x32_bf16(a0, b3, acc[0][3], 0, 0, 0);
        acc[1][0] = __builtin_amdgcn_mfma_f32_16x16x32_bf16(a1, b0, acc[1][0], 0, 0, 0);
        acc[1][1] = __builtin_amdgcn_mfma_f32_16x16x32_bf16(a1, b1, acc[1][1], 0, 0, 0);
        acc[1][2] = __builtin_amdgcn_mfma_f32_16x16x32_bf16(a1, b2, acc[1][2], 0, 0, 0);
        acc[1][3] = __builtin_amdgcn_mfma_f32_16x16x32_bf16(a1, b3, acc[1][3], 0, 0, 0);
    }

#pragma unroll
    for (int mt = 0; mt < 2; ++mt) {
#pragma unroll
        for (int nt = 0; nt < 4; ++nt) {
            const int colg = col0 + nt * 16 + m16;
            const float bi = bias[colg];
#pragma unroll
            for (int r = 0; r < 4; ++r) {
                const int row = row0 + wv * 32 + mt * 16 + quad * 4 + r;
                const float v = acc[mt][nt][r] + bi;
                if (isbf) ((ushort*)dout)[(size_t)row * D_ + colg] = f2bf(v);
                else      ((float*)dout)[(size_t)row * D_ + colg] = v;
            }
        }
    }
}

// ---------------- geometry log-bias v3: conflict-free trig LDS + vector box loads ----------
// glog layout: [bl][it(32)][h(8)][ii(16)][j(512)] fp16 (unchanged; attn3 untouched)
__global__ __launch_bounds__(256) void geom2(const void* __restrict__ box,
                                             const int* __restrict__ nobj,
                                             const void* __restrict__ WG,
                                             const void* __restrict__ bG,
                                             ushort* __restrict__ glog,
                                             const int* __restrict__ flagp) {
    const int isbf = *flagp;
    const int i = blockIdx.x, bl = blockIdx.y;
    const int t = threadIdx.x;

    __shared__ _Float16 trig[128][76];   // stride 76 halves = 38 dwords: bank adv 6 -> ~2-way
    __shared__ _Float16 wgf[16][72];     // B operand: rows 8..15 zero
    __shared__ float mobja[128];
    __shared__ float bgs[8];

    for (int e = t; e < 1024; e += 256) {
        const int h = e >> 6, g = e & 63;
        wgf[h][g] = (_Float16)((h < 8) ? ldf(WG, (size_t)h * 64 + g, isbf) : 0.f);
    }
    if (t < 8) bgs[t] = ldf(bG, t, isbf);

    const float4 bi4 = ldbox(box, (size_t)bl * N_ + i, isbf);
    const float wi = bi4.z - bi4.x + 1.0f, hi = bi4.w - bi4.y + 1.0f;
    const float cxi = (bi4.x + bi4.z) * 0.5f, cyi = (bi4.y + bi4.w) * 0.5f;
    const float rwi = 1.0f / wi, rhi = 1.0f / hi;
    const float lwi = __logf(wi), lhi = __logf(hi);
    const int noi = nobj[bl * N_ + i];
    __syncthreads();

    const int wv = t >> 6, lane = t & 63, m16 = lane & 15, quad = lane >> 4;
    const half8 bf0 = *(const half8*)&wgf[m16][quad * 8];
    const half8 bf1 = *(const half8*)&wgf[m16][quad * 8 + 32];
    _Float16* gb = (_Float16*)glog +
                   ((((size_t)bl * 32 + (i >> 4)) * 8) * 16 + (i & 15)) * 512;
    const float dm[8] = {1.0f, 0.421696503f, 0.177827941f, 0.074989421f,
                         0.031622777f, 0.013335214f, 0.005623413f, 0.002371374f};

    for (int c = 0; c < 4; ++c) {
        const int jbase = c * 128;
        {   // phase 1: trig -> LDS; 2 threads per pair (each does 2 pos dims)
            const int pair = t >> 1, hf = t & 1;
            const int j = jbase + pair;
            const float4 bj4 = ldbox(box, (size_t)bl * N_ + j, isbf);
            const float wj = bj4.z - bj4.x + 1.0f, hj = bj4.w - bj4.y + 1.0f;
            float p0, p1;
            if (hf == 0) {
                const float cxj = (bj4.x + bj4.z) * 0.5f, cyj = (bj4.y + bj4.w) * 0.5f;
                p0 = __logf(fmaxf(fabsf((cxi - cxj) * rwi), 0.001f));
                p1 = __logf(fmaxf(fabsf((cyi - cyj) * rhi), 0.001f));
                mobja[pair] = (noi || nobj[bl * N_ + j]) ? 0.f : 1.f;
            } else {
                p0 = lwi - __logf(wj);
                p1 = lhi - __logf(hj);
            }
#pragma unroll
            for (int pp = 0; pp < 2; ++pp) {
                const float base = 100.f * (pp ? p1 : p0);
                half8 s8, c8;
#pragma unroll
                for (int f = 0; f < 8; ++f) {
                    float sv, cv;
                    __sincosf(base * dm[f], &sv, &cv);
                    s8[f] = (_Float16)sv;
                    c8[f] = (_Float16)cv;
                }
                const int g0 = hf * 16 + pp * 8;
                *(half4*)&trig[pair][g0]          = *(const half4*)&s8;
                *(half4*)&trig[pair][g0 + 4]      = *((const half4*)&s8 + 1);
                *(half4*)&trig[pair][32 + g0]     = *(const half4*)&c8;
                *(half4*)&trig[pair][32 + g0 + 4] = *((const half4*)&c8 + 1);
            }
        }
        __syncthreads();
        {   // phase 2: MFMA [16 pairs x 64] @ WG^T[64 x 8] + bias + log + store
#pragma unroll
            for (int sub = 0; sub < 2; ++sub) {
                const int row = wv * 32 + sub * 16 + m16;
                half8 a0, a1;
                *((half4*)&a0)     = *(const half4*)&trig[row][quad * 8];
                *((half4*)&a0 + 1) = *(const half4*)&trig[row][quad * 8 + 4];
                *((half4*)&a1)     = *(const half4*)&trig[row][32 + quad * 8];
                *((half4*)&a1 + 1) = *(const half4*)&trig[row][32 + quad * 8 + 4];
                floatx4 acc = {};
                acc = __builtin_amdgcn_mfma_f32_16x16x32_f16(a0, bf0, acc, 0, 0, 0);
                acc = __builtin_amdgcn_mfma_f32_16x16x32_f16(a1, bf1, acc, 0, 0, 0);
                if (m16 < 8) {
#pragma unroll
                    for (int r = 0; r < 4; ++r) {
                        const int pair = wv * 32 + sub * 16 + quad * 4 + r;
                        const float wg = acc[r] + bgs[m16];
                        const float gl = __logf(fmaxf(wg, 1e-6f)) * mobja[pair];
                        gb[(size_t)m16 * 8192 + jbase + pair] = (_Float16)gl;
                    }
                }
            }
        }
        __syncthreads();
    }
}

// ---------------- MFMA attention (proven round 5/6, unchanged) ----------------
__global__ __launch_bounds__(256) void attn3(
    const ushort* __restrict__ qw, const ushort* __restrict__ kw,
    const ushort* __restrict__ vt, const int* __restrict__ mask,
    const ushort* __restrict__ glog, ushort* __restrict__ att, int b0) {
    const int it = blockIdx.x, h = blockIdx.y, bl = blockIdx.z;
    const int bg = b0 + bl;
    const int i0 = it * 16;
    const int t = threadIdx.x, wv = t >> 6, lane = t & 63;
    const int m16 = lane & 15, quad = lane >> 4;
    const size_t bh = (size_t)(bg * H_ + h);

    __shared__ float lg[16][516];
    __shared__ ushort sbuf[16 * 520];
    __shared__ float rsumInv[16];

    {
        const uint4* src = (const uint4*)(glog + (((size_t)bl * 32 + it) * 8 + h) * 8192);
        uint4* dst = (uint4*)sbuf;
#pragma unroll
        for (int e = 0; e < 4; ++e) dst[t + 256 * e] = src[t + 256 * e];
    }
    const ushort* qrow = qw + (bh * N_ + i0 + m16) * DK_ + quad * 8;
    const short8 aq0 = *(const short8*)(qrow);
    const short8 aq1 = *(const short8*)(qrow + 32);
    __syncthreads();

#pragma unroll
    for (int tt = 0; tt < 8; ++tt) {
        const int j0 = wv * 128 + tt * 16;
        const ushort* krow = kw + (bh * N_ + j0 + m16) * DK_ + quad * 8;
        const short8 bk0 = *(const short8*)(krow);
        const short8 bk1 = *(const short8*)(krow + 32);
        floatx4 acc = {};
        acc = __builtin_amdgcn_mfma_f32_16x16x32_bf16(aq0, bk0, acc, 0, 0, 0);
        acc = __builtin_amdgcn_mfma_f32_16x16x32_bf16(aq1, bk1, acc, 0, 0, 0);
        const int mj = mask[bg * N_ + j0 + m16];
        const __half* gt = (const __half*)sbuf;
#pragma unroll
        for (int r = 0; r < 4; ++r) {
            const int i = quad * 4 + r;
            const float g = __half2float(gt[i * 512 + j0 + m16]);
            lg[i][j0 + m16] = (mj ? 0.125f * acc[r] : -1e9f) + g;
        }
    }
    __syncthreads();

    {
        const int row = t >> 4, l = t & 15;
        float v[32];
        float mx = -3e38f;
#pragma unroll
        for (int s = 0; s < 32; ++s) { v[s] = lg[row][l + 16 * s]; mx = fmaxf(mx, v[s]); }
#pragma unroll
        for (int d = 1; d < 16; d <<= 1) mx = fmaxf(mx, __shfl_xor(mx, d, 16));
        float sm = 0.f;
#pragma unroll
        for (int s = 0; s < 32; ++s) { const float p = __expf(v[s] - mx); sm += p; v[s] = p; }
#pragma unroll
        for (int d = 1; d < 16; d <<= 1) sm += __shfl_xor(sm, d, 16);
#pragma unroll
        for (int s = 0; s < 32; ++s) sbuf[row * 520 + l + 16 * s] = f2bf(v[s]);
        if (l == 0) rsumInv[row] = 1.0f / sm;
    }
    __syncthreads();

    {
        const int dk0 = wv * 16;
        const ushort* vrow = vt + (bh * DK_ + dk0 + m16) * N_ + quad * 8;
        floatx4 oc = {};
#pragma unroll
        for (int kc = 0; kc < 16; ++kc) {
            const short8 ap = *(const short8*)(sbuf + m16 * 520 + kc * 32 + quad * 8);
            const short8 bv = *(const short8*)(vrow + kc * 32);
            oc = __builtin_amdgcn_mfma_f32_16x16x32_bf16(ap, bv, oc, 0, 0, 0);
        }
#pragma unroll
        for (int r = 0; r < 4; ++r) {
            const int i = quad * 4 + r;
            const float o = oc[r] * rsumInv[i];
            att[((size_t)(bg * N_ + i0 + i)) * D_ + h * DK_ + dk0 + m16] = f2bf(o);
        }
    }
}

// ================= tier-3 fallback (round-3 proven) =================
__global__ __launch_bounds__(256) void gemm16(const void* __restrict__ A,
                                              const void* __restrict__ W,
                                              const void* __restrict__ bias,
                                              void* __restrict__ out,
                                              const int* __restrict__ flagp,
                                              int a_follows, int mode) {
    const int isbf = *flagp;
    const int a_isbf = a_follows ? isbf : 1;
    const int wave = threadIdx.x >> 6;
    const int tile = blockIdx.x * 4 + wave;
    const int tm = tile >> 5, tn = tile & 31;
    const int row0 = tm * 16, col0 = tn * 16;
    const int lane = threadIdx.x & 63;
    const int m = lane & 15, quad = lane >> 4;
    floatx4 acc = {0.f, 0.f, 0.f, 0.f};
    const size_t abase = (size_t)(row0 + m) * D_ + quad * 8;
    const size_t wbase = (size_t)(quad * 8) * D_ + col0 + m;
    for (int k0 = 0; k0 < D_; k0 += 32) {
        short8 af, bf;
#pragma unroll
        for (int j = 0; j < 8; ++j) af[j] = ldb(A, abase + k0 + j, a_isbf);
#pragma unroll
        for (int j = 0; j < 8; ++j) bf[j] = ldb(W, wbase + (size_t)(k0 + j) * D_, isbf);
        acc = __builtin_amdgcn_mfma_f32_16x16x32_bf16(af, bf, acc, 0, 0, 0);
    }
    const int col = col0 + m;
    const float bi = ldf(bias, col, isbf);
#pragma unroll
    for (int r = 0; r < 4; ++r) {
        const int row = row0 + quad * 4 + r;
        const float v = acc[r] + bi;
        if (mode == 1) {
            ((ushort*)out)[(size_t)(((row >> 9) * H_ + (col >> 6)) * N_ + (row & 511)) * DK_ + (col & 63)] = f2bf(v);
        } else if (isbf) {
            ((ushort*)out)[(size_t)row * D_ + col] = f2bf(v);
        } else {
            ((float*)out)[(size_t)row * D_ + col] = v;
        }
    }
}

__global__ __launch_bounds__(256) void attn_old(
    const ushort* __restrict__ qw, const ushort* __restrict__ kw,
    const ushort* __restrict__ vw, const void* __restrict__ box,
    const int* __restrict__ mask, const int* __restrict__ nobj,
    const void* __restrict__ WG, const void* __restrict__ bG,
    ushort* __restrict__ att, const int* __restrict__ flagp) {
    const int isbf = *flagp;
    const int b = blockIdx.z, h = blockIdx.y;
    const int i0 = blockIdx.x * 8;
    const int t = threadIdx.x;
    __shared__ float lg[8][520];
    __shared__ float q_s[8][68];
    __shared__ float wgh[64];
    __shared__ float cxi[8], cyi[8], rwi[8], rhi[8], lwi[8], lhi[8];
    __shared__ int noi[8];
    __shared__ float rsum[8];
    for (int e = t; e < 512; e += 256) {
        const int ii = e >> 6, dk = e & 63;
        q_s[ii][dk] = bf2f(qw[(size_t)((b * H_ + h) * N_ + i0 + ii) * DK_ + dk]) * 0.125f;
    }
    if (t < 64) wgh[t] = ldf(WG, h * 64 + t, isbf);
    if (t < 8) {
        const size_t bb = (size_t)(b * N_ + i0 + t) * 4;
        const float xmn = ldf(box, bb + 0, isbf), ymn = ldf(box, bb + 1, isbf);
        const float xmx = ldf(box, bb + 2, isbf), ymx = ldf(box, bb + 3, isbf);
        const float w = xmx - xmn + 1.0f, hh = ymx - ymn + 1.0f;
        cxi[t] = (xmn + xmx) * 0.5f;
        cyi[t] = (ymn + ymx) * 0.5f;
        rwi[t] = 1.0f / w;
        rhi[t] = 1.0f / hh;
        lwi[t] = __logf(w);
        lhi[t] = __logf(hh);
        noi[t] = nobj[b * N_ + i0 + t];
    }
    const float bg = ldf(bG, h, isbf);
    __syncthreads();
    for (int jl = 0; jl < 2; ++jl) {
        const int j = t + jl * 256;
        float acc[8];
#pragma unroll
        for (int ii = 0; ii < 8; ++ii) acc[ii] = 0.f;
        const uint4* krow = (const uint4*)(kw + (size_t)((b * H_ + h) * N_ + j) * DK_);
#pragma unroll
        for (int c = 0; c < 8; ++c) {
            const uint4 ku = krow[c];
            float kf[8];
            kf[0] = blo(ku.x); kf[1] = bhi(ku.x); kf[2] = blo(ku.y); kf[3] = bhi(ku.y);
            kf[4] = blo(ku.z); kf[5] = bhi(ku.z); kf[6] = blo(ku.w); kf[7] = bhi(ku.w);
#pragma unroll
            for (int ii = 0; ii < 8; ++ii) {
                const float4 qa = *(const float4*)(&q_s[ii][c * 8]);
                const float4 qb = *(const float4*)(&q_s[ii][c * 8 + 4]);
                acc[ii] += qa.x * kf[0] + qa.y * kf[1] + qa.z * kf[2] + qa.w * kf[3] +
                           qb.x * kf[4] + qb.y * kf[5] + qb.z * kf[6] + qb.w * kf[7];
            }
        }
        const int mj = mask[b * N_ + j];
        const size_t bb = (size_t)(b * N_ + j) * 4;
        const float xmn = ldf(box, bb + 0, isbf), ymn = ldf(box, bb + 1, isbf);
        const float xmx = ldf(box, bb + 2, isbf), ymx = ldf(box, bb + 3, isbf);
        const float cxj = (xmn + xmx) * 0.5f, cyj = (ymn + ymx) * 0.5f;
        const float wj = xmx - xmn + 1.0f, hj = ymx - ymn + 1.0f;
        const float lwj = __logf(wj), lhj = __logf(hj);
        const int noj = nobj[b * N_ + j];
        const float dm[8] = {1.0f, 0.421696503f, 0.177827941f, 0.074989421f,
                             0.031622777f, 0.013335214f, 0.005623413f, 0.002371374f};
        for (int ii = 0; ii < 8; ++ii) {
            const float mobj = (noi[ii] || noj) ? 0.f : 1.f;
            const float dx = __logf(fmaxf(fabsf((cxi[ii] - cxj) * rwi[ii]), 0.001f));
            const float dy = __logf(fmaxf(fabsf((cyi[ii] - cyj) * rhi[ii]), 0.001f));
            const float pos[4] = {dx, dy, lwi[ii] - lwj, lhi[ii] - lhj};
            float wg = bg;
            for (int p = 0; p < 4; ++p) {
                const float base = 100.f * pos[p];
#pragma unroll
                for (int f = 0; f < 8; ++f) {
                    float sv, cv;
                    __sincosf(base * dm[f], &sv, &cv);
                    const int g = p * 8 + f;
                    wg += sv * wgh[g] + cv * wgh[32 + g];
                }
            }
            lg[ii][j] = (mj ? acc[ii] : -1e9f) + __logf(fmaxf(wg, 1e-6f)) * mobj;
        }
    }
    __syncthreads();
    {
        const int rr = t >> 5, l32 = t & 31;
        float mx = -3e38f;
        for (int j = l32; j < N_; j += 32) mx = fmaxf(mx, lg[rr][j]);
#pragma unroll
        for (int d = 1; d < 32; d <<= 1) mx = fmaxf(mx, __shfl_xor(mx, d, 32));
        float sm = 0.f;
        for (int j = l32; j < N_; j += 32) {
            const float p = __expf(lg[rr][j] - mx);
            lg[rr][j] = p;
            sm += p;
        }
#pragma unroll
        for (int d = 1; d < 32; d <<= 1) sm += __shfl_xor(sm, d, 32);
        if (l32 == 0) rsum[rr] = sm;
    }
    __syncthreads();
    {
        const int ii = t >> 5, dkp = t & 31;
        float o0 = 0.f, o1 = 0.f;
        const uint* vbase = (const uint*)vw + (size_t)((b * H_ + h) * N_) * (DK_ / 2) + dkp;
        for (int j = 0; j < N_; ++j) {
            const uint u = vbase[(size_t)j * (DK_ / 2)];
            const float p = lg[ii][j];
            o0 += p * blo(u);
            o1 += p * bhi(u);
        }
        const float inv = 1.0f / rsum[ii];
        const uint pk = (uint)f2bf(o0 * inv) | ((uint)f2bf(o1 * inv) << 16);
        ((uint*)att)[(size_t)(b * N_ + i0 + ii) * (D_ / 2) + h * 32 + dkp] = pk;
    }
}

extern "C" void kernel_launch(void* const* d_in, const int* in_sizes, int n_in,
                              void* d_out, int out_size, void* d_ws, size_t ws_size,
                              hipStream_t stream) {
    const void* xq = d_in[0];
    const void* xk = d_in[1];
    const void* xv = d_in[2];
    const void* box = d_in[3];
    const int* mask = (const int*)d_in[4];
    const int* nobj = (const int*)d_in[5];
    const void* Wq = d_in[6];
    const void* bq = d_in[7];
    const void* Wk = d_in[8];
    const void* bk = d_in[9];
    const void* Wv = d_in[10];
    const void* bv = d_in[11];
    const void* Wo = d_in[12];
    const void* bo = d_in[13];
    const void* WG = d_in[14];
    const void* bG = d_in[15];

    char* ws = (char*)d_ws;
    const size_t MB = 1u << 20;

    if (ws_size >= 54 * MB) {   // tier-1 (confirmed active since round 3)
        int* flag = (int*)ws;
        float* biasf = (float*)(ws + 4096);
        ushort* wt = (ushort*)(ws + 16384);
        size_t p = 16384 + 2097152;
        ushort* qw = (ushort*)(ws + p); p += 4194304;
        ushort* kw = (ushort*)(ws + p); p += 4194304;
        ushort* vt = (ushort*)(ws + p); p += 4194304;
        ushort* att = (ushort*)(ws + p); p += 4194304;
        ushort* glog = (ushort*)(ws + p);   // 32 MB: [bl][it][h][16][512] fp16

        hipLaunchKernelGGL(probe_dtype, dim3(1), dim3(256), 0, stream, (const uint*)xq, flag);
        hipLaunchKernelGGL(transw, dim3(16, 16, 4), dim3(256), 0, stream,
                           Wq, Wk, Wv, Wo, bq, bk, bv, bo, wt, biasf, flag);
        hipLaunchKernelGGL(gemm0, dim3(32, 8, 3), dim3(256), 0, stream,
                           xq, xk, xv, wt, biasf, qw, kw, vt, flag);
        hipLaunchKernelGGL(geom2, dim3(N_, B_), dim3(256), 0, stream,
                           box, nobj, WG, bG, glog, flag);
        hipLaunchKernelGGL(attn3, dim3(32, H_, B_), dim3(256), 0, stream,
                           qw, kw, vt, mask, glog, att, 0);
        hipLaunchKernelGGL(gemm1, dim3(32, 8), dim3(256), 0, stream,
                           att, wt, biasf, d_out, flag);
    } else {
        // tier-3 fallback (proven round-3 path, ~16.6 MB)
        int* flag = (int*)ws;
        ushort* qw = (ushort*)(ws + 256);
        ushort* kw = (ushort*)(ws + 256 + 4194304);
        ushort* vw = (ushort*)(ws + 256 + 8388608);
        ushort* att = (ushort*)(ws + 256 + 12582912);
        hipLaunchKernelGGL(probe_dtype, dim3(1), dim3(256), 0, stream, (const uint*)xq, flag);
        hipLaunchKernelGGL(gemm16, dim3(2048), dim3(256), 0, stream, xq, Wq, bq, (void*)qw, flag, 1, 1);
        hipLaunchKernelGGL(gemm16, dim3(2048), dim3(256), 0, stream, xk, Wk, bk, (void*)kw, flag, 1, 1);
        hipLaunchKernelGGL(gemm16, dim3(2048), dim3(256), 0, stream, xv, Wv, bv, (void*)vw, flag, 1, 1);
        hipLaunchKernelGGL(attn_old, dim3(N_ / 8, H_, B_), dim3(256), 0, stream,
                           qw, kw, vw, box, mask, nobj, WG, bG, att, flag);
        hipLaunchKernelGGL(gemm16, dim3(2048), dim3(256), 0, stream, att, Wo, bo, d_out, flag, 0, 2);
    }
}

// Round 8
// 200.211 us; speedup vs baseline: 7.1979x; 1.0492x over previous
//
#include <hip/hip_runtime.h>
#include <hip/hip_fp16.h>

#define B_ 8
#define N_ 512
#define D_ 512
#define H_ 8
#define DK_ 64

typedef unsigned int uint;
typedef unsigned short ushort;
typedef __attribute__((ext_vector_type(8))) short short8;
typedef __attribute__((ext_vector_type(8))) _Float16 half8;
typedef __attribute__((ext_vector_type(4))) _Float16 half4;
typedef __attribute__((ext_vector_type(4))) float floatx4;

__device__ __forceinline__ float bf2f(ushort s) { return __uint_as_float(((uint)s) << 16); }
__device__ __forceinline__ ushort f2bf(float f) {
    uint x = __float_as_uint(f);
    return (ushort)((x + 0x7fffu + ((x >> 16) & 1u)) >> 16);
}
__device__ __forceinline__ float blo(uint u) { return __uint_as_float(u << 16); }
__device__ __forceinline__ float bhi(uint u) { return __uint_as_float(u & 0xffff0000u); }
__device__ __forceinline__ float ldf(const void* p, size_t i, int isbf) {
    return isbf ? bf2f(((const ushort*)p)[i]) : ((const float*)p)[i];
}
__device__ __forceinline__ short ldb(const void* p, size_t i, int isbf) {
    return isbf ? (short)(((const ushort*)p)[i]) : (short)f2bf(((const float*)p)[i]);
}
__device__ __forceinline__ float4 ldbox(const void* p, size_t row, int isbf) {
    if (isbf) {
        const uint2 u = ((const uint2*)p)[row];
        return make_float4(blo(u.x), bhi(u.x), blo(u.y), bhi(u.y));
    }
    return ((const float4*)p)[row];
}
// ---- ISA-level fast math (avoid ocml libcalls) ----
// v_log_f32 returns log2; v_exp_f32 computes 2^x; v_sin/v_cos take REVOLUTIONS.
__device__ __forceinline__ float flog(float x) {
    return __builtin_amdgcn_logf(x) * 0.69314718056f;
}
__device__ __forceinline__ float fexp(float x) {
    return __builtin_amdgcn_exp2f(x * 1.44269504089f);
}
__device__ __forceinline__ void fsincos_rev(float rev, float* s, float* c) {
    const float fr = rev - floorf(rev);   // [0,1) — always valid HW domain
    *s = __builtin_amdgcn_sinf(fr);
    *c = __builtin_amdgcn_cosf(fr);
}

// ---------------- dtype probe (proven) ----------------
__global__ __launch_bounds__(256) void probe_dtype(const uint* __restrict__ q,
                                                   int* __restrict__ flag) {
    __shared__ int s[256];
    const int t = threadIdx.x;
    int cnt = 0;
    for (int i = t; i < 4096; i += 256) {
        const uint e = (q[i] >> 7) & 0xffu;
        cnt += (e >= 0x70u && e <= 0x84u) ? 1 : 0;
    }
    s[t] = cnt;
    __syncthreads();
    for (int d = 128; d > 0; d >>= 1) {
        if (t < d) s[t] += s[t + d];
        __syncthreads();
    }
    if (t == 0) *flag = (s[0] > 3276) ? 1 : 0;
}

// ---------------- W transpose -> Wt[n][k] bf16, + bias convert folded in ----------------
__global__ __launch_bounds__(256) void transw(const void* __restrict__ w0,
                                              const void* __restrict__ w1,
                                              const void* __restrict__ w2,
                                              const void* __restrict__ w3,
                                              const void* __restrict__ b0,
                                              const void* __restrict__ b1,
                                              const void* __restrict__ b2,
                                              const void* __restrict__ b3,
                                              ushort* __restrict__ wt,
                                              float* __restrict__ biasf,
                                              const int* __restrict__ flagp) {
    const int isbf = *flagp;
    const int z = blockIdx.z;
    const void* W = (z == 0) ? w0 : (z == 1) ? w1 : (z == 2) ? w2 : w3;
    const int n0 = blockIdx.x * 32, k0 = blockIdx.y * 32;
    __shared__ float tile[32][33];
    const int tx = threadIdx.x & 31, ty = threadIdx.x >> 5;
#pragma unroll
    for (int r = 0; r < 4; ++r)
        tile[ty + 8 * r][tx] = ldf(W, (size_t)(k0 + ty + 8 * r) * D_ + n0 + tx, isbf);
    if (blockIdx.x == 0 && blockIdx.y == 0) {
        const void* bz = (z == 0) ? b0 : (z == 1) ? b1 : (z == 2) ? b2 : b3;
        for (int e = threadIdx.x; e < 512; e += 256)
            biasf[z * 512 + e] = ldf(bz, e, isbf);
    }
    __syncthreads();
#pragma unroll
    for (int r = 0; r < 4; ++r)
        wt[(size_t)z * 262144 + (size_t)(n0 + ty + 8 * r) * D_ + k0 + tx] =
            f2bf(tile[tx][ty + 8 * r]);
}

// ---------------- MFMA GEMM, QKV: runtime dtype + k+1 reg prefetch ----------------
__global__ __launch_bounds__(256) void gemm0(
    const void* __restrict__ A0, const void* __restrict__ A1, const void* __restrict__ A2,
    const ushort* __restrict__ wt, const float* __restrict__ biasf,
    ushort* __restrict__ oq, ushort* __restrict__ ok, ushort* __restrict__ ov,
    const int* __restrict__ flagp) {
    const int isbf = *flagp;
    const int z = blockIdx.z;
    const char* A = (const char*)((z == 0) ? A0 : (z == 1) ? A1 : A2);
    const ushort* W = wt + (size_t)z * 262144;
    const float* bias = biasf + z * 512;
    const int row0 = blockIdx.x * 128, col0 = blockIdx.y * 64;
    const int t = threadIdx.x, wv = t >> 6, lane = t & 63;
    const int m16 = lane & 15, quad = lane >> 4;

    __shared__ ushort As[128][40];
    __shared__ ushort Ws[64][40];
    floatx4 acc[2][4] = {};

    const int ar = t >> 1, ah = t & 1;
    const int wr = t >> 2, wc = (t & 3) * 8;

    float4 pf0, pf1, pf2, pf3;
    short8 ps0, ps1, pw;

    auto loadA = [&](int k0) {
        const size_t e = (size_t)(row0 + ar) * D_ + k0 + ah * 16;
        if (isbf) {
            ps0 = *(const short8*)(A + 2 * e);
            ps1 = *(const short8*)(A + 2 * e + 16);
        } else {
            const float* ap = (const float*)(A + 4 * e);
            pf0 = *(const float4*)(ap);
            pf1 = *(const float4*)(ap + 4);
            pf2 = *(const float4*)(ap + 8);
            pf3 = *(const float4*)(ap + 12);
        }
        pw = *(const short8*)(W + (size_t)(col0 + wr) * D_ + k0 + wc);
    };
    auto stage = [&]() {
        short8 s0, s1;
        if (isbf) {
            s0 = ps0; s1 = ps1;
        } else {
            s0[0] = (short)f2bf(pf0.x); s0[1] = (short)f2bf(pf0.y);
            s0[2] = (short)f2bf(pf0.z); s0[3] = (short)f2bf(pf0.w);
            s0[4] = (short)f2bf(pf1.x); s0[5] = (short)f2bf(pf1.y);
            s0[6] = (short)f2bf(pf1.z); s0[7] = (short)f2bf(pf1.w);
            s1[0] = (short)f2bf(pf2.x); s1[1] = (short)f2bf(pf2.y);
            s1[2] = (short)f2bf(pf2.z); s1[3] = (short)f2bf(pf2.w);
            s1[4] = (short)f2bf(pf3.x); s1[5] = (short)f2bf(pf3.y);
            s1[6] = (short)f2bf(pf3.z); s1[7] = (short)f2bf(pf3.w);
        }
        *(short8*)&As[ar][ah * 16] = s0;
        *(short8*)&As[ar][ah * 16 + 8] = s1;
        *(short8*)&Ws[wr][wc] = pw;
    };

    loadA(0);
    for (int k0 = 0; k0 < D_; k0 += 32) {
        __syncthreads();
        stage();
        __syncthreads();
        if (k0 + 32 < D_) loadA(k0 + 32);

        const short8 a0 = *(const short8*)&As[wv * 32 + m16][quad * 8];
        const short8 a1 = *(const short8*)&As[wv * 32 + 16 + m16][quad * 8];
        const short8 b0 = *(const short8*)&Ws[m16][quad * 8];
        const short8 b1 = *(const short8*)&Ws[16 + m16][quad * 8];
        const short8 b2 = *(const short8*)&Ws[32 + m16][quad * 8];
        const short8 b3 = *(const short8*)&Ws[48 + m16][quad * 8];
        acc[0][0] = __builtin_amdgcn_mfma_f32_16x16x32_bf16(a0, b0, acc[0][0], 0, 0, 0);
        acc[0][1] = __builtin_amdgcn_mfma_f32_16x16x32_bf16(a0, b1, acc[0][1], 0, 0, 0);
        acc[0][2] = __builtin_amdgcn_mfma_f32_16x16x32_bf16(a0, b2, acc[0][2], 0, 0, 0);
        acc[0][3] = __builtin_amdgcn_mfma_f32_16x16x32_bf16(a0, b3, acc[0][3], 0, 0, 0);
        acc[1][0] = __builtin_amdgcn_mfma_f32_16x16x32_bf16(a1, b0, acc[1][0], 0, 0, 0);
        acc[1][1] = __builtin_amdgcn_mfma_f32_16x16x32_bf16(a1, b1, acc[1][1], 0, 0, 0);
        acc[1][2] = __builtin_amdgcn_mfma_f32_16x16x32_bf16(a1, b2, acc[1][2], 0, 0, 0);
        acc[1][3] = __builtin_amdgcn_mfma_f32_16x16x32_bf16(a1, b3, acc[1][3], 0, 0, 0);
    }

#pragma unroll
    for (int mt = 0; mt < 2; ++mt) {
#pragma unroll
        for (int nt = 0; nt < 4; ++nt) {
            const int colg = col0 + nt * 16 + m16;
            const float bi = bias[colg];
            const float v0 = acc[mt][nt][0] + bi, v1 = acc[mt][nt][1] + bi;
            const float v2 = acc[mt][nt][2] + bi, v3 = acc[mt][nt][3] + bi;
            const int rowb = row0 + wv * 32 + mt * 16 + quad * 4;
            if (z == 2) {
                const int bhv = (rowb >> 9) * H_ + (colg >> 6);
                uint2 pk;
                pk.x = (uint)f2bf(v0) | ((uint)f2bf(v1) << 16);
                pk.y = (uint)f2bf(v2) | ((uint)f2bf(v3) << 16);
                *(uint2*)(ov + ((size_t)bhv * DK_ + (colg & 63)) * N_ + (rowb & 511)) = pk;
            } else {
                ushort* o = (z == 0) ? oq : ok;
                const float vv[4] = {v0, v1, v2, v3};
#pragma unroll
                for (int r = 0; r < 4; ++r) {
                    const int row = rowb + r;
                    o[((size_t)((row >> 9) * H_ + (colg >> 6)) * N_ + (row & 511)) * DK_ +
                      (colg & 63)] = f2bf(vv[r]);
                }
            }
        }
    }
}

// ---------------- MFMA GEMM, output proj ----------------
__global__ __launch_bounds__(256) void gemm1(
    const ushort* __restrict__ att, const ushort* __restrict__ wt,
    const float* __restrict__ biasf, void* __restrict__ dout,
    const int* __restrict__ flagp) {
    const int isbf = *flagp;
    const ushort* W = wt + (size_t)3 * 262144;
    const float* bias = biasf + 3 * 512;
    const int row0 = blockIdx.x * 128, col0 = blockIdx.y * 64;
    const int t = threadIdx.x, wv = t >> 6, lane = t & 63;
    const int m16 = lane & 15, quad = lane >> 4;

    __shared__ ushort As[128][40];
    __shared__ ushort Ws[64][40];
    floatx4 acc[2][4] = {};

    const int ar = t >> 1, ah = t & 1;
    const int wr = t >> 2, wc = (t & 3) * 8;

    short8 ps0, ps1, pw;
    auto loadA = [&](int k0) {
        const ushort* ap = att + (size_t)(row0 + ar) * D_ + k0 + ah * 16;
        ps0 = *(const short8*)(ap);
        ps1 = *(const short8*)(ap + 8);
        pw = *(const short8*)(W + (size_t)(col0 + wr) * D_ + k0 + wc);
    };

    loadA(0);
    for (int k0 = 0; k0 < D_; k0 += 32) {
        __syncthreads();
        *(short8*)&As[ar][ah * 16] = ps0;
        *(short8*)&As[ar][ah * 16 + 8] = ps1;
        *(short8*)&Ws[wr][wc] = pw;
        __syncthreads();
        if (k0 + 32 < D_) loadA(k0 + 32);

        const short8 a0 = *(const short8*)&As[wv * 32 + m16][quad * 8];
        const short8 a1 = *(const short8*)&As[wv * 32 + 16 + m16][quad * 8];
        const short8 b0 = *(const short8*)&Ws[m16][quad * 8];
        const short8 b1 = *(const short8*)&Ws[16 + m16][quad * 8];
        const short8 b2 = *(const short8*)&Ws[32 + m16][quad * 8];
        const short8 b3 = *(const short8*)&Ws[48 + m16][quad * 8];
        acc[0][0] = __builtin_amdgcn_mfma_f32_16x16x32_bf16(a0, b0, acc[0][0], 0, 0, 0);
        acc[0][1] = __builtin_amdgcn_mfma_f32_16x16x32_bf16(a0, b1, acc[0][1], 0, 0, 0);
        acc[0][2] = __builtin_amdgcn_mfma_f32_16x16x32_bf16(a0, b2, acc[0][2], 0, 0, 0);
        acc[0][3] = __builtin_amdgcn_mfma_f32_16x16x32_bf16(a0, b3, acc[0][3], 0, 0, 0);
        acc[1][0] = __builtin_amdgcn_mfma_f32_16x16x32_bf16(a1, b0, acc[1][0], 0, 0, 0);
        acc[1][1] = __builtin_amdgcn_mfma_f32_16x16x32_bf16(a1, b1, acc[1][1], 0, 0, 0);
        acc[1][2] = __builtin_amdgcn_mfma_f32_16x16x32_bf16(a1, b2, acc[1][2], 0, 0, 0);
        acc[1][3] = __builtin_amdgcn_mfma_f32_16x16x32_bf16(a1, b3, acc[1][3], 0, 0, 0);
    }

#pragma unroll
    for (int mt = 0; mt < 2; ++mt) {
#pragma unroll
        for (int nt = 0; nt < 4; ++nt) {
            const int colg = col0 + nt * 16 + m16;
            const float bi = bias[colg];
#pragma unroll
            for (int r = 0; r < 4; ++r) {
                const int row = row0 + wv * 32 + mt * 16 + quad * 4 + r;
                const float v = acc[mt][nt][r] + bi;
                if (isbf) ((ushort*)dout)[(size_t)row * D_ + colg] = f2bf(v);
                else      ((float*)dout)[(size_t)row * D_ + colg] = v;
            }
        }
    }
}

// ---------------- geometry log-bias v4: raw v_sin/v_cos, no libcalls ----------------
// glog layout: [bl][it(32)][h(8)][ii(16)][j(512)] fp16 (unchanged; attn3 untouched)
__global__ __launch_bounds__(256) void geom2(const void* __restrict__ box,
                                             const int* __restrict__ nobj,
                                             const void* __restrict__ WG,
                                             const void* __restrict__ bG,
                                             ushort* __restrict__ glog,
                                             const int* __restrict__ flagp) {
    const int isbf = *flagp;
    const int i = blockIdx.x, bl = blockIdx.y;
    const int t = threadIdx.x;

    __shared__ _Float16 trig[128][76];
    __shared__ _Float16 wgf[16][72];
    __shared__ float mobja[128];
    __shared__ float bgs[8];

    for (int e = t; e < 1024; e += 256) {
        const int h = e >> 6, g = e & 63;
        wgf[h][g] = (_Float16)((h < 8) ? ldf(WG, (size_t)h * 64 + g, isbf) : 0.f);
    }
    if (t < 8) bgs[t] = ldf(bG, t, isbf);

    const float4 bi4 = ldbox(box, (size_t)bl * N_ + i, isbf);
    const float wi = bi4.z - bi4.x + 1.0f, hi = bi4.w - bi4.y + 1.0f;
    const float cxi = (bi4.x + bi4.z) * 0.5f, cyi = (bi4.y + bi4.w) * 0.5f;
    const float rwi = 1.0f / wi, rhi = 1.0f / hi;
    const float lwi = flog(wi), lhi = flog(hi);
    const int noi = nobj[bl * N_ + i];
    __syncthreads();

    const int wv = t >> 6, lane = t & 63, m16 = lane & 15, quad = lane >> 4;
    const half8 bf0 = *(const half8*)&wgf[m16][quad * 8];
    const half8 bf1 = *(const half8*)&wgf[m16][quad * 8 + 32];
    _Float16* gb = (_Float16*)glog +
                   ((((size_t)bl * 32 + (i >> 4)) * 8) * 16 + (i & 15)) * 512;
    // 100 * dim_mat[f] / (2*pi): angle in REVOLUTIONS = pos * dmrev[f]
    const float dmrev[8] = {15.915494f, 6.7115083f, 2.8302207f, 1.1934936f,
                            0.50329214f, 0.21223603f, 0.089498095f, 0.037742074f};

    for (int c = 0; c < 4; ++c) {
        const int jbase = c * 128;
        {   // phase 1: trig -> LDS; 2 threads per pair (each does 2 pos dims)
            const int pair = t >> 1, hf = t & 1;
            const int j = jbase + pair;
            const float4 bj4 = ldbox(box, (size_t)bl * N_ + j, isbf);
            const float wj = bj4.z - bj4.x + 1.0f, hj = bj4.w - bj4.y + 1.0f;
            float p0, p1;
            if (hf == 0) {
                const float cxj = (bj4.x + bj4.z) * 0.5f, cyj = (bj4.y + bj4.w) * 0.5f;
                p0 = flog(fmaxf(fabsf((cxi - cxj) * rwi), 0.001f));
                p1 = flog(fmaxf(fabsf((cyi - cyj) * rhi), 0.001f));
                mobja[pair] = (noi || nobj[bl * N_ + j]) ? 0.f : 1.f;
            } else {
                p0 = lwi - flog(wj);
                p1 = lhi - flog(hj);
            }
#pragma unroll
            for (int pp = 0; pp < 2; ++pp) {
                const float base = pp ? p1 : p0;
                half8 s8, c8;
#pragma unroll
                for (int f = 0; f < 8; ++f) {
                    float sv, cv;
                    fsincos_rev(base * dmrev[f], &sv, &cv);
                    s8[f] = (_Float16)sv;
                    c8[f] = (_Float16)cv;
                }
                const int g0 = hf * 16 + pp * 8;
                *(half4*)&trig[pair][g0]          = *(const half4*)&s8;
                *(half4*)&trig[pair][g0 + 4]      = *((const half4*)&s8 + 1);
                *(half4*)&trig[pair][32 + g0]     = *(const half4*)&c8;
                *(half4*)&trig[pair][32 + g0 + 4] = *((const half4*)&c8 + 1);
            }
        }
        __syncthreads();
        {   // phase 2: MFMA [16 pairs x 64] @ WG^T[64 x 8] + bias + log + store
#pragma unroll
            for (int sub = 0; sub < 2; ++sub) {
                const int row = wv * 32 + sub * 16 + m16;
                half8 a0, a1;
                *((half4*)&a0)     = *(const half4*)&trig[row][quad * 8];
                *((half4*)&a0 + 1) = *(const half4*)&trig[row][quad * 8 + 4];
                *((half4*)&a1)     = *(const half4*)&trig[row][32 + quad * 8];
                *((half4*)&a1 + 1) = *(const half4*)&trig[row][32 + quad * 8 + 4];
                floatx4 acc = {};
                acc = __builtin_amdgcn_mfma_f32_16x16x32_f16(a0, bf0, acc, 0, 0, 0);
                acc = __builtin_amdgcn_mfma_f32_16x16x32_f16(a1, bf1, acc, 0, 0, 0);
                if (m16 < 8) {
#pragma unroll
                    for (int r = 0; r < 4; ++r) {
                        const int pair = wv * 32 + sub * 16 + quad * 4 + r;
                        const float wg = acc[r] + bgs[m16];
                        const float gl = flog(fmaxf(wg, 1e-6f)) * mobja[pair];
                        gb[(size_t)m16 * 8192 + jbase + pair] = (_Float16)gl;
                    }
                }
            }
        }
        __syncthreads();
    }
}

// ---------------- MFMA attention (round 5/6 structure, fexp softmax) ----------------
__global__ __launch_bounds__(256) void attn3(
    const ushort* __restrict__ qw, const ushort* __restrict__ kw,
    const ushort* __restrict__ vt, const int* __restrict__ mask,
    const ushort* __restrict__ glog, ushort* __restrict__ att, int b0) {
    const int it = blockIdx.x, h = blockIdx.y, bl = blockIdx.z;
    const int bg = b0 + bl;
    const int i0 = it * 16;
    const int t = threadIdx.x, wv = t >> 6, lane = t & 63;
    const int m16 = lane & 15, quad = lane >> 4;
    const size_t bh = (size_t)(bg * H_ + h);

    __shared__ float lg[16][516];
    __shared__ ushort sbuf[16 * 520];
    __shared__ float rsumInv[16];

    {
        const uint4* src = (const uint4*)(glog + (((size_t)bl * 32 + it) * 8 + h) * 8192);
        uint4* dst = (uint4*)sbuf;
#pragma unroll
        for (int e = 0; e < 4; ++e) dst[t + 256 * e] = src[t + 256 * e];
    }
    const ushort* qrow = qw + (bh * N_ + i0 + m16) * DK_ + quad * 8;
    const short8 aq0 = *(const short8*)(qrow);
    const short8 aq1 = *(const short8*)(qrow + 32);
    __syncthreads();

#pragma unroll
    for (int tt = 0; tt < 8; ++tt) {
        const int j0 = wv * 128 + tt * 16;
        const ushort* krow = kw + (bh * N_ + j0 + m16) * DK_ + quad * 8;
        const short8 bk0 = *(const short8*)(krow);
        const short8 bk1 = *(const short8*)(krow + 32);
        floatx4 acc = {};
        acc = __builtin_amdgcn_mfma_f32_16x16x32_bf16(aq0, bk0, acc, 0, 0, 0);
        acc = __builtin_amdgcn_mfma_f32_16x16x32_bf16(aq1, bk1, acc, 0, 0, 0);
        const int mj = mask[bg * N_ + j0 + m16];
        const __half* gt = (const __half*)sbuf;
#pragma unroll
        for (int r = 0; r < 4; ++r) {
            const int i = quad * 4 + r;
            const float g = __half2float(gt[i * 512 + j0 + m16]);
            lg[i][j0 + m16] = (mj ? 0.125f * acc[r] : -1e9f) + g;
        }
    }
    __syncthreads();

    {
        const int row = t >> 4, l = t & 15;
        float v[32];
        float mx = -3e38f;
#pragma unroll
        for (int s = 0; s < 32; ++s) { v[s] = lg[row][l + 16 * s]; mx = fmaxf(mx, v[s]); }
#pragma unroll
        for (int d = 1; d < 16; d <<= 1) mx = fmaxf(mx, __shfl_xor(mx, d, 16));
        float sm = 0.f;
#pragma unroll
        for (int s = 0; s < 32; ++s) { const float p = fexp(v[s] - mx); sm += p; v[s] = p; }
#pragma unroll
        for (int d = 1; d < 16; d <<= 1) sm += __shfl_xor(sm, d, 16);
#pragma unroll
        for (int s = 0; s < 32; ++s) sbuf[row * 520 + l + 16 * s] = f2bf(v[s]);
        if (l == 0) rsumInv[row] = 1.0f / sm;
    }
    __syncthreads();

    {
        const int dk0 = wv * 16;
        const ushort* vrow = vt + (bh * DK_ + dk0 + m16) * N_ + quad * 8;
        floatx4 oc = {};
#pragma unroll
        for (int kc = 0; kc < 16; ++kc) {
            const short8 ap = *(const short8*)(sbuf + m16 * 520 + kc * 32 + quad * 8);
            const short8 bv = *(const short8*)(vrow + kc * 32);
            oc = __builtin_amdgcn_mfma_f32_16x16x32_bf16(ap, bv, oc, 0, 0, 0);
        }
#pragma unroll
        for (int r = 0; r < 4; ++r) {
            const int i = quad * 4 + r;
            const float o = oc[r] * rsumInv[i];
            att[((size_t)(bg * N_ + i0 + i)) * D_ + h * DK_ + dk0 + m16] = f2bf(o);
        }
    }
}

// ================= tier-3 fallback (round-3 proven, unchanged) =================
__global__ __launch_bounds__(256) void gemm16(const void* __restrict__ A,
                                              const void* __restrict__ W,
                                              const void* __restrict__ bias,
                                              void* __restrict__ out,
                                              const int* __restrict__ flagp,
                                              int a_follows, int mode) {
    const int isbf = *flagp;
    const int a_isbf = a_follows ? isbf : 1;
    const int wave = threadIdx.x >> 6;
    const int tile = blockIdx.x * 4 + wave;
    const int tm = tile >> 5, tn = tile & 31;
    const int row0 = tm * 16, col0 = tn * 16;
    const int lane = threadIdx.x & 63;
    const int m = lane & 15, quad = lane >> 4;
    floatx4 acc = {0.f, 0.f, 0.f, 0.f};
    const size_t abase = (size_t)(row0 + m) * D_ + quad * 8;
    const size_t wbase = (size_t)(quad * 8) * D_ + col0 + m;
    for (int k0 = 0; k0 < D_; k0 += 32) {
        short8 af, bf;
#pragma unroll
        for (int j = 0; j < 8; ++j) af[j] = ldb(A, abase + k0 + j, a_isbf);
#pragma unroll
        for (int j = 0; j < 8; ++j) bf[j] = ldb(W, wbase + (size_t)(k0 + j) * D_, isbf);
        acc = __builtin_amdgcn_mfma_f32_16x16x32_bf16(af, bf, acc, 0, 0, 0);
    }
    const int col = col0 + m;
    const float bi = ldf(bias, col, isbf);
#pragma unroll
    for (int r = 0; r < 4; ++r) {
        const int row = row0 + quad * 4 + r;
        const float v = acc[r] + bi;
        if (mode == 1) {
            ((ushort*)out)[(size_t)(((row >> 9) * H_ + (col >> 6)) * N_ + (row & 511)) * DK_ + (col & 63)] = f2bf(v);
        } else if (isbf) {
            ((ushort*)out)[(size_t)row * D_ + col] = f2bf(v);
        } else {
            ((float*)out)[(size_t)row * D_ + col] = v;
        }
    }
}

__global__ __launch_bounds__(256) void attn_old(
    const ushort* __restrict__ qw, const ushort* __restrict__ kw,
    const ushort* __restrict__ vw, const void* __restrict__ box,
    const int* __restrict__ mask, const int* __restrict__ nobj,
    const void* __restrict__ WG, const void* __restrict__ bG,
    ushort* __restrict__ att, const int* __restrict__ flagp) {
    const int isbf = *flagp;
    const int b = blockIdx.z, h = blockIdx.y;
    const int i0 = blockIdx.x * 8;
    const int t = threadIdx.x;
    __shared__ float lg[8][520];
    __shared__ float q_s[8][68];
    __shared__ float wgh[64];
    __shared__ float cxi[8], cyi[8], rwi[8], rhi[8], lwi[8], lhi[8];
    __shared__ int noi[8];
    __shared__ float rsum[8];
    for (int e = t; e < 512; e += 256) {
        const int ii = e >> 6, dk = e & 63;
        q_s[ii][dk] = bf2f(qw[(size_t)((b * H_ + h) * N_ + i0 + ii) * DK_ + dk]) * 0.125f;
    }
    if (t < 64) wgh[t] = ldf(WG, h * 64 + t, isbf);
    if (t < 8) {
        const size_t bb = (size_t)(b * N_ + i0 + t) * 4;
        const float xmn = ldf(box, bb + 0, isbf), ymn = ldf(box, bb + 1, isbf);
        const float xmx = ldf(box, bb + 2, isbf), ymx = ldf(box, bb + 3, isbf);
        const float w = xmx - xmn + 1.0f, hh = ymx - ymn + 1.0f;
        cxi[t] = (xmn + xmx) * 0.5f;
        cyi[t] = (ymn + ymx) * 0.5f;
        rwi[t] = 1.0f / w;
        rhi[t] = 1.0f / hh;
        lwi[t] = __logf(w);
        lhi[t] = __logf(hh);
        noi[t] = nobj[b * N_ + i0 + t];
    }
    const float bg = ldf(bG, h, isbf);
    __syncthreads();
    for (int jl = 0; jl < 2; ++jl) {
        const int j = t + jl * 256;
        float acc[8];
#pragma unroll
        for (int ii = 0; ii < 8; ++ii) acc[ii] = 0.f;
        const uint4* krow = (const uint4*)(kw + (size_t)((b * H_ + h) * N_ + j) * DK_);
#pragma unroll
        for (int c = 0; c < 8; ++c) {
            const uint4 ku = krow[c];
            float kf[8];
            kf[0] = blo(ku.x); kf[1] = bhi(ku.x); kf[2] = blo(ku.y); kf[3] = bhi(ku.y);
            kf[4] = blo(ku.z); kf[5] = bhi(ku.z); kf[6] = blo(ku.w); kf[7] = bhi(ku.w);
#pragma unroll
            for (int ii = 0; ii < 8; ++ii) {
                const float4 qa = *(const float4*)(&q_s[ii][c * 8]);
                const float4 qb = *(const float4*)(&q_s[ii][c * 8 + 4]);
                acc[ii] += qa.x * kf[0] + qa.y * kf[1] + qa.z * kf[2] + qa.w * kf[3] +
                           qb.x * kf[4] + qb.y * kf[5] + qb.z * kf[6] + qb.w * kf[7];
            }
        }
        const int mj = mask[b * N_ + j];
        const size_t bb = (size_t)(b * N_ + j) * 4;
        const float xmn = ldf(box, bb + 0, isbf), ymn = ldf(box, bb + 1, isbf);
        const float xmx = ldf(box, bb + 2, isbf), ymx = ldf(box, bb + 3, isbf);
        const float cxj = (xmn + xmx) * 0.5f, cyj = (ymn + ymx) * 0.5f;
        const float wj = xmx - xmn + 1.0f, hj = ymx - ymn + 1.0f;
        const float lwj = __logf(wj), lhj = __logf(hj);
        const int noj = nobj[b * N_ + j];
        const float dm[8] = {1.0f, 0.421696503f, 0.177827941f, 0.074989421f,
                             0.031622777f, 0.013335214f, 0.005623413f, 0.002371374f};
        for (int ii = 0; ii < 8; ++ii) {
            const float mobj = (noi[ii] || noj) ? 0.f : 1.f;
            const float dx = __logf(fmaxf(fabsf((cxi[ii] - cxj) * rwi[ii]), 0.001f));
            const float dy = __logf(fmaxf(fabsf((cyi[ii] - cyj) * rhi[ii]), 0.001f));
            const float pos[4] = {dx, dy, lwi[ii] - lwj, lhi[ii] - lhj};
            float wg = bg;
            for (int p = 0; p < 4; ++p) {
                const float base = 100.f * pos[p];
#pragma unroll
                for (int f = 0; f < 8; ++f) {
                    float sv, cv;
                    __sincosf(base * dm[f], &sv, &cv);
                    const int g = p * 8 + f;
                    wg += sv * wgh[g] + cv * wgh[32 + g];
                }
            }
            lg[ii][j] = (mj ? acc[ii] : -1e9f) + __logf(fmaxf(wg, 1e-6f)) * mobj;
        }
    }
    __syncthreads();
    {
        const int rr = t >> 5, l32 = t & 31;
        float mx = -3e38f;
        for (int j = l32; j < N_; j += 32) mx = fmaxf(mx, lg[rr][j]);
#pragma unroll
        for (int d = 1; d < 32; d <<= 1) mx = fmaxf(mx, __shfl_xor(mx, d, 32));
        float sm = 0.f;
        for (int j = l32; j < N_; j += 32) {
            const float p = __expf(lg[rr][j] - mx);
            lg[rr][j] = p;
            sm += p;
        }
#pragma unroll
        for (int d = 1; d < 32; d <<= 1) sm += __shfl_xor(sm, d, 32);
        if (l32 == 0) rsum[rr] = sm;
    }
    __syncthreads();
    {
        const int ii = t >> 5, dkp = t & 31;
        float o0 = 0.f, o1 = 0.f;
        const uint* vbase = (const uint*)vw + (size_t)((b * H_ + h) * N_) * (DK_ / 2) + dkp;
        for (int j = 0; j < N_; ++j) {
            const uint u = vbase[(size_t)j * (DK_ / 2)];
            const float p = lg[ii][j];
            o0 += p * blo(u);
            o1 += p * bhi(u);
        }
        const float inv = 1.0f / rsum[ii];
        const uint pk = (uint)f2bf(o0 * inv) | ((uint)f2bf(o1 * inv) << 16);
        ((uint*)att)[(size_t)(b * N_ + i0 + ii) * (D_ / 2) + h * 32 + dkp] = pk;
    }
}

extern "C" void kernel_launch(void* const* d_in, const int* in_sizes, int n_in,
                              void* d_out, int out_size, void* d_ws, size_t ws_size,
                              hipStream_t stream) {
    const void* xq = d_in[0];
    const void* xk = d_in[1];
    const void* xv = d_in[2];
    const void* box = d_in[3];
    const int* mask = (const int*)d_in[4];
    const int* nobj = (const int*)d_in[5];
    const void* Wq = d_in[6];
    const void* bq = d_in[7];
    const void* Wk = d_in[8];
    const void* bk = d_in[9];
    const void* Wv = d_in[10];
    const void* bv = d_in[11];
    const void* Wo = d_in[12];
    const void* bo = d_in[13];
    const void* WG = d_in[14];
    const void* bG = d_in[15];

    char* ws = (char*)d_ws;
    const size_t MB = 1u << 20;

    if (ws_size >= 54 * MB) {   // tier-1 (confirmed active since round 3)
        int* flag = (int*)ws;
        float* biasf = (float*)(ws + 4096);
        ushort* wt = (ushort*)(ws + 16384);
        size_t p = 16384 + 2097152;
        ushort* qw = (ushort*)(ws + p); p += 4194304;
        ushort* kw = (ushort*)(ws + p); p += 4194304;
        ushort* vt = (ushort*)(ws + p); p += 4194304;
        ushort* att = (ushort*)(ws + p); p += 4194304;
        ushort* glog = (ushort*)(ws + p);   // 32 MB: [bl][it][h][16][512] fp16

        hipLaunchKernelGGL(probe_dtype, dim3(1), dim3(256), 0, stream, (const uint*)xq, flag);
        hipLaunchKernelGGL(transw, dim3(16, 16, 4), dim3(256), 0, stream,
                           Wq, Wk, Wv, Wo, bq, bk, bv, bo, wt, biasf, flag);
        hipLaunchKernelGGL(gemm0, dim3(32, 8, 3), dim3(256), 0, stream,
                           xq, xk, xv, wt, biasf, qw, kw, vt, flag);
        hipLaunchKernelGGL(geom2, dim3(N_, B_), dim3(256), 0, stream,
                           box, nobj, WG, bG, glog, flag);
        hipLaunchKernelGGL(attn3, dim3(32, H_, B_), dim3(256), 0, stream,
                           qw, kw, vt, mask, glog, att, 0);
        hipLaunchKernelGGL(gemm1, dim3(32, 8), dim3(256), 0, stream,
                           att, wt, biasf, d_out, flag);
    } else {
        // tier-3 fallback (proven round-3 path, ~16.6 MB)
        int* flag = (int*)ws;
        ushort* qw = (ushort*)(ws + 256);
        ushort* kw = (ushort*)(ws + 256 + 4194304);
        ushort* vw = (ushort*)(ws + 256 + 8388608);
        ushort* att = (ushort*)(ws + 256 + 12582912);
        hipLaunchKernelGGL(probe_dtype, dim3(1), dim3(256), 0, stream, (const uint*)xq, flag);
        hipLaunchKernelGGL(gemm16, dim3(2048), dim3(256), 0, stream, xq, Wq, bq, (void*)qw, flag, 1, 1);
        hipLaunchKernelGGL(gemm16, dim3(2048), dim3(256), 0, stream, xk, Wk, bk, (void*)kw, flag, 1, 1);
        hipLaunchKernelGGL(gemm16, dim3(2048), dim3(256), 0, stream, xv, Wv, bv, (void*)vw, flag, 1, 1);
        hipLaunchKernelGGL(attn_old, dim3(N_ / 8, H_, B_), dim3(256), 0, stream,
                           qw, kw, vw, box, mask, nobj, WG, bG, att, flag);
        hipLaunchKernelGGL(gemm16, dim3(2048), dim3(256), 0, stream, att, Wo, bo, d_out, flag, 0, 2);
    }
}

// Round 9
// 198.187 us; speedup vs baseline: 7.2714x; 1.0102x over previous
//
#include <hip/hip_runtime.h>
#include <hip/hip_fp16.h>

#define B_ 8
#define N_ 512
#define D_ 512
#define H_ 8
#define DK_ 64

typedef unsigned int uint;
typedef unsigned short ushort;
typedef __attribute__((ext_vector_type(8))) short short8;
typedef __attribute__((ext_vector_type(8))) _Float16 half8;
typedef __attribute__((ext_vector_type(4))) _Float16 half4;
typedef __attribute__((ext_vector_type(4))) float floatx4;

__device__ __forceinline__ float bf2f(ushort s) { return __uint_as_float(((uint)s) << 16); }
__device__ __forceinline__ ushort f2bf(float f) {
    uint x = __float_as_uint(f);
    return (ushort)((x + 0x7fffu + ((x >> 16) & 1u)) >> 16);
}
__device__ __forceinline__ float blo(uint u) { return __uint_as_float(u << 16); }
__device__ __forceinline__ float bhi(uint u) { return __uint_as_float(u & 0xffff0000u); }
__device__ __forceinline__ float ldf(const void* p, size_t i, int isbf) {
    return isbf ? bf2f(((const ushort*)p)[i]) : ((const float*)p)[i];
}
__device__ __forceinline__ short ldb(const void* p, size_t i, int isbf) {
    return isbf ? (short)(((const ushort*)p)[i]) : (short)f2bf(((const float*)p)[i]);
}
__device__ __forceinline__ float4 ldbox(const void* p, size_t row, int isbf) {
    if (isbf) {
        const uint2 u = ((const uint2*)p)[row];
        return make_float4(blo(u.x), bhi(u.x), blo(u.y), bhi(u.y));
    }
    return ((const float4*)p)[row];
}
// ---- ISA-level fast math ----
__device__ __forceinline__ float flog(float x) {
    return __builtin_amdgcn_logf(x) * 0.69314718056f;
}
__device__ __forceinline__ float fexp(float x) {
    return __builtin_amdgcn_exp2f(x * 1.44269504089f);
}
__device__ __forceinline__ void fsincos_rev(float rev, float* s, float* c) {
    const float fr = rev - floorf(rev);
    *s = __builtin_amdgcn_sinf(fr);
    *c = __builtin_amdgcn_cosf(fr);
}
// pack two rounded fp32 -> packed bf16 pair via v_perm (round-half-up)
__device__ __forceinline__ uint pkbf(uint a, uint b) {
    return __builtin_amdgcn_perm(b + 0x8000u, a + 0x8000u, 0x07060302u);
}

// ---------------- dtype probe (proven) ----------------
__global__ __launch_bounds__(256) void probe_dtype(const uint* __restrict__ q,
                                                   int* __restrict__ flag) {
    __shared__ int s[256];
    const int t = threadIdx.x;
    int cnt = 0;
    for (int i = t; i < 4096; i += 256) {
        const uint e = (q[i] >> 7) & 0xffu;
        cnt += (e >= 0x70u && e <= 0x84u) ? 1 : 0;
    }
    s[t] = cnt;
    __syncthreads();
    for (int d = 128; d > 0; d >>= 1) {
        if (t < d) s[t] += s[t + d];
        __syncthreads();
    }
    if (t == 0) *flag = (s[0] > 3276) ? 1 : 0;
}

// ---------------- W transpose + bias convert ----------------
__global__ __launch_bounds__(256) void transw(const void* __restrict__ w0,
                                              const void* __restrict__ w1,
                                              const void* __restrict__ w2,
                                              const void* __restrict__ w3,
                                              const void* __restrict__ b0,
                                              const void* __restrict__ b1,
                                              const void* __restrict__ b2,
                                              const void* __restrict__ b3,
                                              ushort* __restrict__ wt,
                                              float* __restrict__ biasf,
                                              const int* __restrict__ flagp) {
    const int isbf = *flagp;
    const int z = blockIdx.z;
    const void* W = (z == 0) ? w0 : (z == 1) ? w1 : (z == 2) ? w2 : w3;
    const int n0 = blockIdx.x * 32, k0 = blockIdx.y * 32;
    __shared__ float tile[32][33];
    const int tx = threadIdx.x & 31, ty = threadIdx.x >> 5;
#pragma unroll
    for (int r = 0; r < 4; ++r)
        tile[ty + 8 * r][tx] = ldf(W, (size_t)(k0 + ty + 8 * r) * D_ + n0 + tx, isbf);
    if (blockIdx.x == 0 && blockIdx.y == 0) {
        const void* bz = (z == 0) ? b0 : (z == 1) ? b1 : (z == 2) ? b2 : b3;
        for (int e = threadIdx.x; e < 512; e += 256)
            biasf[z * 512 + e] = ldf(bz, e, isbf);
    }
    __syncthreads();
#pragma unroll
    for (int r = 0; r < 4; ++r)
        wt[(size_t)z * 262144 + (size_t)(n0 + ty + 8 * r) * D_ + k0 + tx] =
            f2bf(tile[tx][ty + 8 * r]);
}

// ---------------- stage1: fused QKV-GEMM (blocks 0..767) + geometry (768..4863) ----------
__global__ __launch_bounds__(256) void stage1(
    const void* __restrict__ xq, const void* __restrict__ xk, const void* __restrict__ xv,
    const ushort* __restrict__ wt, const float* __restrict__ biasf,
    ushort* __restrict__ oq, ushort* __restrict__ ok, ushort* __restrict__ ov,
    const void* __restrict__ box, const int* __restrict__ nobj,
    const void* __restrict__ WG, const void* __restrict__ bG,
    ushort* __restrict__ glog, const int* __restrict__ flagp) {
    __shared__ __align__(16) char smem[22336];
    const int isbf = *flagp;
    const int bid = blockIdx.x;
    const int t = threadIdx.x, wv = t >> 6, lane = t & 63;
    const int m16 = lane & 15, quad = lane >> 4;

    if (bid < 768) {
        // ================= GEMM path =================
        const int z = bid >> 8, rem = bid & 255;
        const int row0 = (rem & 31) * 128, col0 = (rem >> 5) * 64;
        const char* A = (const char*)((z == 0) ? xq : (z == 1) ? xk : xv);
        const ushort* W = wt + (size_t)z * 262144;
        const float* bias = biasf + z * 512;
        ushort (*As)[40] = (ushort(*)[40])smem;
        ushort (*Ws)[40] = (ushort(*)[40])(smem + 10240);
        floatx4 acc[2][4] = {};

        const int ar = t >> 1, ah = t & 1;
        const int wr = t >> 2, wc = (t & 3) * 8;

        uint4 ua, ub, uc, ud;
        short8 ps0, ps1, pw;

        auto loadA = [&](int k0) {
            const size_t e = (size_t)(row0 + ar) * D_ + k0 + ah * 16;
            if (isbf) {
                ps0 = *(const short8*)(A + 2 * e);
                ps1 = *(const short8*)(A + 2 * e + 16);
            } else {
                const uint* ap = (const uint*)A + e;
                ua = *(const uint4*)(ap);
                ub = *(const uint4*)(ap + 4);
                uc = *(const uint4*)(ap + 8);
                ud = *(const uint4*)(ap + 12);
            }
            pw = *(const short8*)(W + (size_t)(col0 + wr) * D_ + k0 + wc);
        };
        auto stage = [&]() {
            if (isbf) {
                *(short8*)&As[ar][ah * 16] = ps0;
                *(short8*)&As[ar][ah * 16 + 8] = ps1;
            } else {
                uint4 lo, hi;
                lo.x = pkbf(ua.x, ua.y); lo.y = pkbf(ua.z, ua.w);
                lo.z = pkbf(ub.x, ub.y); lo.w = pkbf(ub.z, ub.w);
                hi.x = pkbf(uc.x, uc.y); hi.y = pkbf(uc.z, uc.w);
                hi.z = pkbf(ud.x, ud.y); hi.w = pkbf(ud.z, ud.w);
                *(uint4*)&As[ar][ah * 16] = lo;
                *(uint4*)&As[ar][ah * 16 + 8] = hi;
            }
            *(short8*)&Ws[wr][wc] = pw;
        };

        loadA(0);
        for (int k0 = 0; k0 < D_; k0 += 32) {
            __syncthreads();
            stage();
            __syncthreads();
            if (k0 + 32 < D_) loadA(k0 + 32);

            const short8 a0 = *(const short8*)&As[wv * 32 + m16][quad * 8];
            const short8 a1 = *(const short8*)&As[wv * 32 + 16 + m16][quad * 8];
            const short8 b0 = *(const short8*)&Ws[m16][quad * 8];
            const short8 b1 = *(const short8*)&Ws[16 + m16][quad * 8];
            const short8 b2 = *(const short8*)&Ws[32 + m16][quad * 8];
            const short8 b3 = *(const short8*)&Ws[48 + m16][quad * 8];
            acc[0][0] = __builtin_amdgcn_mfma_f32_16x16x32_bf16(a0, b0, acc[0][0], 0, 0, 0);
            acc[0][1] = __builtin_amdgcn_mfma_f32_16x16x32_bf16(a0, b1, acc[0][1], 0, 0, 0);
            acc[0][2] = __builtin_amdgcn_mfma_f32_16x16x32_bf16(a0, b2, acc[0][2], 0, 0, 0);
            acc[0][3] = __builtin_amdgcn_mfma_f32_16x16x32_bf16(a0, b3, acc[0][3], 0, 0, 0);
            acc[1][0] = __builtin_amdgcn_mfma_f32_16x16x32_bf16(a1, b0, acc[1][0], 0, 0, 0);
            acc[1][1] = __builtin_amdgcn_mfma_f32_16x16x32_bf16(a1, b1, acc[1][1], 0, 0, 0);
            acc[1][2] = __builtin_amdgcn_mfma_f32_16x16x32_bf16(a1, b2, acc[1][2], 0, 0, 0);
            acc[1][3] = __builtin_amdgcn_mfma_f32_16x16x32_bf16(a1, b3, acc[1][3], 0, 0, 0);
        }

#pragma unroll
        for (int mt = 0; mt < 2; ++mt) {
#pragma unroll
            for (int nt = 0; nt < 4; ++nt) {
                const int colg = col0 + nt * 16 + m16;
                const float bi = bias[colg];
                const float v0 = acc[mt][nt][0] + bi, v1 = acc[mt][nt][1] + bi;
                const float v2 = acc[mt][nt][2] + bi, v3 = acc[mt][nt][3] + bi;
                const int rowb = row0 + wv * 32 + mt * 16 + quad * 4;
                if (z == 2) {
                    const int bhv = (rowb >> 9) * H_ + (colg >> 6);
                    uint2 pk;
                    pk.x = (uint)f2bf(v0) | ((uint)f2bf(v1) << 16);
                    pk.y = (uint)f2bf(v2) | ((uint)f2bf(v3) << 16);
                    *(uint2*)(ov + ((size_t)bhv * DK_ + (colg & 63)) * N_ + (rowb & 511)) = pk;
                } else {
                    ushort* o = (z == 0) ? oq : ok;
                    const float vv[4] = {v0, v1, v2, v3};
#pragma unroll
                    for (int r = 0; r < 4; ++r) {
                        const int row = rowb + r;
                        o[((size_t)((row >> 9) * H_ + (colg >> 6)) * N_ + (row & 511)) * DK_ +
                          (colg & 63)] = f2bf(vv[r]);
                    }
                }
            }
        }
    } else {
        // ================= geometry path =================
        const int id = bid - 768;
        const int i = id & 511, bl = id >> 9;
        _Float16 (*trig)[76] = (_Float16(*)[76])smem;                 // 19456 B
        _Float16 (*wgf)[72] = (_Float16(*)[72])(smem + 19456);        // 2304 B
        float* mobja = (float*)(smem + 21760);                        // 512 B
        float* bgs = (float*)(smem + 22272);                          // 32 B

        for (int e = t; e < 1024; e += 256) {
            const int h = e >> 6, g = e & 63;
            wgf[h][g] = (_Float16)((h < 8) ? ldf(WG, (size_t)h * 64 + g, isbf) : 0.f);
        }
        if (t < 8) bgs[t] = ldf(bG, t, isbf);

        const float4 bi4 = ldbox(box, (size_t)bl * N_ + i, isbf);
        const float wi = bi4.z - bi4.x + 1.0f, hi = bi4.w - bi4.y + 1.0f;
        const float cxi = (bi4.x + bi4.z) * 0.5f, cyi = (bi4.y + bi4.w) * 0.5f;
        const float rwi = 1.0f / wi, rhi = 1.0f / hi;
        const float lwi = flog(wi), lhi = flog(hi);
        const int noi = nobj[bl * N_ + i];
        __syncthreads();

        const half8 bf0 = *(const half8*)&wgf[m16][quad * 8];
        const half8 bf1 = *(const half8*)&wgf[m16][quad * 8 + 32];
        _Float16* gb = (_Float16*)glog +
                       ((((size_t)bl * 32 + (i >> 4)) * 8) * 16 + (i & 15)) * 512;
        const float dmrev[8] = {15.915494f, 6.7115083f, 2.8302207f, 1.1934936f,
                                0.50329214f, 0.21223603f, 0.089498095f, 0.037742074f};

        for (int c = 0; c < 4; ++c) {
            const int jbase = c * 128;
            {
                const int pair = t >> 1, hf = t & 1;
                const int j = jbase + pair;
                const float4 bj4 = ldbox(box, (size_t)bl * N_ + j, isbf);
                const float wj = bj4.z - bj4.x + 1.0f, hj = bj4.w - bj4.y + 1.0f;
                float p0, p1;
                if (hf == 0) {
                    const float cxj = (bj4.x + bj4.z) * 0.5f, cyj = (bj4.y + bj4.w) * 0.5f;
                    p0 = flog(fmaxf(fabsf((cxi - cxj) * rwi), 0.001f));
                    p1 = flog(fmaxf(fabsf((cyi - cyj) * rhi), 0.001f));
                    mobja[pair] = (noi || nobj[bl * N_ + j]) ? 0.f : 1.f;
                } else {
                    p0 = lwi - flog(wj);
                    p1 = lhi - flog(hj);
                }
#pragma unroll
                for (int pp = 0; pp < 2; ++pp) {
                    const float base = pp ? p1 : p0;
                    half8 s8, c8;
#pragma unroll
                    for (int f = 0; f < 8; ++f) {
                        float sv, cv;
                        fsincos_rev(base * dmrev[f], &sv, &cv);
                        s8[f] = (_Float16)sv;
                        c8[f] = (_Float16)cv;
                    }
                    const int g0 = hf * 16 + pp * 8;
                    *(half4*)&trig[pair][g0]          = *(const half4*)&s8;
                    *(half4*)&trig[pair][g0 + 4]      = *((const half4*)&s8 + 1);
                    *(half4*)&trig[pair][32 + g0]     = *(const half4*)&c8;
                    *(half4*)&trig[pair][32 + g0 + 4] = *((const half4*)&c8 + 1);
                }
            }
            __syncthreads();
            {
#pragma unroll
                for (int sub = 0; sub < 2; ++sub) {
                    const int row = wv * 32 + sub * 16 + m16;
                    half8 a0, a1;
                    *((half4*)&a0)     = *(const half4*)&trig[row][quad * 8];
                    *((half4*)&a0 + 1) = *(const half4*)&trig[row][quad * 8 + 4];
                    *((half4*)&a1)     = *(const half4*)&trig[row][32 + quad * 8];
                    *((half4*)&a1 + 1) = *(const half4*)&trig[row][32 + quad * 8 + 4];
                    floatx4 acc = {};
                    acc = __builtin_amdgcn_mfma_f32_16x16x32_f16(a0, bf0, acc, 0, 0, 0);
                    acc = __builtin_amdgcn_mfma_f32_16x16x32_f16(a1, bf1, acc, 0, 0, 0);
                    if (m16 < 8) {
#pragma unroll
                        for (int r = 0; r < 4; ++r) {
                            const int pair = wv * 32 + sub * 16 + quad * 4 + r;
                            const float wg = acc[r] + bgs[m16];
                            const float gl = flog(fmaxf(wg, 1e-6f)) * mobja[pair];
                            gb[(size_t)m16 * 8192 + jbase + pair] = (_Float16)gl;
                        }
                    }
                }
            }
            __syncthreads();
        }
    }
}

// ---------------- MFMA GEMM, output proj ----------------
__global__ __launch_bounds__(256) void gemm1(
    const ushort* __restrict__ att, const ushort* __restrict__ wt,
    const float* __restrict__ biasf, void* __restrict__ dout,
    const int* __restrict__ flagp) {
    const int isbf = *flagp;
    const ushort* W = wt + (size_t)3 * 262144;
    const float* bias = biasf + 3 * 512;
    const int row0 = blockIdx.x * 128, col0 = blockIdx.y * 64;
    const int t = threadIdx.x, wv = t >> 6, lane = t & 63;
    const int m16 = lane & 15, quad = lane >> 4;

    __shared__ ushort As[128][40];
    __shared__ ushort Ws[64][40];
    floatx4 acc[2][4] = {};

    const int ar = t >> 1, ah = t & 1;
    const int wr = t >> 2, wc = (t & 3) * 8;

    short8 ps0, ps1, pw;
    auto loadA = [&](int k0) {
        const ushort* ap = att + (size_t)(row0 + ar) * D_ + k0 + ah * 16;
        ps0 = *(const short8*)(ap);
        ps1 = *(const short8*)(ap + 8);
        pw = *(const short8*)(W + (size_t)(col0 + wr) * D_ + k0 + wc);
    };

    loadA(0);
    for (int k0 = 0; k0 < D_; k0 += 32) {
        __syncthreads();
        *(short8*)&As[ar][ah * 16] = ps0;
        *(short8*)&As[ar][ah * 16 + 8] = ps1;
        *(short8*)&Ws[wr][wc] = pw;
        __syncthreads();
        if (k0 + 32 < D_) loadA(k0 + 32);

        const short8 a0 = *(const short8*)&As[wv * 32 + m16][quad * 8];
        const short8 a1 = *(const short8*)&As[wv * 32 + 16 + m16][quad * 8];
        const short8 b0 = *(const short8*)&Ws[m16][quad * 8];
        const short8 b1 = *(const short8*)&Ws[16 + m16][quad * 8];
        const short8 b2 = *(const short8*)&Ws[32 + m16][quad * 8];
        const short8 b3 = *(const short8*)&Ws[48 + m16][quad * 8];
        acc[0][0] = __builtin_amdgcn_mfma_f32_16x16x32_bf16(a0, b0, acc[0][0], 0, 0, 0);
        acc[0][1] = __builtin_amdgcn_mfma_f32_16x16x32_bf16(a0, b1, acc[0][1], 0, 0, 0);
        acc[0][2] = __builtin_amdgcn_mfma_f32_16x16x32_bf16(a0, b2, acc[0][2], 0, 0, 0);
        acc[0][3] = __builtin_amdgcn_mfma_f32_16x16x32_bf16(a0, b3, acc[0][3], 0, 0, 0);
        acc[1][0] = __builtin_amdgcn_mfma_f32_16x16x32_bf16(a1, b0, acc[1][0], 0, 0, 0);
        acc[1][1] = __builtin_amdgcn_mfma_f32_16x16x32_bf16(a1, b1, acc[1][1], 0, 0, 0);
        acc[1][2] = __builtin_amdgcn_mfma_f32_16x16x32_bf16(a1, b2, acc[1][2], 0, 0, 0);
        acc[1][3] = __builtin_amdgcn_mfma_f32_16x16x32_bf16(a1, b3, acc[1][3], 0, 0, 0);
    }

#pragma unroll
    for (int mt = 0; mt < 2; ++mt) {
#pragma unroll
        for (int nt = 0; nt < 4; ++nt) {
            const int colg = col0 + nt * 16 + m16;
            const float bi = bias[colg];
#pragma unroll
            for (int r = 0; r < 4; ++r) {
                const int row = row0 + wv * 32 + mt * 16 + quad * 4 + r;
                const float v = acc[mt][nt][r] + bi;
                if (isbf) ((ushort*)dout)[(size_t)row * D_ + colg] = f2bf(v);
                else      ((float*)dout)[(size_t)row * D_ + colg] = v;
            }
        }
    }
}

// ---------------- MFMA attention ----------------
__global__ __launch_bounds__(256) void attn3(
    const ushort* __restrict__ qw, const ushort* __restrict__ kw,
    const ushort* __restrict__ vt, const int* __restrict__ mask,
    const ushort* __restrict__ glog, ushort* __restrict__ att, int b0) {
    const int it = blockIdx.x, h = blockIdx.y, bl = blockIdx.z;
    const int bg = b0 + bl;
    const int i0 = it * 16;
    const int t = threadIdx.x, wv = t >> 6, lane = t & 63;
    const int m16 = lane & 15, quad = lane >> 4;
    const size_t bh = (size_t)(bg * H_ + h);

    __shared__ float lg[16][516];
    __shared__ ushort sbuf[16 * 520];
    __shared__ float rsumInv[16];

    {
        const uint4* src = (const uint4*)(glog + (((size_t)bl * 32 + it) * 8 + h) * 8192);
        uint4* dst = (uint4*)sbuf;
#pragma unroll
        for (int e = 0; e < 4; ++e) dst[t + 256 * e] = src[t + 256 * e];
    }
    const ushort* qrow = qw + (bh * N_ + i0 + m16) * DK_ + quad * 8;
    const short8 aq0 = *(const short8*)(qrow);
    const short8 aq1 = *(const short8*)(qrow + 32);
    __syncthreads();

#pragma unroll
    for (int tt = 0; tt < 8; ++tt) {
        const int j0 = wv * 128 + tt * 16;
        const ushort* krow = kw + (bh * N_ + j0 + m16) * DK_ + quad * 8;
        const short8 bk0 = *(const short8*)(krow);
        const short8 bk1 = *(const short8*)(krow + 32);
        floatx4 acc = {};
        acc = __builtin_amdgcn_mfma_f32_16x16x32_bf16(aq0, bk0, acc, 0, 0, 0);
        acc = __builtin_amdgcn_mfma_f32_16x16x32_bf16(aq1, bk1, acc, 0, 0, 0);
        const int mj = mask[bg * N_ + j0 + m16];
        const __half* gt = (const __half*)sbuf;
#pragma unroll
        for (int r = 0; r < 4; ++r) {
            const int i = quad * 4 + r;
            const float g = __half2float(gt[i * 512 + j0 + m16]);
            lg[i][j0 + m16] = (mj ? 0.125f * acc[r] : -1e9f) + g;
        }
    }
    __syncthreads();

    {
        const int row = t >> 4, l = t & 15;
        float v[32];
        float mx = -3e38f;
#pragma unroll
        for (int s = 0; s < 32; ++s) { v[s] = lg[row][l + 16 * s]; mx = fmaxf(mx, v[s]); }
#pragma unroll
        for (int d = 1; d < 16; d <<= 1) mx = fmaxf(mx, __shfl_xor(mx, d, 16));
        float sm = 0.f;
#pragma unroll
        for (int s = 0; s < 32; ++s) { const float p = fexp(v[s] - mx); sm += p; v[s] = p; }
#pragma unroll
        for (int d = 1; d < 16; d <<= 1) sm += __shfl_xor(sm, d, 16);
#pragma unroll
        for (int s = 0; s < 32; ++s)
            sbuf[row * 520 + l + 16 * s] = (ushort)((__float_as_uint(v[s]) + 0x8000u) >> 16);
        if (l == 0) rsumInv[row] = 1.0f / sm;
    }
    __syncthreads();

    {
        const int dk0 = wv * 16;
        const ushort* vrow = vt + (bh * DK_ + dk0 + m16) * N_ + quad * 8;
        floatx4 oc = {};
#pragma unroll
        for (int kc = 0; kc < 16; ++kc) {
            const short8 ap = *(const short8*)(sbuf + m16 * 520 + kc * 32 + quad * 8);
            const short8 bv = *(const short8*)(vrow + kc * 32);
            oc = __builtin_amdgcn_mfma_f32_16x16x32_bf16(ap, bv, oc, 0, 0, 0);
        }
#pragma unroll
        for (int r = 0; r < 4; ++r) {
            const int i = quad * 4 + r;
            const float o = oc[r] * rsumInv[i];
            att[((size_t)(bg * N_ + i0 + i)) * D_ + h * DK_ + dk0 + m16] = f2bf(o);
        }
    }
}

// ================= tier-3 fallback (round-3 proven, unchanged) =================
__global__ __launch_bounds__(256) void gemm16(const void* __restrict__ A,
                                              const void* __restrict__ W,
                                              const void* __restrict__ bias,
                                              void* __restrict__ out,
                                              const int* __restrict__ flagp,
                                              int a_follows, int mode) {
    const int isbf = *flagp;
    const int a_isbf = a_follows ? isbf : 1;
    const int wave = threadIdx.x >> 6;
    const int tile = blockIdx.x * 4 + wave;
    const int tm = tile >> 5, tn = tile & 31;
    const int row0 = tm * 16, col0 = tn * 16;
    const int lane = threadIdx.x & 63;
    const int m = lane & 15, quad = lane >> 4;
    floatx4 acc = {0.f, 0.f, 0.f, 0.f};
    const size_t abase = (size_t)(row0 + m) * D_ + quad * 8;
    const size_t wbase = (size_t)(quad * 8) * D_ + col0 + m;
    for (int k0 = 0; k0 < D_; k0 += 32) {
        short8 af, bf;
#pragma unroll
        for (int j = 0; j < 8; ++j) af[j] = ldb(A, abase + k0 + j, a_isbf);
#pragma unroll
        for (int j = 0; j < 8; ++j) bf[j] = ldb(W, wbase + (size_t)(k0 + j) * D_, isbf);
        acc = __builtin_amdgcn_mfma_f32_16x16x32_bf16(af, bf, acc, 0, 0, 0);
    }
    const int col = col0 + m;
    const float bi = ldf(bias, col, isbf);
#pragma unroll
    for (int r = 0; r < 4; ++r) {
        const int row = row0 + quad * 4 + r;
        const float v = acc[r] + bi;
        if (mode == 1) {
            ((ushort*)out)[(size_t)(((row >> 9) * H_ + (col >> 6)) * N_ + (row & 511)) * DK_ + (col & 63)] = f2bf(v);
        } else if (isbf) {
            ((ushort*)out)[(size_t)row * D_ + col] = f2bf(v);
        } else {
            ((float*)out)[(size_t)row * D_ + col] = v;
        }
    }
}

__global__ __launch_bounds__(256) void attn_old(
    const ushort* __restrict__ qw, const ushort* __restrict__ kw,
    const ushort* __restrict__ vw, const void* __restrict__ box,
    const int* __restrict__ mask, const int* __restrict__ nobj,
    const void* __restrict__ WG, const void* __restrict__ bG,
    ushort* __restrict__ att, const int* __restrict__ flagp) {
    const int isbf = *flagp;
    const int b = blockIdx.z, h = blockIdx.y;
    const int i0 = blockIdx.x * 8;
    const int t = threadIdx.x;
    __shared__ float lg[8][520];
    __shared__ float q_s[8][68];
    __shared__ float wgh[64];
    __shared__ float cxi[8], cyi[8], rwi[8], rhi[8], lwi[8], lhi[8];
    __shared__ int noi[8];
    __shared__ float rsum[8];
    for (int e = t; e < 512; e += 256) {
        const int ii = e >> 6, dk = e & 63;
        q_s[ii][dk] = bf2f(qw[(size_t)((b * H_ + h) * N_ + i0 + ii) * DK_ + dk]) * 0.125f;
    }
    if (t < 64) wgh[t] = ldf(WG, h * 64 + t, isbf);
    if (t < 8) {
        const size_t bb = (size_t)(b * N_ + i0 + t) * 4;
        const float xmn = ldf(box, bb + 0, isbf), ymn = ldf(box, bb + 1, isbf);
        const float xmx = ldf(box, bb + 2, isbf), ymx = ldf(box, bb + 3, isbf);
        const float w = xmx - xmn + 1.0f, hh = ymx - ymn + 1.0f;
        cxi[t] = (xmn + xmx) * 0.5f;
        cyi[t] = (ymn + ymx) * 0.5f;
        rwi[t] = 1.0f / w;
        rhi[t] = 1.0f / hh;
        lwi[t] = __logf(w);
        lhi[t] = __logf(hh);
        noi[t] = nobj[b * N_ + i0 + t];
    }
    const float bg = ldf(bG, h, isbf);
    __syncthreads();
    for (int jl = 0; jl < 2; ++jl) {
        const int j = t + jl * 256;
        float acc[8];
#pragma unroll
        for (int ii = 0; ii < 8; ++ii) acc[ii] = 0.f;
        const uint4* krow = (const uint4*)(kw + (size_t)((b * H_ + h) * N_ + j) * DK_);
#pragma unroll
        for (int c = 0; c < 8; ++c) {
            const uint4 ku = krow[c];
            float kf[8];
            kf[0] = blo(ku.x); kf[1] = bhi(ku.x); kf[2] = blo(ku.y); kf[3] = bhi(ku.y);
            kf[4] = blo(ku.z); kf[5] = bhi(ku.z); kf[6] = blo(ku.w); kf[7] = bhi(ku.w);
#pragma unroll
            for (int ii = 0; ii < 8; ++ii) {
                const float4 qa = *(const float4*)(&q_s[ii][c * 8]);
                const float4 qb = *(const float4*)(&q_s[ii][c * 8 + 4]);
                acc[ii] += qa.x * kf[0] + qa.y * kf[1] + qa.z * kf[2] + qa.w * kf[3] +
                           qb.x * kf[4] + qb.y * kf[5] + qb.z * kf[6] + qb.w * kf[7];
            }
        }
        const int mj = mask[b * N_ + j];
        const size_t bb = (size_t)(b * N_ + j) * 4;
        const float xmn = ldf(box, bb + 0, isbf), ymn = ldf(box, bb + 1, isbf);
        const float xmx = ldf(box, bb + 2, isbf), ymx = ldf(box, bb + 3, isbf);
        const float cxj = (xmn + xmx) * 0.5f, cyj = (ymn + ymx) * 0.5f;
        const float wj = xmx - xmn + 1.0f, hj = ymx - ymn + 1.0f;
        const float lwj = __logf(wj), lhj = __logf(hj);
        const int noj = nobj[b * N_ + j];
        const float dm[8] = {1.0f, 0.421696503f, 0.177827941f, 0.074989421f,
                             0.031622777f, 0.013335214f, 0.005623413f, 0.002371374f};
        for (int ii = 0; ii < 8; ++ii) {
            const float mobj = (noi[ii] || noj) ? 0.f : 1.f;
            const float dx = __logf(fmaxf(fabsf((cxi[ii] - cxj) * rwi[ii]), 0.001f));
            const float dy = __logf(fmaxf(fabsf((cyi[ii] - cyj) * rhi[ii]), 0.001f));
            const float pos[4] = {dx, dy, lwi[ii] - lwj, lhi[ii] - lhj};
            float wg = bg;
            for (int p = 0; p < 4; ++p) {
                const float base = 100.f * pos[p];
#pragma unroll
                for (int f = 0; f < 8; ++f) {
                    float sv, cv;
                    __sincosf(base * dm[f], &sv, &cv);
                    const int g = p * 8 + f;
                    wg += sv * wgh[g] + cv * wgh[32 + g];
                }
            }
            lg[ii][j] = (mj ? acc[ii] : -1e9f) + __logf(fmaxf(wg, 1e-6f)) * mobj;
        }
    }
    __syncthreads();
    {
        const int rr = t >> 5, l32 = t & 31;
        float mx = -3e38f;
        for (int j = l32; j < N_; j += 32) mx = fmaxf(mx, lg[rr][j]);
#pragma unroll
        for (int d = 1; d < 32; d <<= 1) mx = fmaxf(mx, __shfl_xor(mx, d, 32));
        float sm = 0.f;
        for (int j = l32; j < N_; j += 32) {
            const float p = __expf(lg[rr][j] - mx);
            lg[rr][j] = p;
            sm += p;
        }
#pragma unroll
        for (int d = 1; d < 32; d <<= 1) sm += __shfl_xor(sm, d, 32);
        if (l32 == 0) rsum[rr] = sm;
    }
    __syncthreads();
    {
        const int ii = t >> 5, dkp = t & 31;
        float o0 = 0.f, o1 = 0.f;
        const uint* vbase = (const uint*)vw + (size_t)((b * H_ + h) * N_) * (DK_ / 2) + dkp;
        for (int j = 0; j < N_; ++j) {
            const uint u = vbase[(size_t)j * (DK_ / 2)];
            const float p = lg[ii][j];
            o0 += p * blo(u);
            o1 += p * bhi(u);
        }
        const float inv = 1.0f / rsum[ii];
        const uint pk = (uint)f2bf(o0 * inv) | ((uint)f2bf(o1 * inv) << 16);
        ((uint*)att)[(size_t)(b * N_ + i0 + ii) * (D_ / 2) + h * 32 + dkp] = pk;
    }
}

extern "C" void kernel_launch(void* const* d_in, const int* in_sizes, int n_in,
                              void* d_out, int out_size, void* d_ws, size_t ws_size,
                              hipStream_t stream) {
    const void* xq = d_in[0];
    const void* xk = d_in[1];
    const void* xv = d_in[2];
    const void* box = d_in[3];
    const int* mask = (const int*)d_in[4];
    const int* nobj = (const int*)d_in[5];
    const void* Wq = d_in[6];
    const void* bq = d_in[7];
    const void* Wk = d_in[8];
    const void* bk = d_in[9];
    const void* Wv = d_in[10];
    const void* bv = d_in[11];
    const void* Wo = d_in[12];
    const void* bo = d_in[13];
    const void* WG = d_in[14];
    const void* bG = d_in[15];

    char* ws = (char*)d_ws;
    const size_t MB = 1u << 20;

    if (ws_size >= 54 * MB) {   // tier-1 (confirmed active since round 3)
        int* flag = (int*)ws;
        float* biasf = (float*)(ws + 4096);
        ushort* wt = (ushort*)(ws + 16384);
        size_t p = 16384 + 2097152;
        ushort* qw = (ushort*)(ws + p); p += 4194304;
        ushort* kw = (ushort*)(ws + p); p += 4194304;
        ushort* vt = (ushort*)(ws + p); p += 4194304;
        ushort* att = (ushort*)(ws + p); p += 4194304;
        ushort* glog = (ushort*)(ws + p);   // 32 MB: [bl][it][h][16][512] fp16

        hipLaunchKernelGGL(probe_dtype, dim3(1), dim3(256), 0, stream, (const uint*)xq, flag);
        hipLaunchKernelGGL(transw, dim3(16, 16, 4), dim3(256), 0, stream,
                           Wq, Wk, Wv, Wo, bq, bk, bv, bo, wt, biasf, flag);
        hipLaunchKernelGGL(stage1, dim3(4864), dim3(256), 0, stream,
                           xq, xk, xv, wt, biasf, qw, kw, vt,
                           box, nobj, WG, bG, glog, flag);
        hipLaunchKernelGGL(attn3, dim3(32, H_, B_), dim3(256), 0, stream,
                           qw, kw, vt, mask, glog, att, 0);
        hipLaunchKernelGGL(gemm1, dim3(32, 8), dim3(256), 0, stream,
                           att, wt, biasf, d_out, flag);
    } else {
        // tier-3 fallback (proven round-3 path, ~16.6 MB)
        int* flag = (int*)ws;
        ushort* qw = (ushort*)(ws + 256);
        ushort* kw = (ushort*)(ws + 256 + 4194304);
        ushort* vw = (ushort*)(ws + 256 + 8388608);
        ushort* att = (ushort*)(ws + 256 + 12582912);
        hipLaunchKernelGGL(probe_dtype, dim3(1), dim3(256), 0, stream, (const uint*)xq, flag);
        hipLaunchKernelGGL(gemm16, dim3(2048), dim3(256), 0, stream, xq, Wq, bq, (void*)qw, flag, 1, 1);
        hipLaunchKernelGGL(gemm16, dim3(2048), dim3(256), 0, stream, xk, Wk, bk, (void*)kw, flag, 1, 1);
        hipLaunchKernelGGL(gemm16, dim3(2048), dim3(256), 0, stream, xv, Wv, bv, (void*)vw, flag, 1, 1);
        hipLaunchKernelGGL(attn_old, dim3(N_ / 8, H_, B_), dim3(256), 0, stream,
                           qw, kw, vw, box, mask, nobj, WG, bG, att, flag);
        hipLaunchKernelGGL(gemm16, dim3(2048), dim3(256), 0, stream, att, Wo, bo, d_out, flag, 0, 2);
    }
}

// Round 10
// 187.766 us; speedup vs baseline: 7.6750x; 1.0555x over previous
//
#include <hip/hip_runtime.h>
#include <hip/hip_fp16.h>

#define B_ 8
#define N_ 512
#define D_ 512
#define H_ 8
#define DK_ 64

typedef unsigned int uint;
typedef unsigned short ushort;
typedef __attribute__((ext_vector_type(8))) short short8;
typedef __attribute__((ext_vector_type(8))) _Float16 half8;
typedef __attribute__((ext_vector_type(4))) _Float16 half4;
typedef __attribute__((ext_vector_type(4))) float floatx4;

__device__ __forceinline__ float bf2f(ushort s) { return __uint_as_float(((uint)s) << 16); }
__device__ __forceinline__ ushort f2bf(float f) {
    uint x = __float_as_uint(f);
    return (ushort)((x + 0x7fffu + ((x >> 16) & 1u)) >> 16);
}
__device__ __forceinline__ float blo(uint u) { return __uint_as_float(u << 16); }
__device__ __forceinline__ float bhi(uint u) { return __uint_as_float(u & 0xffff0000u); }
__device__ __forceinline__ float ldf(const void* p, size_t i, int isbf) {
    return isbf ? bf2f(((const ushort*)p)[i]) : ((const float*)p)[i];
}
__device__ __forceinline__ short ldb(const void* p, size_t i, int isbf) {
    return isbf ? (short)(((const ushort*)p)[i]) : (short)f2bf(((const float*)p)[i]);
}
__device__ __forceinline__ float4 ldbox(const void* p, size_t row, int isbf) {
    if (isbf) {
        const uint2 u = ((const uint2*)p)[row];
        return make_float4(blo(u.x), bhi(u.x), blo(u.y), bhi(u.y));
    }
    return ((const float4*)p)[row];
}
// ---- ISA-level fast math ----
__device__ __forceinline__ float flog(float x) {
    return __builtin_amdgcn_logf(x) * 0.69314718056f;
}
__device__ __forceinline__ float fexp(float x) {
    return __builtin_amdgcn_exp2f(x * 1.44269504089f);
}
__device__ __forceinline__ void fsincos_rev(float rev, float* s, float* c) {
    const float fr = rev - floorf(rev);
    *s = __builtin_amdgcn_sinf(fr);
    *c = __builtin_amdgcn_cosf(fr);
}
__device__ __forceinline__ uint pkbf(uint a, uint b) {
    return __builtin_amdgcn_perm(b + 0x8000u, a + 0x8000u, 0x07060302u);
}
// dtype sniff over first 4096 words (per-block redundant compute; deterministic)
__device__ __forceinline__ int sniff_dtype(const uint* q, int* scratch) {
    const int t = threadIdx.x;
    int cnt = 0;
    for (int i = t; i < 4096; i += 256) {
        const uint e = (q[i] >> 7) & 0xffu;
        cnt += (e >= 0x70u && e <= 0x84u) ? 1 : 0;
    }
    scratch[t] = cnt;
    __syncthreads();
    for (int d = 128; d > 0; d >>= 1) {
        if (t < d) scratch[t] += scratch[t + d];
        __syncthreads();
    }
    const int r = (scratch[0] > 3276) ? 1 : 0;
    __syncthreads();
    return r;
}

// ---------------- dtype probe (tier-3 only) ----------------
__global__ __launch_bounds__(256) void probe_dtype(const uint* __restrict__ q,
                                                   int* __restrict__ flag) {
    __shared__ int s[256];
    const int r = sniff_dtype(q, s);
    if (threadIdx.x == 0) *flag = r;
}

// ---------------- W transpose + bias convert + flag publish ----------------
__global__ __launch_bounds__(256) void transw(const void* __restrict__ w0,
                                              const void* __restrict__ w1,
                                              const void* __restrict__ w2,
                                              const void* __restrict__ w3,
                                              const void* __restrict__ b0,
                                              const void* __restrict__ b1,
                                              const void* __restrict__ b2,
                                              const void* __restrict__ b3,
                                              const uint* __restrict__ xq,
                                              ushort* __restrict__ wt,
                                              float* __restrict__ biasf,
                                              int* __restrict__ flag) {
    __shared__ int cnt_s[256];
    const int isbf = sniff_dtype(xq, cnt_s);
    const int z = blockIdx.z;
    const void* W = (z == 0) ? w0 : (z == 1) ? w1 : (z == 2) ? w2 : w3;
    const int n0 = blockIdx.x * 32, k0 = blockIdx.y * 32;
    __shared__ float tile[32][33];
    const int tx = threadIdx.x & 31, ty = threadIdx.x >> 5;
#pragma unroll
    for (int r = 0; r < 4; ++r)
        tile[ty + 8 * r][tx] = ldf(W, (size_t)(k0 + ty + 8 * r) * D_ + n0 + tx, isbf);
    if (blockIdx.x == 0 && blockIdx.y == 0) {
        const void* bz = (z == 0) ? b0 : (z == 1) ? b1 : (z == 2) ? b2 : b3;
        for (int e = threadIdx.x; e < 512; e += 256)
            biasf[z * 512 + e] = ldf(bz, e, isbf);
        if (z == 0 && threadIdx.x == 0) *flag = isbf;
    }
    __syncthreads();
#pragma unroll
    for (int r = 0; r < 4; ++r)
        wt[(size_t)z * 262144 + (size_t)(n0 + ty + 8 * r) * D_ + k0 + tx] =
            f2bf(tile[tx][ty + 8 * r]);
}

// ---------------- stage1: interleaved QKV-GEMM (64x64 tiles) + geometry ----------------
// 512 groups x 11 blocks: k<3 -> gemm (1536), else geom (4096). Total 5632.
__global__ __launch_bounds__(256) void stage1(
    const void* __restrict__ xq, const void* __restrict__ xk, const void* __restrict__ xv,
    const ushort* __restrict__ wt, const float* __restrict__ biasf,
    ushort* __restrict__ oq, ushort* __restrict__ ok, ushort* __restrict__ ov,
    const void* __restrict__ box, const int* __restrict__ nobj,
    const void* __restrict__ WG, const void* __restrict__ bG,
    ushort* __restrict__ glog, const int* __restrict__ flagp) {
    __shared__ __align__(16) char smem[22336];
    const int isbf = *flagp;
    const int grp = blockIdx.x / 11, kk = blockIdx.x % 11;
    const int t = threadIdx.x, wv = t >> 6, lane = t & 63;
    const int m16 = lane & 15, quad = lane >> 4;

    if (kk < 3) {
        // ================= GEMM path: 64x64 tile =================
        const int id = grp * 3 + kk;
        const int z = id >> 9, rem = id & 511;
        const int row0 = (rem & 63) * 64, col0 = (rem >> 6) * 64;
        const char* A = (const char*)((z == 0) ? xq : (z == 1) ? xk : xv);
        const ushort* W = wt + (size_t)z * 262144;
        const float* bias = biasf + z * 512;
        ushort (*As)[40] = (ushort(*)[40])smem;
        ushort (*Ws)[40] = (ushort(*)[40])(smem + 5120);
        floatx4 acc[4] = {};

        const int ar = t >> 2, ac = (t & 3) * 8;

        uint4 ua, ub;
        short8 ps, pw;
        auto loadA = [&](int k0) {
            const size_t e = (size_t)(row0 + ar) * D_ + k0 + ac;
            if (isbf) {
                ps = *(const short8*)(A + 2 * e);
            } else {
                const uint* ap = (const uint*)A + e;
                ua = *(const uint4*)(ap);
                ub = *(const uint4*)(ap + 4);
            }
            pw = *(const short8*)(W + (size_t)(col0 + ar) * D_ + k0 + ac);
        };
        auto stage = [&]() {
            if (isbf) {
                *(short8*)&As[ar][ac] = ps;
            } else {
                uint4 lo;
                lo.x = pkbf(ua.x, ua.y); lo.y = pkbf(ua.z, ua.w);
                lo.z = pkbf(ub.x, ub.y); lo.w = pkbf(ub.z, ub.w);
                *(uint4*)&As[ar][ac] = lo;
            }
            *(short8*)&Ws[ar][ac] = pw;
        };

        loadA(0);
        for (int k0 = 0; k0 < D_; k0 += 32) {
            __syncthreads();
            stage();
            __syncthreads();
            if (k0 + 32 < D_) loadA(k0 + 32);

            const short8 a0 = *(const short8*)&As[wv * 16 + m16][quad * 8];
            const short8 b0 = *(const short8*)&Ws[m16][quad * 8];
            const short8 b1 = *(const short8*)&Ws[16 + m16][quad * 8];
            const short8 b2 = *(const short8*)&Ws[32 + m16][quad * 8];
            const short8 b3 = *(const short8*)&Ws[48 + m16][quad * 8];
            acc[0] = __builtin_amdgcn_mfma_f32_16x16x32_bf16(a0, b0, acc[0], 0, 0, 0);
            acc[1] = __builtin_amdgcn_mfma_f32_16x16x32_bf16(a0, b1, acc[1], 0, 0, 0);
            acc[2] = __builtin_amdgcn_mfma_f32_16x16x32_bf16(a0, b2, acc[2], 0, 0, 0);
            acc[3] = __builtin_amdgcn_mfma_f32_16x16x32_bf16(a0, b3, acc[3], 0, 0, 0);
        }

#pragma unroll
        for (int nt = 0; nt < 4; ++nt) {
            const int colg = col0 + nt * 16 + m16;
            const float bi = bias[colg];
            const float v0 = acc[nt][0] + bi, v1 = acc[nt][1] + bi;
            const float v2 = acc[nt][2] + bi, v3 = acc[nt][3] + bi;
            const int rowb = row0 + wv * 16 + quad * 4;
            if (z == 2) {
                const int bhv = (rowb >> 9) * H_ + (colg >> 6);
                uint2 pk;
                pk.x = (uint)f2bf(v0) | ((uint)f2bf(v1) << 16);
                pk.y = (uint)f2bf(v2) | ((uint)f2bf(v3) << 16);
                *(uint2*)(ov + ((size_t)bhv * DK_ + (colg & 63)) * N_ + (rowb & 511)) = pk;
            } else {
                ushort* o = (z == 0) ? oq : ok;
                const float vv[4] = {v0, v1, v2, v3};
#pragma unroll
                for (int r = 0; r < 4; ++r) {
                    const int row = rowb + r;
                    o[((size_t)((row >> 9) * H_ + (colg >> 6)) * N_ + (row & 511)) * DK_ +
                      (colg & 63)] = f2bf(vv[r]);
                }
            }
        }
    } else {
        // ================= geometry path =================
        const int id = grp * 8 + (kk - 3);
        const int i = id & 511, bl = id >> 9;
        _Float16 (*trig)[76] = (_Float16(*)[76])smem;                 // 19456 B
        _Float16 (*wgf)[72] = (_Float16(*)[72])(smem + 19456);        // 2304 B
        float* mobja = (float*)(smem + 21760);                        // 512 B
        float* bgs = (float*)(smem + 22272);                          // 32 B

        for (int e = t; e < 1024; e += 256) {
            const int h = e >> 6, g = e & 63;
            wgf[h][g] = (_Float16)((h < 8) ? ldf(WG, (size_t)h * 64 + g, isbf) : 0.f);
        }
        if (t < 8) bgs[t] = ldf(bG, t, isbf);

        const float4 bi4 = ldbox(box, (size_t)bl * N_ + i, isbf);
        const float wi = bi4.z - bi4.x + 1.0f, hi = bi4.w - bi4.y + 1.0f;
        const float cxi = (bi4.x + bi4.z) * 0.5f, cyi = (bi4.y + bi4.w) * 0.5f;
        const float rwi = 1.0f / wi, rhi = 1.0f / hi;
        const float lwi = flog(wi), lhi = flog(hi);
        const int noi = nobj[bl * N_ + i];
        __syncthreads();

        const half8 bf0 = *(const half8*)&wgf[m16][quad * 8];
        const half8 bf1 = *(const half8*)&wgf[m16][quad * 8 + 32];
        _Float16* gb = (_Float16*)glog +
                       ((((size_t)bl * 32 + (i >> 4)) * 8) * 16 + (i & 15)) * 512;
        const float dmrev[8] = {15.915494f, 6.7115083f, 2.8302207f, 1.1934936f,
                                0.50329214f, 0.21223603f, 0.089498095f, 0.037742074f};

        for (int c = 0; c < 4; ++c) {
            const int jbase = c * 128;
            {
                const int pair = t >> 1, hf = t & 1;
                const int j = jbase + pair;
                const float4 bj4 = ldbox(box, (size_t)bl * N_ + j, isbf);
                const float wj = bj4.z - bj4.x + 1.0f, hj = bj4.w - bj4.y + 1.0f;
                float p0, p1;
                if (hf == 0) {
                    const float cxj = (bj4.x + bj4.z) * 0.5f, cyj = (bj4.y + bj4.w) * 0.5f;
                    p0 = flog(fmaxf(fabsf((cxi - cxj) * rwi), 0.001f));
                    p1 = flog(fmaxf(fabsf((cyi - cyj) * rhi), 0.001f));
                    mobja[pair] = (noi || nobj[bl * N_ + j]) ? 0.f : 1.f;
                } else {
                    p0 = lwi - flog(wj);
                    p1 = lhi - flog(hj);
                }
#pragma unroll
                for (int pp = 0; pp < 2; ++pp) {
                    const float base = pp ? p1 : p0;
                    half8 s8, c8;
#pragma unroll
                    for (int f = 0; f < 8; ++f) {
                        float sv, cv;
                        fsincos_rev(base * dmrev[f], &sv, &cv);
                        s8[f] = (_Float16)sv;
                        c8[f] = (_Float16)cv;
                    }
                    const int g0 = hf * 16 + pp * 8;
                    *(half4*)&trig[pair][g0]          = *(const half4*)&s8;
                    *(half4*)&trig[pair][g0 + 4]      = *((const half4*)&s8 + 1);
                    *(half4*)&trig[pair][32 + g0]     = *(const half4*)&c8;
                    *(half4*)&trig[pair][32 + g0 + 4] = *((const half4*)&c8 + 1);
                }
            }
            __syncthreads();
            {
#pragma unroll
                for (int sub = 0; sub < 2; ++sub) {
                    const int row = wv * 32 + sub * 16 + m16;
                    half8 a0, a1;
                    *((half4*)&a0)     = *(const half4*)&trig[row][quad * 8];
                    *((half4*)&a0 + 1) = *(const half4*)&trig[row][quad * 8 + 4];
                    *((half4*)&a1)     = *(const half4*)&trig[row][32 + quad * 8];
                    *((half4*)&a1 + 1) = *(const half4*)&trig[row][32 + quad * 8 + 4];
                    floatx4 acc = {};
                    acc = __builtin_amdgcn_mfma_f32_16x16x32_f16(a0, bf0, acc, 0, 0, 0);
                    acc = __builtin_amdgcn_mfma_f32_16x16x32_f16(a1, bf1, acc, 0, 0, 0);
                    if (m16 < 8) {
#pragma unroll
                        for (int r = 0; r < 4; ++r) {
                            const int pair = wv * 32 + sub * 16 + quad * 4 + r;
                            const float wg = acc[r] + bgs[m16];
                            const float gl = flog(fmaxf(wg, 1e-6f)) * mobja[pair];
                            gb[(size_t)m16 * 8192 + jbase + pair] = (_Float16)gl;
                        }
                    }
                }
            }
            __syncthreads();
        }
    }
}

// ---------------- MFMA GEMM, output proj: 64x64 tiles, 512 blocks ----------------
__global__ __launch_bounds__(256) void gemm1(
    const ushort* __restrict__ att, const ushort* __restrict__ wt,
    const float* __restrict__ biasf, void* __restrict__ dout,
    const int* __restrict__ flagp) {
    const int isbf = *flagp;
    const ushort* W = wt + (size_t)3 * 262144;
    const float* bias = biasf + 3 * 512;
    const int row0 = blockIdx.x * 64, col0 = blockIdx.y * 64;
    const int t = threadIdx.x, wv = t >> 6, lane = t & 63;
    const int m16 = lane & 15, quad = lane >> 4;

    __shared__ ushort As[64][40];
    __shared__ ushort Ws[64][40];
    floatx4 acc[4] = {};

    const int ar = t >> 2, ac = (t & 3) * 8;

    short8 ps, pw;
    auto loadA = [&](int k0) {
        ps = *(const short8*)(att + (size_t)(row0 + ar) * D_ + k0 + ac);
        pw = *(const short8*)(W + (size_t)(col0 + ar) * D_ + k0 + ac);
    };

    loadA(0);
    for (int k0 = 0; k0 < D_; k0 += 32) {
        __syncthreads();
        *(short8*)&As[ar][ac] = ps;
        *(short8*)&Ws[ar][ac] = pw;
        __syncthreads();
        if (k0 + 32 < D_) loadA(k0 + 32);

        const short8 a0 = *(const short8*)&As[wv * 16 + m16][quad * 8];
        const short8 b0 = *(const short8*)&Ws[m16][quad * 8];
        const short8 b1 = *(const short8*)&Ws[16 + m16][quad * 8];
        const short8 b2 = *(const short8*)&Ws[32 + m16][quad * 8];
        const short8 b3 = *(const short8*)&Ws[48 + m16][quad * 8];
        acc[0] = __builtin_amdgcn_mfma_f32_16x16x32_bf16(a0, b0, acc[0], 0, 0, 0);
        acc[1] = __builtin_amdgcn_mfma_f32_16x16x32_bf16(a0, b1, acc[1], 0, 0, 0);
        acc[2] = __builtin_amdgcn_mfma_f32_16x16x32_bf16(a0, b2, acc[2], 0, 0, 0);
        acc[3] = __builtin_amdgcn_mfma_f32_16x16x32_bf16(a0, b3, acc[3], 0, 0, 0);
    }

#pragma unroll
    for (int nt = 0; nt < 4; ++nt) {
        const int colg = col0 + nt * 16 + m16;
        const float bi = bias[colg];
#pragma unroll
        for (int r = 0; r < 4; ++r) {
            const int row = row0 + wv * 16 + quad * 4 + r;
            const float v = acc[nt][r] + bi;
            if (isbf) ((ushort*)dout)[(size_t)row * D_ + colg] = f2bf(v);
            else      ((float*)dout)[(size_t)row * D_ + colg] = v;
        }
    }
}

// ---------------- MFMA attention (proven, unchanged) ----------------
__global__ __launch_bounds__(256) void attn3(
    const ushort* __restrict__ qw, const ushort* __restrict__ kw,
    const ushort* __restrict__ vt, const int* __restrict__ mask,
    const ushort* __restrict__ glog, ushort* __restrict__ att, int b0) {
    const int it = blockIdx.x, h = blockIdx.y, bl = blockIdx.z;
    const int bg = b0 + bl;
    const int i0 = it * 16;
    const int t = threadIdx.x, wv = t >> 6, lane = t & 63;
    const int m16 = lane & 15, quad = lane >> 4;
    const size_t bh = (size_t)(bg * H_ + h);

    __shared__ float lg[16][516];
    __shared__ ushort sbuf[16 * 520];
    __shared__ float rsumInv[16];

    {
        const uint4* src = (const uint4*)(glog + (((size_t)bl * 32 + it) * 8 + h) * 8192);
        uint4* dst = (uint4*)sbuf;
#pragma unroll
        for (int e = 0; e < 4; ++e) dst[t + 256 * e] = src[t + 256 * e];
    }
    const ushort* qrow = qw + (bh * N_ + i0 + m16) * DK_ + quad * 8;
    const short8 aq0 = *(const short8*)(qrow);
    const short8 aq1 = *(const short8*)(qrow + 32);
    __syncthreads();

#pragma unroll
    for (int tt = 0; tt < 8; ++tt) {
        const int j0 = wv * 128 + tt * 16;
        const ushort* krow = kw + (bh * N_ + j0 + m16) * DK_ + quad * 8;
        const short8 bk0 = *(const short8*)(krow);
        const short8 bk1 = *(const short8*)(krow + 32);
        floatx4 acc = {};
        acc = __builtin_amdgcn_mfma_f32_16x16x32_bf16(aq0, bk0, acc, 0, 0, 0);
        acc = __builtin_amdgcn_mfma_f32_16x16x32_bf16(aq1, bk1, acc, 0, 0, 0);
        const int mj = mask[bg * N_ + j0 + m16];
        const __half* gt = (const __half*)sbuf;
#pragma unroll
        for (int r = 0; r < 4; ++r) {
            const int i = quad * 4 + r;
            const float g = __half2float(gt[i * 512 + j0 + m16]);
            lg[i][j0 + m16] = (mj ? 0.125f * acc[r] : -1e9f) + g;
        }
    }
    __syncthreads();

    {
        const int row = t >> 4, l = t & 15;
        float v[32];
        float mx = -3e38f;
#pragma unroll
        for (int s = 0; s < 32; ++s) { v[s] = lg[row][l + 16 * s]; mx = fmaxf(mx, v[s]); }
#pragma unroll
        for (int d = 1; d < 16; d <<= 1) mx = fmaxf(mx, __shfl_xor(mx, d, 16));
        float sm = 0.f;
#pragma unroll
        for (int s = 0; s < 32; ++s) { const float p = fexp(v[s] - mx); sm += p; v[s] = p; }
#pragma unroll
        for (int d = 1; d < 16; d <<= 1) sm += __shfl_xor(sm, d, 16);
#pragma unroll
        for (int s = 0; s < 32; ++s)
            sbuf[row * 520 + l + 16 * s] = (ushort)((__float_as_uint(v[s]) + 0x8000u) >> 16);
        if (l == 0) rsumInv[row] = 1.0f / sm;
    }
    __syncthreads();

    {
        const int dk0 = wv * 16;
        const ushort* vrow = vt + (bh * DK_ + dk0 + m16) * N_ + quad * 8;
        floatx4 oc = {};
#pragma unroll
        for (int kc = 0; kc < 16; ++kc) {
            const short8 ap = *(const short8*)(sbuf + m16 * 520 + kc * 32 + quad * 8);
            const short8 bv = *(const short8*)(vrow + kc * 32);
            oc = __builtin_amdgcn_mfma_f32_16x16x32_bf16(ap, bv, oc, 0, 0, 0);
        }
#pragma unroll
        for (int r = 0; r < 4; ++r) {
            const int i = quad * 4 + r;
            const float o = oc[r] * rsumInv[i];
            att[((size_t)(bg * N_ + i0 + i)) * D_ + h * DK_ + dk0 + m16] = f2bf(o);
        }
    }
}

// ================= tier-3 fallback (round-3 proven, unchanged) =================
__global__ __launch_bounds__(256) void gemm16(const void* __restrict__ A,
                                              const void* __restrict__ W,
                                              const void* __restrict__ bias,
                                              void* __restrict__ out,
                                              const int* __restrict__ flagp,
                                              int a_follows, int mode) {
    const int isbf = *flagp;
    const int a_isbf = a_follows ? isbf : 1;
    const int wave = threadIdx.x >> 6;
    const int tile = blockIdx.x * 4 + wave;
    const int tm = tile >> 5, tn = tile & 31;
    const int row0 = tm * 16, col0 = tn * 16;
    const int lane = threadIdx.x & 63;
    const int m = lane & 15, quad = lane >> 4;
    floatx4 acc = {0.f, 0.f, 0.f, 0.f};
    const size_t abase = (size_t)(row0 + m) * D_ + quad * 8;
    const size_t wbase = (size_t)(quad * 8) * D_ + col0 + m;
    for (int k0 = 0; k0 < D_; k0 += 32) {
        short8 af, bf;
#pragma unroll
        for (int j = 0; j < 8; ++j) af[j] = ldb(A, abase + k0 + j, a_isbf);
#pragma unroll
        for (int j = 0; j < 8; ++j) bf[j] = ldb(W, wbase + (size_t)(k0 + j) * D_, isbf);
        acc = __builtin_amdgcn_mfma_f32_16x16x32_bf16(af, bf, acc, 0, 0, 0);
    }
    const int col = col0 + m;
    const float bi = ldf(bias, col, isbf);
#pragma unroll
    for (int r = 0; r < 4; ++r) {
        const int row = row0 + quad * 4 + r;
        const float v = acc[r] + bi;
        if (mode == 1) {
            ((ushort*)out)[(size_t)(((row >> 9) * H_ + (col >> 6)) * N_ + (row & 511)) * DK_ + (col & 63)] = f2bf(v);
        } else if (isbf) {
            ((ushort*)out)[(size_t)row * D_ + col] = f2bf(v);
        } else {
            ((float*)out)[(size_t)row * D_ + col] = v;
        }
    }
}

__global__ __launch_bounds__(256) void attn_old(
    const ushort* __restrict__ qw, const ushort* __restrict__ kw,
    const ushort* __restrict__ vw, const void* __restrict__ box,
    const int* __restrict__ mask, const int* __restrict__ nobj,
    const void* __restrict__ WG, const void* __restrict__ bG,
    ushort* __restrict__ att, const int* __restrict__ flagp) {
    const int isbf = *flagp;
    const int b = blockIdx.z, h = blockIdx.y;
    const int i0 = blockIdx.x * 8;
    const int t = threadIdx.x;
    __shared__ float lg[8][520];
    __shared__ float q_s[8][68];
    __shared__ float wgh[64];
    __shared__ float cxi[8], cyi[8], rwi[8], rhi[8], lwi[8], lhi[8];
    __shared__ int noi[8];
    __shared__ float rsum[8];
    for (int e = t; e < 512; e += 256) {
        const int ii = e >> 6, dk = e & 63;
        q_s[ii][dk] = bf2f(qw[(size_t)((b * H_ + h) * N_ + i0 + ii) * DK_ + dk]) * 0.125f;
    }
    if (t < 64) wgh[t] = ldf(WG, h * 64 + t, isbf);
    if (t < 8) {
        const size_t bb = (size_t)(b * N_ + i0 + t) * 4;
        const float xmn = ldf(box, bb + 0, isbf), ymn = ldf(box, bb + 1, isbf);
        const float xmx = ldf(box, bb + 2, isbf), ymx = ldf(box, bb + 3, isbf);
        const float w = xmx - xmn + 1.0f, hh = ymx - ymn + 1.0f;
        cxi[t] = (xmn + xmx) * 0.5f;
        cyi[t] = (ymn + ymx) * 0.5f;
        rwi[t] = 1.0f / w;
        rhi[t] = 1.0f / hh;
        lwi[t] = __logf(w);
        lhi[t] = __logf(hh);
        noi[t] = nobj[b * N_ + i0 + t];
    }
    const float bg = ldf(bG, h, isbf);
    __syncthreads();
    for (int jl = 0; jl < 2; ++jl) {
        const int j = t + jl * 256;
        float acc[8];
#pragma unroll
        for (int ii = 0; ii < 8; ++ii) acc[ii] = 0.f;
        const uint4* krow = (const uint4*)(kw + (size_t)((b * H_ + h) * N_ + j) * DK_);
#pragma unroll
        for (int c = 0; c < 8; ++c) {
            const uint4 ku = krow[c];
            float kf[8];
            kf[0] = blo(ku.x); kf[1] = bhi(ku.x); kf[2] = blo(ku.y); kf[3] = bhi(ku.y);
            kf[4] = blo(ku.z); kf[5] = bhi(ku.z); kf[6] = blo(ku.w); kf[7] = bhi(ku.w);
#pragma unroll
            for (int ii = 0; ii < 8; ++ii) {
                const float4 qa = *(const float4*)(&q_s[ii][c * 8]);
                const float4 qb = *(const float4*)(&q_s[ii][c * 8 + 4]);
                acc[ii] += qa.x * kf[0] + qa.y * kf[1] + qa.z * kf[2] + qa.w * kf[3] +
                           qb.x * kf[4] + qb.y * kf[5] + qb.z * kf[6] + qb.w * kf[7];
            }
        }
        const int mj = mask[b * N_ + j];
        const size_t bb = (size_t)(b * N_ + j) * 4;
        const float xmn = ldf(box, bb + 0, isbf), ymn = ldf(box, bb + 1, isbf);
        const float xmx = ldf(box, bb + 2, isbf), ymx = ldf(box, bb + 3, isbf);
        const float cxj = (xmn + xmx) * 0.5f, cyj = (ymn + ymx) * 0.5f;
        const float wj = xmx - xmn + 1.0f, hj = ymx - ymn + 1.0f;
        const float lwj = __logf(wj), lhj = __logf(hj);
        const int noj = nobj[b * N_ + j];
        const float dm[8] = {1.0f, 0.421696503f, 0.177827941f, 0.074989421f,
                             0.031622777f, 0.013335214f, 0.005623413f, 0.002371374f};
        for (int ii = 0; ii < 8; ++ii) {
            const float mobj = (noi[ii] || noj) ? 0.f : 1.f;
            const float dx = __logf(fmaxf(fabsf((cxi[ii] - cxj) * rwi[ii]), 0.001f));
            const float dy = __logf(fmaxf(fabsf((cyi[ii] - cyj) * rhi[ii]), 0.001f));
            const float pos[4] = {dx, dy, lwi[ii] - lwj, lhi[ii] - lhj};
            float wg = bg;
            for (int p = 0; p < 4; ++p) {
                const float base = 100.f * pos[p];
#pragma unroll
                for (int f = 0; f < 8; ++f) {
                    float sv, cv;
                    __sincosf(base * dm[f], &sv, &cv);
                    const int g = p * 8 + f;
                    wg += sv * wgh[g] + cv * wgh[32 + g];
                }
            }
            lg[ii][j] = (mj ? acc[ii] : -1e9f) + __logf(fmaxf(wg, 1e-6f)) * mobj;
        }
    }
    __syncthreads();
    {
        const int rr = t >> 5, l32 = t & 31;
        float mx = -3e38f;
        for (int j = l32; j < N_; j += 32) mx = fmaxf(mx, lg[rr][j]);
#pragma unroll
        for (int d = 1; d < 32; d <<= 1) mx = fmaxf(mx, __shfl_xor(mx, d, 32));
        float sm = 0.f;
        for (int j = l32; j < N_; j += 32) {
            const float p = __expf(lg[rr][j] - mx);
            lg[rr][j] = p;
            sm += p;
        }
#pragma unroll
        for (int d = 1; d < 32; d <<= 1) sm += __shfl_xor(sm, d, 32);
        if (l32 == 0) rsum[rr] = sm;
    }
    __syncthreads();
    {
        const int ii = t >> 5, dkp = t & 31;
        float o0 = 0.f, o1 = 0.f;
        const uint* vbase = (const uint*)vw + (size_t)((b * H_ + h) * N_) * (DK_ / 2) + dkp;
        for (int j = 0; j < N_; ++j) {
            const uint u = vbase[(size_t)j * (DK_ / 2)];
            const float p = lg[ii][j];
            o0 += p * blo(u);
            o1 += p * bhi(u);
        }
        const float inv = 1.0f / rsum[ii];
        const uint pk = (uint)f2bf(o0 * inv) | ((uint)f2bf(o1 * inv) << 16);
        ((uint*)att)[(size_t)(b * N_ + i0 + ii) * (D_ / 2) + h * 32 + dkp] = pk;
    }
}

extern "C" void kernel_launch(void* const* d_in, const int* in_sizes, int n_in,
                              void* d_out, int out_size, void* d_ws, size_t ws_size,
                              hipStream_t stream) {
    const void* xq = d_in[0];
    const void* xk = d_in[1];
    const void* xv = d_in[2];
    const void* box = d_in[3];
    const int* mask = (const int*)d_in[4];
    const int* nobj = (const int*)d_in[5];
    const void* Wq = d_in[6];
    const void* bq = d_in[7];
    const void* Wk = d_in[8];
    const void* bk = d_in[9];
    const void* Wv = d_in[10];
    const void* bv = d_in[11];
    const void* Wo = d_in[12];
    const void* bo = d_in[13];
    const void* WG = d_in[14];
    const void* bG = d_in[15];

    char* ws = (char*)d_ws;
    const size_t MB = 1u << 20;

    if (ws_size >= 54 * MB) {   // tier-1 (confirmed active since round 3)
        int* flag = (int*)ws;
        float* biasf = (float*)(ws + 4096);
        ushort* wt = (ushort*)(ws + 16384);
        size_t p = 16384 + 2097152;
        ushort* qw = (ushort*)(ws + p); p += 4194304;
        ushort* kw = (ushort*)(ws + p); p += 4194304;
        ushort* vt = (ushort*)(ws + p); p += 4194304;
        ushort* att = (ushort*)(ws + p); p += 4194304;
        ushort* glog = (ushort*)(ws + p);   // 32 MB: [bl][it][h][16][512] fp16

        hipLaunchKernelGGL(transw, dim3(16, 16, 4), dim3(256), 0, stream,
                           Wq, Wk, Wv, Wo, bq, bk, bv, bo, (const uint*)xq,
                           wt, biasf, flag);
        hipLaunchKernelGGL(stage1, dim3(5632), dim3(256), 0, stream,
                           xq, xk, xv, wt, biasf, qw, kw, vt,
                           box, nobj, WG, bG, glog, flag);
        hipLaunchKernelGGL(attn3, dim3(32, H_, B_), dim3(256), 0, stream,
                           qw, kw, vt, mask, glog, att, 0);
        hipLaunchKernelGGL(gemm1, dim3(64, 8), dim3(256), 0, stream,
                           att, wt, biasf, d_out, flag);
    } else {
        // tier-3 fallback (proven round-3 path, ~16.6 MB)
        int* flag = (int*)ws;
        ushort* qw = (ushort*)(ws + 256);
        ushort* kw = (ushort*)(ws + 256 + 4194304);
        ushort* vw = (ushort*)(ws + 256 + 8388608);
        ushort* att = (ushort*)(ws + 256 + 12582912);
        hipLaunchKernelGGL(probe_dtype, dim3(1), dim3(256), 0, stream, (const uint*)xq, flag);
        hipLaunchKernelGGL(gemm16, dim3(2048), dim3(256), 0, stream, xq, Wq, bq, (void*)qw, flag, 1, 1);
        hipLaunchKernelGGL(gemm16, dim3(2048), dim3(256), 0, stream, xk, Wk, bk, (void*)kw, flag, 1, 1);
        hipLaunchKernelGGL(gemm16, dim3(2048), dim3(256), 0, stream, xv, Wv, bv, (void*)vw, flag, 1, 1);
        hipLaunchKernelGGL(attn_old, dim3(N_ / 8, H_, B_), dim3(256), 0, stream,
                           qw, kw, vw, box, mask, nobj, WG, bG, att, flag);
        hipLaunchKernelGGL(gemm16, dim3(2048), dim3(256), 0, stream, att, Wo, bo, d_out, flag, 0, 2);
    }
}

// Round 11
// 186.607 us; speedup vs baseline: 7.7226x; 1.0062x over previous
//
#include <hip/hip_runtime.h>
#include <hip/hip_fp16.h>

#define B_ 8
#define N_ 512
#define D_ 512
#define H_ 8
#define DK_ 64

typedef unsigned int uint;
typedef unsigned short ushort;
typedef __attribute__((ext_vector_type(8))) short short8;
typedef __attribute__((ext_vector_type(8))) _Float16 half8;
typedef __attribute__((ext_vector_type(4))) _Float16 half4;
typedef __attribute__((ext_vector_type(4))) float floatx4;

__device__ __forceinline__ float bf2f(ushort s) { return __uint_as_float(((uint)s) << 16); }
__device__ __forceinline__ ushort f2bf(float f) {
    uint x = __float_as_uint(f);
    return (ushort)((x + 0x7fffu + ((x >> 16) & 1u)) >> 16);
}
__device__ __forceinline__ float blo(uint u) { return __uint_as_float(u << 16); }
__device__ __forceinline__ float bhi(uint u) { return __uint_as_float(u & 0xffff0000u); }
__device__ __forceinline__ float ldf(const void* p, size_t i, int isbf) {
    return isbf ? bf2f(((const ushort*)p)[i]) : ((const float*)p)[i];
}
__device__ __forceinline__ short ldb(const void* p, size_t i, int isbf) {
    return isbf ? (short)(((const ushort*)p)[i]) : (short)f2bf(((const float*)p)[i]);
}
__device__ __forceinline__ float4 ldbox(const void* p, size_t row, int isbf) {
    if (isbf) {
        const uint2 u = ((const uint2*)p)[row];
        return make_float4(blo(u.x), bhi(u.x), blo(u.y), bhi(u.y));
    }
    return ((const float4*)p)[row];
}
// ---- ISA-level fast math ----
__device__ __forceinline__ float flog(float x) {
    return __builtin_amdgcn_logf(x) * 0.69314718056f;
}
__device__ __forceinline__ float fexp(float x) {
    return __builtin_amdgcn_exp2f(x * 1.44269504089f);
}
__device__ __forceinline__ void fsincos_rev(float rev, float* s, float* c) {
    const float fr = rev - floorf(rev);
    *s = __builtin_amdgcn_sinf(fr);
    *c = __builtin_amdgcn_cosf(fr);
}
__device__ __forceinline__ uint pkbf(uint a, uint b) {
    return __builtin_amdgcn_perm(b + 0x8000u, a + 0x8000u, 0x07060302u);
}
// dtype sniff over first 4096 words (per-block redundant compute; deterministic)
__device__ __forceinline__ int sniff_dtype(const uint* q, int* scratch) {
    const int t = threadIdx.x;
    int cnt = 0;
    for (int i = t; i < 4096; i += 256) {
        const uint e = (q[i] >> 7) & 0xffu;
        cnt += (e >= 0x70u && e <= 0x84u) ? 1 : 0;
    }
    scratch[t] = cnt;
    __syncthreads();
    for (int d = 128; d > 0; d >>= 1) {
        if (t < d) scratch[t] += scratch[t + d];
        __syncthreads();
    }
    const int r = (scratch[0] > 3276) ? 1 : 0;
    __syncthreads();
    return r;
}

// ---------------- dtype probe (tier-3 only) ----------------
__global__ __launch_bounds__(256) void probe_dtype(const uint* __restrict__ q,
                                                   int* __restrict__ flag) {
    __shared__ int s[256];
    const int r = sniff_dtype(q, s);
    if (threadIdx.x == 0) *flag = r;
}

// ---------------- W transpose + bias convert + flag publish ----------------
__global__ __launch_bounds__(256) void transw(const void* __restrict__ w0,
                                              const void* __restrict__ w1,
                                              const void* __restrict__ w2,
                                              const void* __restrict__ w3,
                                              const void* __restrict__ b0,
                                              const void* __restrict__ b1,
                                              const void* __restrict__ b2,
                                              const void* __restrict__ b3,
                                              const uint* __restrict__ xq,
                                              ushort* __restrict__ wt,
                                              float* __restrict__ biasf,
                                              int* __restrict__ flag) {
    __shared__ int cnt_s[256];
    const int isbf = sniff_dtype(xq, cnt_s);
    const int z = blockIdx.z;
    const void* W = (z == 0) ? w0 : (z == 1) ? w1 : (z == 2) ? w2 : w3;
    const int n0 = blockIdx.x * 32, k0 = blockIdx.y * 32;
    __shared__ float tile[32][33];
    const int tx = threadIdx.x & 31, ty = threadIdx.x >> 5;
#pragma unroll
    for (int r = 0; r < 4; ++r)
        tile[ty + 8 * r][tx] = ldf(W, (size_t)(k0 + ty + 8 * r) * D_ + n0 + tx, isbf);
    if (blockIdx.x == 0 && blockIdx.y == 0) {
        const void* bz = (z == 0) ? b0 : (z == 1) ? b1 : (z == 2) ? b2 : b3;
        for (int e = threadIdx.x; e < 512; e += 256)
            biasf[z * 512 + e] = ldf(bz, e, isbf);
        if (z == 0 && threadIdx.x == 0) *flag = isbf;
    }
    __syncthreads();
#pragma unroll
    for (int r = 0; r < 4; ++r)
        wt[(size_t)z * 262144 + (size_t)(n0 + ty + 8 * r) * D_ + k0 + tx] =
            f2bf(tile[tx][ty + 8 * r]);
}

// ---------------- stage1: interleaved QKV-GEMM (64x64 tiles) + geometry ----------------
// 512 groups x 11 blocks: k<3 -> gemm (1536), else geom (4096). Total 5632.
// smem 20352 B -> 8 blocks/CU.
__global__ __launch_bounds__(256) void stage1(
    const void* __restrict__ xq, const void* __restrict__ xk, const void* __restrict__ xv,
    const ushort* __restrict__ wt, const float* __restrict__ biasf,
    ushort* __restrict__ oq, ushort* __restrict__ ok, ushort* __restrict__ ov,
    const void* __restrict__ box, const int* __restrict__ nobj,
    const void* __restrict__ WG, const void* __restrict__ bG,
    ushort* __restrict__ glog, const int* __restrict__ flagp) {
    __shared__ __align__(16) char smem[20352];
    const int isbf = *flagp;
    const int grp = blockIdx.x / 11, kk = blockIdx.x % 11;
    const int t = threadIdx.x, wv = t >> 6, lane = t & 63;
    const int m16 = lane & 15, quad = lane >> 4;

    if (kk < 3) {
        // ================= GEMM path: 64x64 tile =================
        const int id = grp * 3 + kk;
        const int z = id >> 9, rem = id & 511;
        const int row0 = (rem & 63) * 64, col0 = (rem >> 6) * 64;
        const char* A = (const char*)((z == 0) ? xq : (z == 1) ? xk : xv);
        const ushort* W = wt + (size_t)z * 262144;
        const float* bias = biasf + z * 512;
        ushort (*As)[40] = (ushort(*)[40])smem;
        ushort (*Ws)[40] = (ushort(*)[40])(smem + 5120);
        floatx4 acc[4] = {};

        const int ar = t >> 2, ac = (t & 3) * 8;

        uint4 ua, ub;
        short8 ps, pw;
        auto loadA = [&](int k0) {
            const size_t e = (size_t)(row0 + ar) * D_ + k0 + ac;
            if (isbf) {
                ps = *(const short8*)(A + 2 * e);
            } else {
                const uint* ap = (const uint*)A + e;
                ua = *(const uint4*)(ap);
                ub = *(const uint4*)(ap + 4);
            }
            pw = *(const short8*)(W + (size_t)(col0 + ar) * D_ + k0 + ac);
        };
        auto stage = [&]() {
            if (isbf) {
                *(short8*)&As[ar][ac] = ps;
            } else {
                uint4 lo;
                lo.x = pkbf(ua.x, ua.y); lo.y = pkbf(ua.z, ua.w);
                lo.z = pkbf(ub.x, ub.y); lo.w = pkbf(ub.z, ub.w);
                *(uint4*)&As[ar][ac] = lo;
            }
            *(short8*)&Ws[ar][ac] = pw;
        };

        loadA(0);
        for (int k0 = 0; k0 < D_; k0 += 32) {
            __syncthreads();
            stage();
            __syncthreads();
            if (k0 + 32 < D_) loadA(k0 + 32);

            const short8 a0 = *(const short8*)&As[wv * 16 + m16][quad * 8];
            const short8 b0 = *(const short8*)&Ws[m16][quad * 8];
            const short8 b1 = *(const short8*)&Ws[16 + m16][quad * 8];
            const short8 b2 = *(const short8*)&Ws[32 + m16][quad * 8];
            const short8 b3 = *(const short8*)&Ws[48 + m16][quad * 8];
            acc[0] = __builtin_amdgcn_mfma_f32_16x16x32_bf16(a0, b0, acc[0], 0, 0, 0);
            acc[1] = __builtin_amdgcn_mfma_f32_16x16x32_bf16(a0, b1, acc[1], 0, 0, 0);
            acc[2] = __builtin_amdgcn_mfma_f32_16x16x32_bf16(a0, b2, acc[2], 0, 0, 0);
            acc[3] = __builtin_amdgcn_mfma_f32_16x16x32_bf16(a0, b3, acc[3], 0, 0, 0);
        }

#pragma unroll
        for (int nt = 0; nt < 4; ++nt) {
            const int colg = col0 + nt * 16 + m16;
            const float bi = bias[colg];
            const float v0 = acc[nt][0] + bi, v1 = acc[nt][1] + bi;
            const float v2 = acc[nt][2] + bi, v3 = acc[nt][3] + bi;
            const int rowb = row0 + wv * 16 + quad * 4;
            if (z == 2) {
                const int bhv = (rowb >> 9) * H_ + (colg >> 6);
                uint2 pk;
                pk.x = (uint)f2bf(v0) | ((uint)f2bf(v1) << 16);
                pk.y = (uint)f2bf(v2) | ((uint)f2bf(v3) << 16);
                *(uint2*)(ov + ((size_t)bhv * DK_ + (colg & 63)) * N_ + (rowb & 511)) = pk;
            } else {
                ushort* o = (z == 0) ? oq : ok;
                const float vv[4] = {v0, v1, v2, v3};
#pragma unroll
                for (int r = 0; r < 4; ++r) {
                    const int row = rowb + r;
                    o[((size_t)((row >> 9) * H_ + (colg >> 6)) * N_ + (row & 511)) * DK_ +
                      (colg & 63)] = f2bf(vv[r]);
                }
            }
        }
    } else {
        // ================= geometry path =================
        const int id = grp * 8 + (kk - 3);
        const int i = id & 511, bl = id >> 9;
        _Float16 (*trig)[68] = (_Float16(*)[68])smem;                 // 17408 B
        _Float16 (*wgf)[72] = (_Float16(*)[72])(smem + 17408);        // 2304 B
        float* mobja = (float*)(smem + 19712);                        // 512 B
        float* bgs = (float*)(smem + 20224);                          // 32 B

        for (int e = t; e < 1024; e += 256) {
            const int h = e >> 6, g = e & 63;
            wgf[h][g] = (_Float16)((h < 8) ? ldf(WG, (size_t)h * 64 + g, isbf) : 0.f);
        }
        if (t < 8) bgs[t] = ldf(bG, t, isbf);

        const float4 bi4 = ldbox(box, (size_t)bl * N_ + i, isbf);
        const float wi = bi4.z - bi4.x + 1.0f, hi = bi4.w - bi4.y + 1.0f;
        const float cxi = (bi4.x + bi4.z) * 0.5f, cyi = (bi4.y + bi4.w) * 0.5f;
        const float rwi = 1.0f / wi, rhi = 1.0f / hi;
        const float lwi = flog(wi), lhi = flog(hi);
        const int noi = nobj[bl * N_ + i];
        __syncthreads();

        const half8 bf0 = *(const half8*)&wgf[m16][quad * 8];
        const half8 bf1 = *(const half8*)&wgf[m16][quad * 8 + 32];
        _Float16* gb = (_Float16*)glog +
                       ((((size_t)bl * 32 + (i >> 4)) * 8) * 16 + (i & 15)) * 512;
        const float dmrev[8] = {15.915494f, 6.7115083f, 2.8302207f, 1.1934936f,
                                0.50329214f, 0.21223603f, 0.089498095f, 0.037742074f};

        for (int c = 0; c < 4; ++c) {
            const int jbase = c * 128;
            {
                const int pair = t >> 1, hf = t & 1;
                const int j = jbase + pair;
                const float4 bj4 = ldbox(box, (size_t)bl * N_ + j, isbf);
                const float wj = bj4.z - bj4.x + 1.0f, hj = bj4.w - bj4.y + 1.0f;
                float p0, p1;
                if (hf == 0) {
                    const float cxj = (bj4.x + bj4.z) * 0.5f, cyj = (bj4.y + bj4.w) * 0.5f;
                    p0 = flog(fmaxf(fabsf((cxi - cxj) * rwi), 0.001f));
                    p1 = flog(fmaxf(fabsf((cyi - cyj) * rhi), 0.001f));
                    mobja[pair] = (noi || nobj[bl * N_ + j]) ? 0.f : 1.f;
                } else {
                    p0 = lwi - flog(wj);
                    p1 = lhi - flog(hj);
                }
#pragma unroll
                for (int pp = 0; pp < 2; ++pp) {
                    const float base = pp ? p1 : p0;
                    half8 s8, c8;
#pragma unroll
                    for (int f = 0; f < 8; ++f) {
                        float sv, cv;
                        fsincos_rev(base * dmrev[f], &sv, &cv);
                        s8[f] = (_Float16)sv;
                        c8[f] = (_Float16)cv;
                    }
                    const int g0 = hf * 16 + pp * 8;
                    *(half4*)&trig[pair][g0]          = *(const half4*)&s8;
                    *(half4*)&trig[pair][g0 + 4]      = *((const half4*)&s8 + 1);
                    *(half4*)&trig[pair][32 + g0]     = *(const half4*)&c8;
                    *(half4*)&trig[pair][32 + g0 + 4] = *((const half4*)&c8 + 1);
                }
            }
            __syncthreads();
            {
#pragma unroll
                for (int sub = 0; sub < 2; ++sub) {
                    const int row = wv * 32 + sub * 16 + m16;
                    half8 a0, a1;
                    *((half4*)&a0)     = *(const half4*)&trig[row][quad * 8];
                    *((half4*)&a0 + 1) = *(const half4*)&trig[row][quad * 8 + 4];
                    *((half4*)&a1)     = *(const half4*)&trig[row][32 + quad * 8];
                    *((half4*)&a1 + 1) = *(const half4*)&trig[row][32 + quad * 8 + 4];
                    floatx4 acc = {};
                    acc = __builtin_amdgcn_mfma_f32_16x16x32_f16(a0, bf0, acc, 0, 0, 0);
                    acc = __builtin_amdgcn_mfma_f32_16x16x32_f16(a1, bf1, acc, 0, 0, 0);
                    if (m16 < 8) {
#pragma unroll
                        for (int r = 0; r < 4; ++r) {
                            const int pair = wv * 32 + sub * 16 + quad * 4 + r;
                            const float wg = acc[r] + bgs[m16];
                            const float gl = flog(fmaxf(wg, 1e-6f)) * mobja[pair];
                            gb[(size_t)m16 * 8192 + jbase + pair] = (_Float16)gl;
                        }
                    }
                }
            }
            __syncthreads();
        }
    }
}

// ---------------- MFMA GEMM, output proj: 64x64 tiles, 512 blocks ----------------
__global__ __launch_bounds__(256) void gemm1(
    const ushort* __restrict__ att, const ushort* __restrict__ wt,
    const float* __restrict__ biasf, void* __restrict__ dout,
    const int* __restrict__ flagp) {
    const int isbf = *flagp;
    const ushort* W = wt + (size_t)3 * 262144;
    const float* bias = biasf + 3 * 512;
    const int row0 = blockIdx.x * 64, col0 = blockIdx.y * 64;
    const int t = threadIdx.x, wv = t >> 6, lane = t & 63;
    const int m16 = lane & 15, quad = lane >> 4;

    __shared__ ushort As[64][40];
    __shared__ ushort Ws[64][40];
    floatx4 acc[4] = {};

    const int ar = t >> 2, ac = (t & 3) * 8;

    short8 ps, pw;
    auto loadA = [&](int k0) {
        ps = *(const short8*)(att + (size_t)(row0 + ar) * D_ + k0 + ac);
        pw = *(const short8*)(W + (size_t)(col0 + ar) * D_ + k0 + ac);
    };

    loadA(0);
    for (int k0 = 0; k0 < D_; k0 += 32) {
        __syncthreads();
        *(short8*)&As[ar][ac] = ps;
        *(short8*)&Ws[ar][ac] = pw;
        __syncthreads();
        if (k0 + 32 < D_) loadA(k0 + 32);

        const short8 a0 = *(const short8*)&As[wv * 16 + m16][quad * 8];
        const short8 b0 = *(const short8*)&Ws[m16][quad * 8];
        const short8 b1 = *(const short8*)&Ws[16 + m16][quad * 8];
        const short8 b2 = *(const short8*)&Ws[32 + m16][quad * 8];
        const short8 b3 = *(const short8*)&Ws[48 + m16][quad * 8];
        acc[0] = __builtin_amdgcn_mfma_f32_16x16x32_bf16(a0, b0, acc[0], 0, 0, 0);
        acc[1] = __builtin_amdgcn_mfma_f32_16x16x32_bf16(a0, b1, acc[1], 0, 0, 0);
        acc[2] = __builtin_amdgcn_mfma_f32_16x16x32_bf16(a0, b2, acc[2], 0, 0, 0);
        acc[3] = __builtin_amdgcn_mfma_f32_16x16x32_bf16(a0, b3, acc[3], 0, 0, 0);
    }

#pragma unroll
    for (int nt = 0; nt < 4; ++nt) {
        const int colg = col0 + nt * 16 + m16;
        const float bi = bias[colg];
#pragma unroll
        for (int r = 0; r < 4; ++r) {
            const int row = row0 + wv * 16 + quad * 4 + r;
            const float v = acc[nt][r] + bi;
            if (isbf) ((ushort*)dout)[(size_t)row * D_ + colg] = f2bf(v);
            else      ((float*)dout)[(size_t)row * D_ + colg] = v;
        }
    }
}

// ---------------- MFMA attention: register logits, 17 KB LDS (8+ blocks/CU) ----------------
__global__ __launch_bounds__(256) void attn3(
    const ushort* __restrict__ qw, const ushort* __restrict__ kw,
    const ushort* __restrict__ vt, const int* __restrict__ mask,
    const ushort* __restrict__ glog, ushort* __restrict__ att, int b0) {
    const int it = blockIdx.x, h = blockIdx.y, bl = blockIdx.z;
    const int bg = b0 + bl;
    const int i0 = it * 16;
    const int t = threadIdx.x, wv = t >> 6, lane = t & 63;
    const int m16 = lane & 15, quad = lane >> 4;
    const size_t bh = (size_t)(bg * H_ + h);

    __shared__ ushort sbuf[16 * 520];   // phase A: glog fp16 [16][512]; later: P bf16 [16][520]
    __shared__ float red[16][4];
    __shared__ float rmax[16];
    __shared__ float rsumInv[16];

    {   // stage glog tile (contiguous 16 KB)
        const uint4* src = (const uint4*)(glog + (((size_t)bl * 32 + it) * 8 + h) * 8192);
        uint4* dst = (uint4*)sbuf;
#pragma unroll
        for (int e = 0; e < 4; ++e) dst[t + 256 * e] = src[t + 256 * e];
    }
    const ushort* qrow = qw + (bh * N_ + i0 + m16) * DK_ + quad * 8;
    const short8 aq0 = *(const short8*)(qrow);
    const short8 aq1 = *(const short8*)(qrow + 32);
    __syncthreads();

    // QK^T + glog add, logits held in registers (C-layout)
    float lt[8][4];
#pragma unroll
    for (int tt = 0; tt < 8; ++tt) {
        const int j0 = wv * 128 + tt * 16;
        const ushort* krow = kw + (bh * N_ + j0 + m16) * DK_ + quad * 8;
        const short8 bk0 = *(const short8*)(krow);
        const short8 bk1 = *(const short8*)(krow + 32);
        floatx4 acc = {};
        acc = __builtin_amdgcn_mfma_f32_16x16x32_bf16(aq0, bk0, acc, 0, 0, 0);
        acc = __builtin_amdgcn_mfma_f32_16x16x32_bf16(aq1, bk1, acc, 0, 0, 0);
        const int mj = mask[bg * N_ + j0 + m16];
        const __half* gt = (const __half*)sbuf;
#pragma unroll
        for (int r = 0; r < 4; ++r) {
            const int i = quad * 4 + r;
            const float g = __half2float(gt[i * 512 + j0 + m16]);
            lt[tt][r] = (mj ? 0.125f * acc[r] : -1e9f) + g;
        }
    }
    // row max: in-thread over tt, shuffle over the 16 lanes of the quad, LDS across waves
    {
        float pm[4];
#pragma unroll
        for (int r = 0; r < 4; ++r) {
            float m = lt[0][r];
#pragma unroll
            for (int tt = 1; tt < 8; ++tt) m = fmaxf(m, lt[tt][r]);
#pragma unroll
            for (int d = 1; d < 16; d <<= 1) m = fmaxf(m, __shfl_xor(m, d, 16));
            pm[r] = m;
        }
        if (m16 == 0) {
#pragma unroll
            for (int r = 0; r < 4; ++r) red[quad * 4 + r][wv] = pm[r];
        }
    }
    __syncthreads();
    if (t < 16) rmax[t] = fmaxf(fmaxf(red[t][0], red[t][1]), fmaxf(red[t][2], red[t][3]));
    __syncthreads();
    // exp, P -> sbuf bf16 (overwrites staged glog), partial sums
    {
        float ps[4];
#pragma unroll
        for (int r = 0; r < 4; ++r) {
            const int i = quad * 4 + r;
            const float mx = rmax[i];
            float s = 0.f;
#pragma unroll
            for (int tt = 0; tt < 8; ++tt) {
                const float p = fexp(lt[tt][r] - mx);
                s += p;
                sbuf[i * 520 + wv * 128 + tt * 16 + m16] =
                    (ushort)((__float_as_uint(p) + 0x8000u) >> 16);
            }
#pragma unroll
            for (int d = 1; d < 16; d <<= 1) s += __shfl_xor(s, d, 16);
            ps[r] = s;
        }
        if (m16 == 0) {
#pragma unroll
            for (int r = 0; r < 4; ++r) red[quad * 4 + r][wv] = ps[r];
        }
    }
    __syncthreads();
    if (t < 16) rsumInv[t] = 1.0f / (red[t][0] + red[t][1] + red[t][2] + red[t][3]);
    __syncthreads();

    {   // PV: wave wv -> dk columns wv*16..+15
        const int dk0 = wv * 16;
        const ushort* vrow = vt + (bh * DK_ + dk0 + m16) * N_ + quad * 8;
        floatx4 oc = {};
#pragma unroll
        for (int kc = 0; kc < 16; ++kc) {
            const short8 ap = *(const short8*)(sbuf + m16 * 520 + kc * 32 + quad * 8);
            const short8 bv = *(const short8*)(vrow + kc * 32);
            oc = __builtin_amdgcn_mfma_f32_16x16x32_bf16(ap, bv, oc, 0, 0, 0);
        }
#pragma unroll
        for (int r = 0; r < 4; ++r) {
            const int i = quad * 4 + r;
            const float o = oc[r] * rsumInv[i];
            att[((size_t)(bg * N_ + i0 + i)) * D_ + h * DK_ + dk0 + m16] = f2bf(o);
        }
    }
}

// ================= tier-3 fallback (round-3 proven, unchanged) =================
__global__ __launch_bounds__(256) void gemm16(const void* __restrict__ A,
                                              const void* __restrict__ W,
                                              const void* __restrict__ bias,
                                              void* __restrict__ out,
                                              const int* __restrict__ flagp,
                                              int a_follows, int mode) {
    const int isbf = *flagp;
    const int a_isbf = a_follows ? isbf : 1;
    const int wave = threadIdx.x >> 6;
    const int tile = blockIdx.x * 4 + wave;
    const int tm = tile >> 5, tn = tile & 31;
    const int row0 = tm * 16, col0 = tn * 16;
    const int lane = threadIdx.x & 63;
    const int m = lane & 15, quad = lane >> 4;
    floatx4 acc = {0.f, 0.f, 0.f, 0.f};
    const size_t abase = (size_t)(row0 + m) * D_ + quad * 8;
    const size_t wbase = (size_t)(quad * 8) * D_ + col0 + m;
    for (int k0 = 0; k0 < D_; k0 += 32) {
        short8 af, bf;
#pragma unroll
        for (int j = 0; j < 8; ++j) af[j] = ldb(A, abase + k0 + j, a_isbf);
#pragma unroll
        for (int j = 0; j < 8; ++j) bf[j] = ldb(W, wbase + (size_t)(k0 + j) * D_, isbf);
        acc = __builtin_amdgcn_mfma_f32_16x16x32_bf16(af, bf, acc, 0, 0, 0);
    }
    const int col = col0 + m;
    const float bi = ldf(bias, col, isbf);
#pragma unroll
    for (int r = 0; r < 4; ++r) {
        const int row = row0 + quad * 4 + r;
        const float v = acc[r] + bi;
        if (mode == 1) {
            ((ushort*)out)[(size_t)(((row >> 9) * H_ + (col >> 6)) * N_ + (row & 511)) * DK_ + (col & 63)] = f2bf(v);
        } else if (isbf) {
            ((ushort*)out)[(size_t)row * D_ + col] = f2bf(v);
        } else {
            ((float*)out)[(size_t)row * D_ + col] = v;
        }
    }
}

__global__ __launch_bounds__(256) void attn_old(
    const ushort* __restrict__ qw, const ushort* __restrict__ kw,
    const ushort* __restrict__ vw, const void* __restrict__ box,
    const int* __restrict__ mask, const int* __restrict__ nobj,
    const void* __restrict__ WG, const void* __restrict__ bG,
    ushort* __restrict__ att, const int* __restrict__ flagp) {
    const int isbf = *flagp;
    const int b = blockIdx.z, h = blockIdx.y;
    const int i0 = blockIdx.x * 8;
    const int t = threadIdx.x;
    __shared__ float lg[8][520];
    __shared__ float q_s[8][68];
    __shared__ float wgh[64];
    __shared__ float cxi[8], cyi[8], rwi[8], rhi[8], lwi[8], lhi[8];
    __shared__ int noi[8];
    __shared__ float rsum[8];
    for (int e = t; e < 512; e += 256) {
        const int ii = e >> 6, dk = e & 63;
        q_s[ii][dk] = bf2f(qw[(size_t)((b * H_ + h) * N_ + i0 + ii) * DK_ + dk]) * 0.125f;
    }
    if (t < 64) wgh[t] = ldf(WG, h * 64 + t, isbf);
    if (t < 8) {
        const size_t bb = (size_t)(b * N_ + i0 + t) * 4;
        const float xmn = ldf(box, bb + 0, isbf), ymn = ldf(box, bb + 1, isbf);
        const float xmx = ldf(box, bb + 2, isbf), ymx = ldf(box, bb + 3, isbf);
        const float w = xmx - xmn + 1.0f, hh = ymx - ymn + 1.0f;
        cxi[t] = (xmn + xmx) * 0.5f;
        cyi[t] = (ymn + ymx) * 0.5f;
        rwi[t] = 1.0f / w;
        rhi[t] = 1.0f / hh;
        lwi[t] = __logf(w);
        lhi[t] = __logf(hh);
        noi[t] = nobj[b * N_ + i0 + t];
    }
    const float bg = ldf(bG, h, isbf);
    __syncthreads();
    for (int jl = 0; jl < 2; ++jl) {
        const int j = t + jl * 256;
        float acc[8];
#pragma unroll
        for (int ii = 0; ii < 8; ++ii) acc[ii] = 0.f;
        const uint4* krow = (const uint4*)(kw + (size_t)((b * H_ + h) * N_ + j) * DK_);
#pragma unroll
        for (int c = 0; c < 8; ++c) {
            const uint4 ku = krow[c];
            float kf[8];
            kf[0] = blo(ku.x); kf[1] = bhi(ku.x); kf[2] = blo(ku.y); kf[3] = bhi(ku.y);
            kf[4] = blo(ku.z); kf[5] = bhi(ku.z); kf[6] = blo(ku.w); kf[7] = bhi(ku.w);
#pragma unroll
            for (int ii = 0; ii < 8; ++ii) {
                const float4 qa = *(const float4*)(&q_s[ii][c * 8]);
                const float4 qb = *(const float4*)(&q_s[ii][c * 8 + 4]);
                acc[ii] += qa.x * kf[0] + qa.y * kf[1] + qa.z * kf[2] + qa.w * kf[3] +
                           qb.x * kf[4] + qb.y * kf[5] + qb.z * kf[6] + qb.w * kf[7];
            }
        }
        const int mj = mask[b * N_ + j];
        const size_t bb = (size_t)(b * N_ + j) * 4;
        const float xmn = ldf(box, bb + 0, isbf), ymn = ldf(box, bb + 1, isbf);
        const float xmx = ldf(box, bb + 2, isbf), ymx = ldf(box, bb + 3, isbf);
        const float cxj = (xmn + xmx) * 0.5f, cyj = (ymn + ymx) * 0.5f;
        const float wj = xmx - xmn + 1.0f, hj = ymx - ymn + 1.0f;
        const float lwj = __logf(wj), lhj = __logf(hj);
        const int noj = nobj[b * N_ + j];
        const float dm[8] = {1.0f, 0.421696503f, 0.177827941f, 0.074989421f,
                             0.031622777f, 0.013335214f, 0.005623413f, 0.002371374f};
        for (int ii = 0; ii < 8; ++ii) {
            const float mobj = (noi[ii] || noj) ? 0.f : 1.f;
            const float dx = __logf(fmaxf(fabsf((cxi[ii] - cxj) * rwi[ii]), 0.001f));
            const float dy = __logf(fmaxf(fabsf((cyi[ii] - cyj) * rhi[ii]), 0.001f));
            const float pos[4] = {dx, dy, lwi[ii] - lwj, lhi[ii] - lhj};
            float wg = bg;
            for (int p = 0; p < 4; ++p) {
                const float base = 100.f * pos[p];
#pragma unroll
                for (int f = 0; f < 8; ++f) {
                    float sv, cv;
                    __sincosf(base * dm[f], &sv, &cv);
                    const int g = p * 8 + f;
                    wg += sv * wgh[g] + cv * wgh[32 + g];
                }
            }
            lg[ii][j] = (mj ? acc[ii] : -1e9f) + __logf(fmaxf(wg, 1e-6f)) * mobj;
        }
    }
    __syncthreads();
    {
        const int rr = t >> 5, l32 = t & 31;
        float mx = -3e38f;
        for (int j = l32; j < N_; j += 32) mx = fmaxf(mx, lg[rr][j]);
#pragma unroll
        for (int d = 1; d < 32; d <<= 1) mx = fmaxf(mx, __shfl_xor(mx, d, 32));
        float sm = 0.f;
        for (int j = l32; j < N_; j += 32) {
            const float p = __expf(lg[rr][j] - mx);
            lg[rr][j] = p;
            sm += p;
        }
#pragma unroll
        for (int d = 1; d < 32; d <<= 1) sm += __shfl_xor(sm, d, 32);
        if (l32 == 0) rsum[rr] = sm;
    }
    __syncthreads();
    {
        const int ii = t >> 5, dkp = t & 31;
        float o0 = 0.f, o1 = 0.f;
        const uint* vbase = (const uint*)vw + (size_t)((b * H_ + h) * N_) * (DK_ / 2) + dkp;
        for (int j = 0; j < N_; ++j) {
            const uint u = vbase[(size_t)j * (DK_ / 2)];
            const float p = lg[ii][j];
            o0 += p * blo(u);
            o1 += p * bhi(u);
        }
        const float inv = 1.0f / rsum[ii];
        const uint pk = (uint)f2bf(o0 * inv) | ((uint)f2bf(o1 * inv) << 16);
        ((uint*)att)[(size_t)(b * N_ + i0 + ii) * (D_ / 2) + h * 32 + dkp] = pk;
    }
}

extern "C" void kernel_launch(void* const* d_in, const int* in_sizes, int n_in,
                              void* d_out, int out_size, void* d_ws, size_t ws_size,
                              hipStream_t stream) {
    const void* xq = d_in[0];
    const void* xk = d_in[1];
    const void* xv = d_in[2];
    const void* box = d_in[3];
    const int* mask = (const int*)d_in[4];
    const int* nobj = (const int*)d_in[5];
    const void* Wq = d_in[6];
    const void* bq = d_in[7];
    const void* Wk = d_in[8];
    const void* bk = d_in[9];
    const void* Wv = d_in[10];
    const void* bv = d_in[11];
    const void* Wo = d_in[12];
    const void* bo = d_in[13];
    const void* WG = d_in[14];
    const void* bG = d_in[15];

    char* ws = (char*)d_ws;
    const size_t MB = 1u << 20;

    if (ws_size >= 54 * MB) {   // tier-1 (confirmed active since round 3)
        int* flag = (int*)ws;
        float* biasf = (float*)(ws + 4096);
        ushort* wt = (ushort*)(ws + 16384);
        size_t p = 16384 + 2097152;
        ushort* qw = (ushort*)(ws + p); p += 4194304;
        ushort* kw = (ushort*)(ws + p); p += 4194304;
        ushort* vt = (ushort*)(ws + p); p += 4194304;
        ushort* att = (ushort*)(ws + p); p += 4194304;
        ushort* glog = (ushort*)(ws + p);   // 32 MB: [bl][it][h][16][512] fp16

        hipLaunchKernelGGL(transw, dim3(16, 16, 4), dim3(256), 0, stream,
                           Wq, Wk, Wv, Wo, bq, bk, bv, bo, (const uint*)xq,
                           wt, biasf, flag);
        hipLaunchKernelGGL(stage1, dim3(5632), dim3(256), 0, stream,
                           xq, xk, xv, wt, biasf, qw, kw, vt,
                           box, nobj, WG, bG, glog, flag);
        hipLaunchKernelGGL(attn3, dim3(32, H_, B_), dim3(256), 0, stream,
                           qw, kw, vt, mask, glog, att, 0);
        hipLaunchKernelGGL(gemm1, dim3(64, 8), dim3(256), 0, stream,
                           att, wt, biasf, d_out, flag);
    } else {
        // tier-3 fallback (proven round-3 path, ~16.6 MB)
        int* flag = (int*)ws;
        ushort* qw = (ushort*)(ws + 256);
        ushort* kw = (ushort*)(ws + 256 + 4194304);
        ushort* vw = (ushort*)(ws + 256 + 8388608);
        ushort* att = (ushort*)(ws + 256 + 12582912);
        hipLaunchKernelGGL(probe_dtype, dim3(1), dim3(256), 0, stream, (const uint*)xq, flag);
        hipLaunchKernelGGL(gemm16, dim3(2048), dim3(256), 0, stream, xq, Wq, bq, (void*)qw, flag, 1, 1);
        hipLaunchKernelGGL(gemm16, dim3(2048), dim3(256), 0, stream, xk, Wk, bk, (void*)kw, flag, 1, 1);
        hipLaunchKernelGGL(gemm16, dim3(2048), dim3(256), 0, stream, xv, Wv, bv, (void*)vw, flag, 1, 1);
        hipLaunchKernelGGL(attn_old, dim3(N_ / 8, H_, B_), dim3(256), 0, stream,
                           qw, kw, vw, box, mask, nobj, WG, bG, att, flag);
        hipLaunchKernelGGL(gemm16, dim3(2048), dim3(256), 0, stream, att, Wo, bo, d_out, flag, 0, 2);
    }
}